// Round 6
// baseline (641.581 us; speedup 1.0000x reference)
//
#include <hip/hip_runtime.h>

typedef unsigned short u16;
typedef __attribute__((ext_vector_type(8))) short bf16x8;
typedef __attribute__((ext_vector_type(4))) float f32x4;
typedef __attribute__((ext_vector_type(4))) u16 u16x4;

#define C1 0.18033688011112042f   // log2(e)/8  (folds the 1/sqrt(64) score scale)

#define GLDS(g, l) __builtin_amdgcn_global_load_lds( \
    (const __attribute__((address_space(1))) void*)(g), \
    (__attribute__((address_space(3))) void*)(l), 16, 0, 0)

__device__ __forceinline__ u16 f2bf(float x){
  unsigned u = __float_as_uint(x);
  u += 0x7fffu + ((u >> 16) & 1u);
  return (u16)(u >> 16);
}
__device__ __forceinline__ float bf2f(u16 h){ return __uint_as_float(((unsigned)h) << 16); }
__device__ __forceinline__ void fsplit(float x, u16 &h, u16 &l){
  h = f2bf(x);
  l = f2bf(x - bf2f(h));
}

// RTNE pack of (x0,x1) -> u32 {bf16(x1):bf16(x0)}, plus lo-residual pack.
__device__ __forceinline__ void pksplit(float x0, float x1, unsigned &h, unsigned &l){
  unsigned r0 = __float_as_uint(x0); r0 += 0x7fffu + ((r0 >> 16) & 1u);
  unsigned r1 = __float_as_uint(x1); r1 += 0x7fffu + ((r1 >> 16) & 1u);
  h = (r0 >> 16) | (r1 & 0xffff0000u);
  float y0 = x0 - __uint_as_float(r0 & 0xffff0000u);
  float y1 = x1 - __uint_as_float(r1 & 0xffff0000u);
  unsigned s0 = __float_as_uint(y0); s0 += 0x7fffu + ((s0 >> 16) & 1u);
  unsigned s1 = __float_as_uint(y1); s1 += 0x7fffu + ((s1 >> 16) & 1u);
  l = (s0 >> 16) | (s1 & 0xffff0000u);
}

// hi-only RTNE pack of (x0,x1) -> u32 {bf16(x1):bf16(x0)}.
__device__ __forceinline__ unsigned pkhi(float x0, float x1){
  unsigned r0 = __float_as_uint(x0); r0 += 0x7fffu + ((r0 >> 16) & 1u);
  unsigned r1 = __float_as_uint(x1); r1 += 0x7fffu + ((r1 >> 16) & 1u);
  return (r0 >> 16) | (r1 & 0xffff0000u);
}

// Stage a [ROWS][64]-bf16 tile (row = 128B) into LDS with XOR-swizzled 16B slots
// (register-staged variant, used by the projection GEMMs).
template<int ROWS, int NT>
__device__ __forceinline__ void stage_tile(bf16x8* lds, const u16* __restrict__ g,
                                           size_t row0, int ldg, int col0, int tid){
#pragma unroll
  for (int p = 0; p < (ROWS*8)/NT; ++p){
    int idx = tid + p*NT;
    int r = idx >> 3, slot = idx & 7;
    bf16x8 v = *(const bf16x8*)(g + (row0 + (size_t)r)*(size_t)ldg + col0 + slot*8);
    lds[r*8 + (slot ^ (r & 7))] = v;
  }
}

__device__ __forceinline__ bf16x8 frag(const bf16x8* lds, int r, int slot){
  return lds[r*8 + (slot ^ (r & 7))];
}

// split-bf16 3-term product: X*Y ~= Xh*Yh + Xh*Yl + Xl*Yh   (fp32 accumulate)
__device__ __forceinline__ f32x4 mfma3(bf16x8 xh, bf16x8 xl, bf16x8 yh, bf16x8 yl, f32x4 c){
  c = __builtin_amdgcn_mfma_f32_16x16x32_bf16(xh, yh, c, 0, 0, 0);
  c = __builtin_amdgcn_mfma_f32_16x16x32_bf16(xh, yl, c, 0, 0, 0);
  c = __builtin_amdgcn_mfma_f32_16x16x32_bf16(xl, yh, c, 0, 0, 0);
  return c;
}

// ---- C/D-layout -> B-fragment relayout via 4-lane shuffle (full 64-elem) ----
// Input : lane (cl,gq) holds X[q=cl][u = a*16 + gq*4 + r] as f32 (a=0..3, r=0..3).
// Output: (oh0,ol0) = hi/lo bf16x8 of X[q=cl][u = gq*8 + j], (oh1,ol1) for u=32+...
// Word f=ks*4+c: source lane gq_s = 2*(gq&1)+(c>>1); packed word t = ks*4 +
// 2*(gq>>1) + (c&1) -> shuffle both t0/t0+2 candidates, select by dest gq>>1.
__device__ __forceinline__ void exchange(const f32x4* X, int srcA, int srcB, bool sel_hi,
                                         bf16x8& oh0, bf16x8& oh1, bf16x8& ol0, bf16x8& ol1)
{
  unsigned hi[8], lo[8];
#pragma unroll
  for (int a = 0; a < 4; ++a)
#pragma unroll
    for (int b0 = 0; b0 < 2; ++b0)
      pksplit(X[a][2*b0], X[a][2*b0+1], hi[a*2+b0], lo[a*2+b0]);
  unsigned OH[8], OL[8];
#pragma unroll
  for (int f = 0; f < 8; ++f){
    const int t0 = (f>>2)*4 + (f&1);
    const int sl = ((f&3)>>1) ? srcB : srcA;
    unsigned h0 = (unsigned)__shfl((int)hi[t0],     sl, 64);
    unsigned h2 = (unsigned)__shfl((int)hi[t0 + 2], sl, 64);
    unsigned l0_ = (unsigned)__shfl((int)lo[t0],     sl, 64);
    unsigned l2_ = (unsigned)__shfl((int)lo[t0 + 2], sl, 64);
    OH[f] = sel_hi ? h2 : h0;
    OL[f] = sel_hi ? l2_ : l0_;
  }
  union U { unsigned u[4]; bf16x8 b; };
  U a0, a1, b0_, b1_;
#pragma unroll
  for (int c = 0; c < 4; ++c){ a0.u[c]=OH[c]; a1.u[c]=OH[4+c]; b0_.u[c]=OL[c]; b1_.u[c]=OL[4+c]; }
  oh0=a0.b; oh1=a1.b; ol0=b0_.b; ol1=b1_.b;
}

// 32-row, hi-only variant: input X[0..1] (2 C/D frags = rows 0..31), output ONE
// B-frag covering u = gq*8 + j. Identical math to the f<4 half of exchange():
// word c: src lane gq_s = 2*(gq&1)+(c>>1) (srcA/srcB by c>>1), packed word
// t = 2*(gq>>1) + (c&1) -> candidates hi[c&1] / hi[(c&1)+2], select by gq>>1.
__device__ __forceinline__ bf16x8 exchange_hi32(const f32x4* X, int srcA, int srcB, bool sel_hi){
  unsigned hi[4];
#pragma unroll
  for (int a = 0; a < 2; ++a)
#pragma unroll
    for (int b0 = 0; b0 < 2; ++b0)
      hi[a*2+b0] = pkhi(X[a][2*b0], X[a][2*b0+1]);
  unsigned OH[4];
#pragma unroll
  for (int c = 0; c < 4; ++c){
    const int t0 = c & 1;
    const int sl = (c>>1) ? srcB : srcA;
    unsigned h0 = (unsigned)__shfl((int)hi[t0],     sl, 64);
    unsigned h2 = (unsigned)__shfl((int)hi[t0 + 2], sl, 64);
    OH[c] = sel_hi ? h2 : h0;
  }
  union { unsigned u[4]; bf16x8 b; } o;
#pragma unroll
  for (int c = 0; c < 4; ++c) o.u[c] = OH[c];
  return o.b;
}

// ---------------- elementwise split: fp32 -> (hi,lo) bf16 ----------------
__global__ void __launch_bounds__(256) k_split_in(const float* __restrict__ x,
                                                  u16* __restrict__ hh, u16* __restrict__ ll, int n4){
  for (int i = blockIdx.x*256 + threadIdx.x; i < n4; i += gridDim.x*256){
    float4 v = ((const float4*)x)[i];
    float a[4] = {v.x, v.y, v.z, v.w};
    u16x4 h, l;
#pragma unroll
    for (int j = 0; j < 4; ++j){ u16 p, q; fsplit(a[j], p, q); h[j] = p; l[j] = q; }
    *(u16x4*)(hh + (size_t)i*4) = h;
    *(u16x4*)(ll + (size_t)i*4) = l;
  }
}

// ---------------- weight transpose + split: W[k][n] -> Wt[n][k] hi/lo ----------------
__global__ void __launch_bounds__(256) k_wsplit(const float* __restrict__ W,
                                                u16* __restrict__ Th, u16* __restrict__ Tl){
  __shared__ float t[32][33];
  int tx = threadIdx.x & 31, ty = threadIdx.x >> 5;      // 32 x 8
  int n0 = blockIdx.x*32, k0 = blockIdx.y*32;
#pragma unroll
  for (int i = 0; i < 4; ++i)
    t[ty + 8*i][tx] = W[(size_t)(k0 + ty + 8*i)*1024 + n0 + tx];
  __syncthreads();
#pragma unroll
  for (int i = 0; i < 4; ++i){
    int n = n0 + ty + 8*i, k = k0 + tx;
    u16 a, b; fsplit(t[tx][ty + 8*i], a, b);
    Th[(size_t)n*1024 + k] = a;
    Tl[(size_t)n*1024 + k] = b;
  }
}

// ---------------- projection / output GEMM ----------------
// C(4096x1024) = A(4096x1024) * Bt^T (+bias), tile 128x64, 4 waves x (32 rows x 64 cols)
// MODE 0: Q  -> LN, natural head-major split write
// MODE 1: K  -> LN, natural + transposed split writes
// MODE 2: V  -> transposed split write
// MODE 3: out-> fp32 write to d_out
template<int MODE>
__global__ void __launch_bounds__(256, 3) k_proj(
    const u16* __restrict__ Ah, const u16* __restrict__ Al,
    const u16* __restrict__ Bh, const u16* __restrict__ Bl,
    const float* __restrict__ bias, const float* __restrict__ gamma, const float* __restrict__ beta,
    u16* __restrict__ Nh, u16* __restrict__ Nl,
    u16* __restrict__ Th, u16* __restrict__ Tl,
    float* __restrict__ Fo)
{
  __shared__ bf16x8 sAh[128*8], sAl[128*8], sBh[64*8], sBl[64*8];
  const int tid = threadIdx.x, lane = tid & 63, w = tid >> 6;
  const int cl = lane & 15, gq = lane >> 4;
  const int nt = blockIdx.x, mt = blockIdx.y;
  f32x4 acc[2][4] = {};
  for (int kt = 0; kt < 16; ++kt){
    __syncthreads();
    stage_tile<128,256>(sAh, Ah, (size_t)mt*128, 1024, kt*64, tid);
    stage_tile<128,256>(sAl, Al, (size_t)mt*128, 1024, kt*64, tid);
    stage_tile<64,256>(sBh, Bh, (size_t)nt*64, 1024, kt*64, tid);
    stage_tile<64,256>(sBl, Bl, (size_t)nt*64, 1024, kt*64, tid);
    __syncthreads();
#pragma unroll
    for (int ks = 0; ks < 2; ++ks){
      const int slot = ks*4 + gq;
      bf16x8 ah0 = frag(sAh, w*32 + cl, slot);
      bf16x8 al0 = frag(sAl, w*32 + cl, slot);
      bf16x8 ah1 = frag(sAh, w*32 + 16 + cl, slot);
      bf16x8 al1 = frag(sAl, w*32 + 16 + cl, slot);
#pragma unroll
      for (int f = 0; f < 4; ++f){
        bf16x8 bh_ = frag(sBh, f*16 + cl, slot);
        bf16x8 bl_ = frag(sBl, f*16 + cl, slot);
        acc[0][f] = mfma3(ah0, al0, bh_, bl_, acc[0][f]);
        acc[1][f] = mfma3(ah1, al1, bh_, bl_, acc[1][f]);
      }
    }
  }
  float bv[4];
#pragma unroll
  for (int f = 0; f < 4; ++f) bv[f] = bias[nt*64 + f*16 + cl];
  float gm[4], bt[4];
  if constexpr (MODE <= 1){
#pragma unroll
    for (int f = 0; f < 4; ++f){ gm[f] = gamma[f*16 + cl]; bt[f] = beta[f*16 + cl]; }
  }
#pragma unroll
  for (int mi = 0; mi < 2; ++mi){
    float v[4][4];
#pragma unroll
    for (int f = 0; f < 4; ++f)
#pragma unroll
      for (int r = 0; r < 4; ++r) v[f][r] = acc[mi][f][r] + bv[f];
    if constexpr (MODE <= 1){
#pragma unroll
      for (int r = 0; r < 4; ++r){
        float s1 = v[0][r] + v[1][r] + v[2][r] + v[3][r];
        float s2 = v[0][r]*v[0][r] + v[1][r]*v[1][r] + v[2][r]*v[2][r] + v[3][r]*v[3][r];
#pragma unroll
        for (int d = 1; d < 16; d <<= 1){ s1 += __shfl_xor(s1, d); s2 += __shfl_xor(s2, d); }
        float mu = s1 * (1.f/64.f);
        float var = s2 * (1.f/64.f) - mu*mu;
        float rs = rsqrtf(var + 1e-5f);
#pragma unroll
        for (int f = 0; f < 4; ++f) v[f][r] = (v[f][r] - mu)*rs*gm[f] + bt[f];
      }
    }
    const int mrow = mt*128 + w*32 + mi*16 + gq*4;   // + r
    if constexpr (MODE == 3){
#pragma unroll
      for (int f = 0; f < 4; ++f)
#pragma unroll
        for (int r = 0; r < 4; ++r)
          Fo[(size_t)(mrow + r)*1024 + nt*64 + f*16 + cl] = v[f][r];
    } else {
      const int b = mrow >> 11, srow = mrow & 2047;
      const size_t hb = (size_t)(b*16 + nt);          // head-major (b*16 + head)
      if constexpr (MODE <= 1){
#pragma unroll
        for (int f = 0; f < 4; ++f)
#pragma unroll
          for (int r = 0; r < 4; ++r){
            u16 h_, l_; fsplit(v[f][r], h_, l_);
            size_t ix = (hb*2048 + srow + r)*64 + f*16 + cl;
            Nh[ix] = h_; Nl[ix] = l_;
          }
      }
      if constexpr (MODE == 1 || MODE == 2){
#pragma unroll
        for (int f = 0; f < 4; ++f){
          u16x4 h4, l4;
#pragma unroll
          for (int r = 0; r < 4; ++r){ u16 a_, b_; fsplit(v[f][r], a_, b_); h4[r] = a_; l4[r] = b_; }
          size_t ix = (hb*64 + f*16 + cl)*2048 + srow;
          *(u16x4*)(Th + ix) = h4;
          *(u16x4*)(Tl + ix) = l4;
        }
      }
    }
  }
}

// ---------------- fused Hopfield attention ----------------
// Block = 512 thr (8 waves), owns (bh, 128 q). Wave w: q32-group g = w&3
// (2 sub-groups of 16), kv-half h = w>>2 (32 of the 64 tile rows). Each K/T
// b128 read feeds both q-groups -> per-CU LDS read traffic halved vs 1:1.
// Fixed-max softmax (scores in [-64,64] deterministically); P bf16 hi-only.
// At iteration end, wave pairs (w, w+4) reduce accO/lsum through the DEAD
// double-buffer half (prefetch at kt==31 deferred until after the reduce).
// LDS regions (bf16x8 units): r*1024 + buf*512, r: 0=KH 1=KL 2=TH 3=TL.
__global__ void __launch_bounds__(512, 4) k_hopfield(
    const u16* __restrict__ Qh, const u16* __restrict__ Ql,
    const u16* __restrict__ Kh, const u16* __restrict__ Kl,
    const u16* __restrict__ Kth, const u16* __restrict__ Ktl,
    const u16* __restrict__ Vth, const u16* __restrict__ Vtl,
    u16* __restrict__ Oh, u16* __restrict__ Ol)
{
  __shared__ bf16x8 smem[4096];
  __shared__ float lred[512];
  const int tid = threadIdx.x, lane = tid & 63, w = tid >> 6;
  const int cl = lane & 15, gq = lane >> 4;
  const int g = w & 3, h = w >> 2;
  int flat = blockIdx.x;
  flat = (flat & 7)*64 + (flat >> 3);              // XCD swizzle (512 % 8 == 0: bijective)
  const int bh = flat >> 4, qt = flat & 15;
  const size_t base = (size_t)bh * (2048*64);

  // staging: thread stages slot tid of each 64x64 tile; source pre-swizzled so
  // the lane-linear LDS write lands XOR-swizzled. GLDS base is wave-uniform.
  const int sr = tid >> 3, ss = (tid & 7) ^ (sr & 7);
  const size_t offK = base + (size_t)sr*64 + ss*8;      // + kt*4096
  const size_t offT = base + (size_t)sr*2048 + ss*8;    // + kt*64
  const int wb = w << 6;                                // wave-uniform LDS offset
#define DST(r_, b_) (&smem[(r_)*1024 + (b_)*512 + wb])

  // q fragments (B-operand layout), 2 q-groups, live across all 4 iterations
  bf16x8 qfh[2][2], qfl[2][2];
#pragma unroll
  for (int qg = 0; qg < 2; ++qg){
    const int q = qt*128 + g*32 + qg*16 + cl;
#pragma unroll
    for (int ks = 0; ks < 2; ++ks){
      size_t ix = base + (size_t)q*64 + ks*32 + gq*8;
      qfh[qg][ks] = *(const bf16x8*)(Qh + ix);
      qfl[qg][ks] = *(const bf16x8*)(Ql + ix);
    }
  }

  const int srcA = cl + ((gq & 1) << 5);   // shuffle source lanes for exchange()
  const int srcB = srcA + 16;
  const bool sel_hi = gq >= 2;             // dest-side select: t-offset = 2*(gq>>1)

  float lsum[2] = {0.f, 0.f};              // per-q-group partial denominators
  f32x4 accO[2][4] = {};

  // prologue: stage tile 0 (it=0 -> T source is Kt)
  GLDS(Kh  + offK, DST(0,0));
  GLDS(Kl  + offK, DST(1,0));
  GLDS(Kth + offT, DST(2,0));
  GLDS(Ktl + offT, DST(3,0));
  __syncthreads();

  for (int t = 0; t < 128; ++t){
    const int cur = t & 1, nb = cur ^ 1, kt = t & 31;
    if (kt != 31){                         // prefetch t+1 (deferred at kt==31)
      const int nt_ = t + 1, nit = nt_ >> 5, nkt = nt_ & 31;
      const u16* th = (nit < 3) ? Kth : Vth;
      const u16* tl = (nit < 3) ? Ktl : Vtl;
      const size_t oK = offK + (size_t)nkt*4096;
      const size_t oT = offT + (size_t)nkt*64;
      GLDS(Kh + oK, DST(0,nb));
      GLDS(Kl + oK, DST(1,nb));
      GLDS(th + oT, DST(2,nb));
      GLDS(tl + oT, DST(3,nb));
    }
    // ---- QK^T: St[kv-half h][q], both q-groups share each K fragment ----
    const bf16x8* pKH = smem + 0*1024 + cur*512;
    const bf16x8* pKL = smem + 1*1024 + cur*512;
    const bf16x8* pTH = smem + 2*1024 + cur*512;
    const bf16x8* pTL = smem + 3*1024 + cur*512;
    f32x4 S2[2][2] = {};
    __builtin_amdgcn_s_setprio(1);
#pragma unroll
    for (int ks = 0; ks < 2; ++ks){
      const int slot = ks*4 + gq;
#pragma unroll
      for (int i = 0; i < 2; ++i){
        bf16x8 kh_ = frag(pKH, h*32 + i*16 + cl, slot);
        bf16x8 kl_ = frag(pKL, h*32 + i*16 + cl, slot);
        S2[0][i] = mfma3(kh_, kl_, qfh[0][ks], qfl[0][ks], S2[0][i]);
        S2[1][i] = mfma3(kh_, kl_, qfh[1][ks], qfl[1][ks], S2[1][i]);
      }
    }
    __builtin_amdgcn_s_setprio(0);
    // ---- fixed-max softmax + P relayout (per q-group, hi-only) ----
    bf16x8 pfrag[2];
#pragma unroll
    for (int qg = 0; qg < 2; ++qg){
#pragma unroll
      for (int i = 0; i < 2; ++i)
#pragma unroll
        for (int r = 0; r < 4; ++r){
          float p = exp2f((S2[qg][i][r] - 64.f)*C1);
          S2[qg][i][r] = p;
          lsum[qg] += p;
        }
      pfrag[qg] = exchange_hi32(S2[qg], srcA, srcB, sel_hi);
    }
    // ---- PV: O^T += T^T * P^T over this wave's kv-half (slot = h*4+gq) ----
    const int pslot = h*4 + gq;
    __builtin_amdgcn_s_setprio(1);
#pragma unroll
    for (int db = 0; db < 4; ++db){
      bf16x8 vh_ = frag(pTH, db*16 + cl, pslot);
      bf16x8 vl_ = frag(pTL, db*16 + cl, pslot);
      accO[0][db] = __builtin_amdgcn_mfma_f32_16x16x32_bf16(vh_, pfrag[0], accO[0][db], 0, 0, 0);
      accO[0][db] = __builtin_amdgcn_mfma_f32_16x16x32_bf16(vl_, pfrag[0], accO[0][db], 0, 0, 0);
      accO[1][db] = __builtin_amdgcn_mfma_f32_16x16x32_bf16(vh_, pfrag[1], accO[1][db], 0, 0, 0);
      accO[1][db] = __builtin_amdgcn_mfma_f32_16x16x32_bf16(vl_, pfrag[1], accO[1][db], 0, 0, 0);
    }
    __builtin_amdgcn_s_setprio(0);
    // ---- iteration epilogue: pair-reduce through dead buffer nb ----
    if (kt == 31){
      union B16 { f32x4 f; bf16x8 b; };
      const int didx = (g*64 + lane)*8;    // 8 b128 slots per lane, per pair g
      // dead-buffer slot d (0..2047) -> region (d>>9), buffer nb, slot d&511
#define SCR(d_) (smem + (((d_)>>9)*1024 + nb*512 + ((d_)&511)))
      if (h == 1){                         // upper: export accO + lsum
#pragma unroll
        for (int qg = 0; qg < 2; ++qg)
#pragma unroll
          for (int db = 0; db < 4; ++db){
            B16 u_; u_.f = accO[qg][db];
            *SCR(didx + qg*4 + db) = u_.b;
          }
        lred[(g*64 + lane)*2 + 0] = lsum[0];
        lred[(g*64 + lane)*2 + 1] = lsum[1];
      }
      __syncthreads();
      if (h == 0){                         // lower: sum, normalize, rebuild q
        f32x4 vals[2][4];
#pragma unroll
        for (int qg = 0; qg < 2; ++qg){
#pragma unroll
          for (int db = 0; db < 4; ++db){
            B16 u_; u_.b = *SCR(didx + qg*4 + db);
#pragma unroll
            for (int r = 0; r < 4; ++r) accO[qg][db][r] += u_.f[r];
          }
          float lt = lsum[qg] + lred[(g*64 + lane)*2 + qg];
          lt += __shfl_xor(lt, 16);
          lt += __shfl_xor(lt, 32);
          const float inv = 1.f / lt;
#pragma unroll
          for (int db = 0; db < 4; ++db)
#pragma unroll
            for (int r = 0; r < 4; ++r) vals[qg][db][r] = accO[qg][db][r]*inv;
        }
        if (t < 127){
#pragma unroll
          for (int qg = 0; qg < 2; ++qg){
            exchange(vals[qg], srcA, srcB, sel_hi,
                     qfh[qg][0], qfh[qg][1], qfl[qg][0], qfl[qg][1]);
#pragma unroll
            for (int ks = 0; ks < 2; ++ks){   // export q-frags (same slots, own reads done)
              *SCR(didx + qg*2 + ks)     = qfh[qg][ks];
              *SCR(didx + 4 + qg*2 + ks) = qfl[qg][ks];
            }
          }
        } else {                          // final readout: write O
          const int b = bh >> 4, hd = bh & 15;
#pragma unroll
          for (int qg = 0; qg < 2; ++qg){
            const int q = qt*128 + g*32 + qg*16 + cl;
            const size_t row = (size_t)b*2048 + q;
#pragma unroll
            for (int db = 0; db < 4; ++db){
              u16x4 h4, l4;
#pragma unroll
              for (int r = 0; r < 4; ++r){
                u16 a_, b_; fsplit(vals[qg][db][r], a_, b_); h4[r] = a_; l4[r] = b_;
              }
              size_t ix = row*1024 + hd*64 + db*16 + gq*4;
              *(u16x4*)(Oh + ix) = h4;
              *(u16x4*)(Ol + ix) = l4;
            }
          }
        }
      }
      if (t < 127){
        __syncthreads();
        if (h == 1){                      // upper: import rebuilt q-frags
#pragma unroll
          for (int qg = 0; qg < 2; ++qg)
#pragma unroll
            for (int ks = 0; ks < 2; ++ks){
              qfh[qg][ks] = *SCR(didx + qg*2 + ks);
              qfl[qg][ks] = *SCR(didx + 4 + qg*2 + ks);
            }
        }
        __syncthreads();                  // scratch reads done before GLDS lands
        const int nt_ = t + 1, nit = nt_ >> 5, nkt = nt_ & 31;
        const u16* th = (nit < 3) ? Kth : Vth;
        const u16* tl = (nit < 3) ? Ktl : Vtl;
        const size_t oK = offK + (size_t)nkt*4096;
        const size_t oT = offT + (size_t)nkt*64;
        GLDS(Kh + oK, DST(0,nb));
        GLDS(Kl + oK, DST(1,nb));
        GLDS(th + oT, DST(2,nb));
        GLDS(tl + oT, DST(3,nb));
        lsum[0] = lsum[1] = 0.f;
#pragma unroll
        for (int qg = 0; qg < 2; ++qg)
#pragma unroll
          for (int db = 0; db < 4; ++db) accO[qg][db] = f32x4{0,0,0,0};
      }
#undef SCR
    }
    __syncthreads();
  }
#undef DST
}

extern "C" void kernel_launch(void* const* d_in, const int* in_sizes, int n_in,
                              void* d_out, int out_size, void* d_ws, size_t ws_size,
                              hipStream_t stream) {
  (void)in_sizes; (void)n_in; (void)out_size; (void)ws_size;
  const float* query = (const float*)d_in[0];
  const float* key   = (const float*)d_in[1];
  const float* value = (const float*)d_in[2];
  const float* Wq = (const float*)d_in[3];
  const float* bq = (const float*)d_in[4];
  const float* Wk = (const float*)d_in[5];
  const float* bk = (const float*)d_in[6];
  const float* Wv = (const float*)d_in[7];
  const float* bv = (const float*)d_in[8];
  const float* Wo = (const float*)d_in[9];
  const float* bo = (const float*)d_in[10];
  const float* gamma = (const float*)d_in[11];
  const float* beta  = (const float*)d_in[12];
  float* out = (float*)d_out;

  char* ws = (char*)d_ws;
  const size_t MB = 1024*1024;
  u16* inq_h = (u16*)(ws + 0*MB),  *inq_l = (u16*)(ws + 8*MB);
  u16* ink_h = (u16*)(ws + 16*MB), *ink_l = (u16*)(ws + 24*MB);
  u16* inv_h = (u16*)(ws + 32*MB), *inv_l = (u16*)(ws + 40*MB);
  u16* wq_h = (u16*)(ws + 48*MB), *wq_l = (u16*)(ws + 50*MB);
  u16* wk_h = (u16*)(ws + 52*MB), *wk_l = (u16*)(ws + 54*MB);
  u16* wv_h = (u16*)(ws + 56*MB), *wv_l = (u16*)(ws + 58*MB);
  u16* wo_h = (u16*)(ws + 60*MB), *wo_l = (u16*)(ws + 62*MB);
  u16* Qh  = (u16*)(ws + 64*MB),  *Ql  = (u16*)(ws + 72*MB);
  u16* Kh  = (u16*)(ws + 80*MB),  *Kl  = (u16*)(ws + 88*MB);
  u16* Kth = (u16*)(ws + 96*MB),  *Ktl = (u16*)(ws + 104*MB);
  u16* Vth = (u16*)(ws + 112*MB), *Vtl = (u16*)(ws + 120*MB);
  u16* Oh = inq_h, *Ol = inq_l;    // reuse: inq dead after proj<0>

  const int n4 = 4096*1024/4;
  k_split_in<<<dim3(2048), dim3(256), 0, stream>>>(query, inq_h, inq_l, n4);
  k_split_in<<<dim3(2048), dim3(256), 0, stream>>>(key,   ink_h, ink_l, n4);
  k_split_in<<<dim3(2048), dim3(256), 0, stream>>>(value, inv_h, inv_l, n4);
  k_wsplit<<<dim3(32,32), dim3(256), 0, stream>>>(Wq, wq_h, wq_l);
  k_wsplit<<<dim3(32,32), dim3(256), 0, stream>>>(Wk, wk_h, wk_l);
  k_wsplit<<<dim3(32,32), dim3(256), 0, stream>>>(Wv, wv_h, wv_l);
  k_wsplit<<<dim3(32,32), dim3(256), 0, stream>>>(Wo, wo_h, wo_l);

  k_proj<0><<<dim3(16,32), dim3(256), 0, stream>>>(inq_h, inq_l, wq_h, wq_l, bq, gamma, beta,
                                                   Qh, Ql, nullptr, nullptr, nullptr);
  k_proj<1><<<dim3(16,32), dim3(256), 0, stream>>>(ink_h, ink_l, wk_h, wk_l, bk, gamma, beta,
                                                   Kh, Kl, Kth, Ktl, nullptr);
  k_proj<2><<<dim3(16,32), dim3(256), 0, stream>>>(inv_h, inv_l, wv_h, wv_l, bv, nullptr, nullptr,
                                                   nullptr, nullptr, Vth, Vtl, nullptr);

  k_hopfield<<<dim3(512), dim3(512), 0, stream>>>(Qh, Ql, Kh, Kl, Kth, Ktl, Vth, Vtl, Oh, Ol);

  k_proj<3><<<dim3(16,32), dim3(256), 0, stream>>>(Oh, Ol, wo_h, wo_l, bo, nullptr, nullptr,
                                                   nullptr, nullptr, nullptr, nullptr, out);
}

// Round 7
// 522.387 us; speedup vs baseline: 1.2282x; 1.2282x over previous
//
#include <hip/hip_runtime.h>

typedef unsigned short u16;
typedef __attribute__((ext_vector_type(8))) short bf16x8;
typedef __attribute__((ext_vector_type(4))) float f32x4;
typedef __attribute__((ext_vector_type(4))) u16 u16x4;

#define C1 0.18033688011112042f   // log2(e)/8  (folds the 1/sqrt(64) score scale)

#define GLDS(g, l) __builtin_amdgcn_global_load_lds( \
    (const __attribute__((address_space(1))) void*)(g), \
    (__attribute__((address_space(3))) void*)(l), 16, 0, 0)

__device__ __forceinline__ u16 f2bf(float x){
  unsigned u = __float_as_uint(x);
  u += 0x7fffu + ((u >> 16) & 1u);
  return (u16)(u >> 16);
}
__device__ __forceinline__ float bf2f(u16 h){ return __uint_as_float(((unsigned)h) << 16); }
__device__ __forceinline__ void fsplit(float x, u16 &h, u16 &l){
  h = f2bf(x);
  l = f2bf(x - bf2f(h));
}

// RTNE pack of (x0,x1) -> u32 {bf16(x1):bf16(x0)}, plus lo-residual pack.
__device__ __forceinline__ void pksplit(float x0, float x1, unsigned &h, unsigned &l){
  unsigned r0 = __float_as_uint(x0); r0 += 0x7fffu + ((r0 >> 16) & 1u);
  unsigned r1 = __float_as_uint(x1); r1 += 0x7fffu + ((r1 >> 16) & 1u);
  h = (r0 >> 16) | (r1 & 0xffff0000u);
  float y0 = x0 - __uint_as_float(r0 & 0xffff0000u);
  float y1 = x1 - __uint_as_float(r1 & 0xffff0000u);
  unsigned s0 = __float_as_uint(y0); s0 += 0x7fffu + ((s0 >> 16) & 1u);
  unsigned s1 = __float_as_uint(y1); s1 += 0x7fffu + ((s1 >> 16) & 1u);
  l = (s0 >> 16) | (s1 & 0xffff0000u);
}

// hi-only RTNE pack of (x0,x1) -> u32 {bf16(x1):bf16(x0)}.
__device__ __forceinline__ unsigned pkhi(float x0, float x1){
  unsigned r0 = __float_as_uint(x0); r0 += 0x7fffu + ((r0 >> 16) & 1u);
  unsigned r1 = __float_as_uint(x1); r1 += 0x7fffu + ((r1 >> 16) & 1u);
  return (r0 >> 16) | (r1 & 0xffff0000u);
}

// Stage a [ROWS][64]-bf16 tile (row = 128B) into LDS with XOR-swizzled 16B slots
// (register-staged variant, used by the projection GEMMs).
template<int ROWS, int NT>
__device__ __forceinline__ void stage_tile(bf16x8* lds, const u16* __restrict__ g,
                                           size_t row0, int ldg, int col0, int tid){
#pragma unroll
  for (int p = 0; p < (ROWS*8)/NT; ++p){
    int idx = tid + p*NT;
    int r = idx >> 3, slot = idx & 7;
    bf16x8 v = *(const bf16x8*)(g + (row0 + (size_t)r)*(size_t)ldg + col0 + slot*8);
    lds[r*8 + (slot ^ (r & 7))] = v;
  }
}

__device__ __forceinline__ bf16x8 frag(const bf16x8* lds, int r, int slot){
  return lds[r*8 + (slot ^ (r & 7))];
}

// split-bf16 3-term product: X*Y ~= Xh*Yh + Xh*Yl + Xl*Yh   (fp32 accumulate)
__device__ __forceinline__ f32x4 mfma3(bf16x8 xh, bf16x8 xl, bf16x8 yh, bf16x8 yl, f32x4 c){
  c = __builtin_amdgcn_mfma_f32_16x16x32_bf16(xh, yh, c, 0, 0, 0);
  c = __builtin_amdgcn_mfma_f32_16x16x32_bf16(xh, yl, c, 0, 0, 0);
  c = __builtin_amdgcn_mfma_f32_16x16x32_bf16(xl, yh, c, 0, 0, 0);
  return c;
}

// ---- C/D-layout -> B-fragment relayout via 4-lane shuffle --------------------
// Input : lane (cl,gq) holds X[q=cl][u = a*16 + gq*4 + r] as f32 (a=0..3, r=0..3).
// Output: (oh0,ol0) = hi/lo bf16x8 of X[q=cl][u = gq*8 + j], (oh1,ol1) for u=32+...
// Word f=ks*4+c: source lane gq_s = 2*(gq&1)+(c>>1); packed word t = ks*4 +
// 2*(gq>>1) + (c&1) -> shuffle both t0/t0+2 candidates, select by dest gq>>1.
__device__ __forceinline__ void exchange(const f32x4* X, int srcA, int srcB, bool sel_hi,
                                         bf16x8& oh0, bf16x8& oh1, bf16x8& ol0, bf16x8& ol1)
{
  unsigned hi[8], lo[8];
#pragma unroll
  for (int a = 0; a < 4; ++a)
#pragma unroll
    for (int b0 = 0; b0 < 2; ++b0)
      pksplit(X[a][2*b0], X[a][2*b0+1], hi[a*2+b0], lo[a*2+b0]);
  unsigned OH[8], OL[8];
#pragma unroll
  for (int f = 0; f < 8; ++f){
    const int t0 = (f>>2)*4 + (f&1);
    const int sl = ((f&3)>>1) ? srcB : srcA;
    unsigned h0 = (unsigned)__shfl((int)hi[t0],     sl, 64);
    unsigned h2 = (unsigned)__shfl((int)hi[t0 + 2], sl, 64);
    unsigned l0_ = (unsigned)__shfl((int)lo[t0],     sl, 64);
    unsigned l2_ = (unsigned)__shfl((int)lo[t0 + 2], sl, 64);
    OH[f] = sel_hi ? h2 : h0;
    OL[f] = sel_hi ? l2_ : l0_;
  }
  union U { unsigned u[4]; bf16x8 b; };
  U a0, a1, b0_, b1_;
#pragma unroll
  for (int c = 0; c < 4; ++c){ a0.u[c]=OH[c]; a1.u[c]=OH[4+c]; b0_.u[c]=OL[c]; b1_.u[c]=OL[4+c]; }
  oh0=a0.b; oh1=a1.b; ol0=b0_.b; ol1=b1_.b;
}

// hi-only variant (for P: bf16 precision suffices)
__device__ __forceinline__ void exchange_hi(const f32x4* X, int srcA, int srcB, bool sel_hi,
                                            bf16x8& oh0, bf16x8& oh1)
{
  unsigned hi[8];
#pragma unroll
  for (int a = 0; a < 4; ++a)
#pragma unroll
    for (int b0 = 0; b0 < 2; ++b0)
      hi[a*2+b0] = pkhi(X[a][2*b0], X[a][2*b0+1]);
  unsigned OH[8];
#pragma unroll
  for (int f = 0; f < 8; ++f){
    const int t0 = (f>>2)*4 + (f&1);
    const int sl = ((f&3)>>1) ? srcB : srcA;
    unsigned h0 = (unsigned)__shfl((int)hi[t0],     sl, 64);
    unsigned h2 = (unsigned)__shfl((int)hi[t0 + 2], sl, 64);
    OH[f] = sel_hi ? h2 : h0;
  }
  union U { unsigned u[4]; bf16x8 b; };
  U a0, a1;
#pragma unroll
  for (int c = 0; c < 4; ++c){ a0.u[c]=OH[c]; a1.u[c]=OH[4+c]; }
  oh0=a0.b; oh1=a1.b;
}

// ---------------- elementwise split: fp32 -> (hi,lo) bf16 ----------------
__global__ void __launch_bounds__(256) k_split_in(const float* __restrict__ x,
                                                  u16* __restrict__ hh, u16* __restrict__ ll, int n4){
  for (int i = blockIdx.x*256 + threadIdx.x; i < n4; i += gridDim.x*256){
    float4 v = ((const float4*)x)[i];
    float a[4] = {v.x, v.y, v.z, v.w};
    u16x4 h, l;
#pragma unroll
    for (int j = 0; j < 4; ++j){ u16 p, q; fsplit(a[j], p, q); h[j] = p; l[j] = q; }
    *(u16x4*)(hh + (size_t)i*4) = h;
    *(u16x4*)(ll + (size_t)i*4) = l;
  }
}

// ---------------- weight transpose + split: W[k][n] -> Wt[n][k] hi/lo ----------------
__global__ void __launch_bounds__(256) k_wsplit(const float* __restrict__ W,
                                                u16* __restrict__ Th, u16* __restrict__ Tl){
  __shared__ float t[32][33];
  int tx = threadIdx.x & 31, ty = threadIdx.x >> 5;      // 32 x 8
  int n0 = blockIdx.x*32, k0 = blockIdx.y*32;
#pragma unroll
  for (int i = 0; i < 4; ++i)
    t[ty + 8*i][tx] = W[(size_t)(k0 + ty + 8*i)*1024 + n0 + tx];
  __syncthreads();
#pragma unroll
  for (int i = 0; i < 4; ++i){
    int n = n0 + ty + 8*i, k = k0 + tx;
    u16 a, b; fsplit(t[tx][ty + 8*i], a, b);
    Th[(size_t)n*1024 + k] = a;
    Tl[(size_t)n*1024 + k] = b;
  }
}

// ---------------- projection / output GEMM ----------------
// C(4096x1024) = A(4096x1024) * Bt^T (+bias), tile 128x64, 4 waves x (32 rows x 64 cols)
// MODE 0: Q  -> LN, natural head-major split write
// MODE 1: K  -> LN, natural + transposed split writes
// MODE 2: V  -> transposed split write
// MODE 3: out-> fp32 write to d_out
template<int MODE>
__global__ void __launch_bounds__(256, 3) k_proj(
    const u16* __restrict__ Ah, const u16* __restrict__ Al,
    const u16* __restrict__ Bh, const u16* __restrict__ Bl,
    const float* __restrict__ bias, const float* __restrict__ gamma, const float* __restrict__ beta,
    u16* __restrict__ Nh, u16* __restrict__ Nl,
    u16* __restrict__ Th, u16* __restrict__ Tl,
    float* __restrict__ Fo)
{
  __shared__ bf16x8 sAh[128*8], sAl[128*8], sBh[64*8], sBl[64*8];
  const int tid = threadIdx.x, lane = tid & 63, w = tid >> 6;
  const int cl = lane & 15, gq = lane >> 4;
  const int nt = blockIdx.x, mt = blockIdx.y;
  f32x4 acc[2][4] = {};
  for (int kt = 0; kt < 16; ++kt){
    __syncthreads();
    stage_tile<128,256>(sAh, Ah, (size_t)mt*128, 1024, kt*64, tid);
    stage_tile<128,256>(sAl, Al, (size_t)mt*128, 1024, kt*64, tid);
    stage_tile<64,256>(sBh, Bh, (size_t)nt*64, 1024, kt*64, tid);
    stage_tile<64,256>(sBl, Bl, (size_t)nt*64, 1024, kt*64, tid);
    __syncthreads();
#pragma unroll
    for (int ks = 0; ks < 2; ++ks){
      const int slot = ks*4 + gq;
      bf16x8 ah0 = frag(sAh, w*32 + cl, slot);
      bf16x8 al0 = frag(sAl, w*32 + cl, slot);
      bf16x8 ah1 = frag(sAh, w*32 + 16 + cl, slot);
      bf16x8 al1 = frag(sAl, w*32 + 16 + cl, slot);
#pragma unroll
      for (int f = 0; f < 4; ++f){
        bf16x8 bh_ = frag(sBh, f*16 + cl, slot);
        bf16x8 bl_ = frag(sBl, f*16 + cl, slot);
        acc[0][f] = mfma3(ah0, al0, bh_, bl_, acc[0][f]);
        acc[1][f] = mfma3(ah1, al1, bh_, bl_, acc[1][f]);
      }
    }
  }
  float bv[4];
#pragma unroll
  for (int f = 0; f < 4; ++f) bv[f] = bias[nt*64 + f*16 + cl];
  float gm[4], bt[4];
  if constexpr (MODE <= 1){
#pragma unroll
    for (int f = 0; f < 4; ++f){ gm[f] = gamma[f*16 + cl]; bt[f] = beta[f*16 + cl]; }
  }
#pragma unroll
  for (int mi = 0; mi < 2; ++mi){
    float v[4][4];
#pragma unroll
    for (int f = 0; f < 4; ++f)
#pragma unroll
      for (int r = 0; r < 4; ++r) v[f][r] = acc[mi][f][r] + bv[f];
    if constexpr (MODE <= 1){
#pragma unroll
      for (int r = 0; r < 4; ++r){
        float s1 = v[0][r] + v[1][r] + v[2][r] + v[3][r];
        float s2 = v[0][r]*v[0][r] + v[1][r]*v[1][r] + v[2][r]*v[2][r] + v[3][r]*v[3][r];
#pragma unroll
        for (int d = 1; d < 16; d <<= 1){ s1 += __shfl_xor(s1, d); s2 += __shfl_xor(s2, d); }
        float mu = s1 * (1.f/64.f);
        float var = s2 * (1.f/64.f) - mu*mu;
        float rs = rsqrtf(var + 1e-5f);
#pragma unroll
        for (int f = 0; f < 4; ++f) v[f][r] = (v[f][r] - mu)*rs*gm[f] + bt[f];
      }
    }
    const int mrow = mt*128 + w*32 + mi*16 + gq*4;   // + r
    if constexpr (MODE == 3){
#pragma unroll
      for (int f = 0; f < 4; ++f)
#pragma unroll
        for (int r = 0; r < 4; ++r)
          Fo[(size_t)(mrow + r)*1024 + nt*64 + f*16 + cl] = v[f][r];
    } else {
      const int b = mrow >> 11, srow = mrow & 2047;
      const size_t hb = (size_t)(b*16 + nt);          // head-major (b*16 + head)
      if constexpr (MODE <= 1){
#pragma unroll
        for (int f = 0; f < 4; ++f)
#pragma unroll
          for (int r = 0; r < 4; ++r){
            u16 h_, l_; fsplit(v[f][r], h_, l_);
            size_t ix = (hb*2048 + srow + r)*64 + f*16 + cl;
            Nh[ix] = h_; Nl[ix] = l_;
          }
      }
      if constexpr (MODE == 1 || MODE == 2){
#pragma unroll
        for (int f = 0; f < 4; ++f){
          u16x4 h4, l4;
#pragma unroll
          for (int r = 0; r < 4; ++r){ u16 a_, b_; fsplit(v[f][r], a_, b_); h4[r] = a_; l4[r] = b_; }
          size_t ix = (hb*64 + f*16 + cl)*2048 + srow;
          *(u16x4*)(Th + ix) = h4;
          *(u16x4*)(Tl + ix) = l4;
        }
      }
    }
  }
}

// ---------------- fused Hopfield attention: all 4 iterations in one launch ----------------
// Block = 512 thr (8 waves), owns (bh, 128 q rows). Grid 512 = 2 blocks/CU.
// FIXED-MAX softmax (scores in [-64,64] deterministically -> m=64, no online max).
// K is bf16 hi-only in LDS: S = Kh*(Qh+Ql) (the dropped Kl*q term is ~1e-2 rms on
// scores -> ~1e-3 relative on P, below the accepted P-hi-only quantization).
// P bf16 hi-only; PV keeps full T hi/lo. l accumulated per-lane, reduced per iter.
__global__ void __launch_bounds__(512, 4) k_hopfield(
    const u16* __restrict__ Qh, const u16* __restrict__ Ql,
    const u16* __restrict__ Kh,
    const u16* __restrict__ Kth, const u16* __restrict__ Ktl,
    const u16* __restrict__ Vth, const u16* __restrict__ Vtl,
    u16* __restrict__ Oh, u16* __restrict__ Ol)
{
  __shared__ bf16x8 sKh[2][512], sTh[2][512], sTl[2][512];
  const int tid = threadIdx.x, lane = tid & 63, w = tid >> 6;
  const int cl = lane & 15, gq = lane >> 4;
  int flat = blockIdx.x;
  flat = (flat & 7)*64 + (flat >> 3);              // XCD swizzle (512 % 8 == 0: bijective)
  const int bh = flat >> 4, qt = flat & 15;
  const size_t base = (size_t)bh * (2048*64);
  const int q = qt*128 + w*16 + cl;

  // staging geometry: thread stages slot idx=tid of each 64x64 tile; source column
  // pre-swizzled so the lane-linear LDS write yields the XOR-swizzled layout.
  const int sr = tid >> 3, ss = (tid & 7) ^ (sr & 7);
  const size_t offK = base + (size_t)sr*64 + ss*8;      // + kt*4096
  const size_t offT = base + (size_t)sr*2048 + ss*8;    // + kt*64
  const int wslot = w << 6;                             // wave's LDS chunk (bf16x8 units)

  // q fragments (B-operand layout), live in registers across all 4 iterations
  bf16x8 qfh[2], qfl[2];
#pragma unroll
  for (int ks = 0; ks < 2; ++ks){
    size_t ix = base + (size_t)q*64 + ks*32 + gq*8;
    qfh[ks] = *(const bf16x8*)(Qh + ix);
    qfl[ks] = *(const bf16x8*)(Ql + ix);
  }

  const int srcA = cl + ((gq & 1) << 5);   // shuffle source lanes for exchange()
  const int srcB = srcA + 16;
  const bool sel_hi = gq >= 2;             // dest-side select: t-offset = 2*(gq>>1)

  float lsum = 0.f;                        // per-lane partial softmax denominator
  f32x4 accO[4] = {};

  // prologue: stage tile 0 (it=0 -> T source is Kt)
  GLDS(Kh  + offK, &sKh[0][wslot]);
  GLDS(Kth + offT, &sTh[0][wslot]);
  GLDS(Ktl + offT, &sTl[0][wslot]);
  __syncthreads();

  for (int t = 0; t < 128; ++t){
    const int cur = t & 1, kt = t & 31;
    if (t < 127){
      const int nt_ = t + 1, nb = nt_ & 1, nit = nt_ >> 5, nkt = nt_ & 31;
      const u16* th = (nit < 3) ? Kth : Vth;
      const u16* tl = (nit < 3) ? Ktl : Vtl;
      const size_t oK = offK + (size_t)nkt*4096;
      const size_t oT = offT + (size_t)nkt*64;
      GLDS(Kh + oK, &sKh[nb][wslot]);
      GLDS(th + oT, &sTh[nb][wslot]);
      GLDS(tl + oT, &sTl[nb][wslot]);
    }
    // ---- QK^T: St[kv][q] = Kh * (Qh + Ql) ----
    f32x4 S[4] = {};
    __builtin_amdgcn_s_setprio(1);
#pragma unroll
    for (int ks = 0; ks < 2; ++ks){
      const int slot = ks*4 + gq;
#pragma unroll
      for (int i = 0; i < 4; ++i){
        bf16x8 kh_ = frag(&sKh[cur][0], i*16 + cl, slot);
        S[i] = __builtin_amdgcn_mfma_f32_16x16x32_bf16(kh_, qfh[ks], S[i], 0, 0, 0);
        S[i] = __builtin_amdgcn_mfma_f32_16x16x32_bf16(kh_, qfl[ks], S[i], 0, 0, 0);
      }
    }
    __builtin_amdgcn_s_setprio(0);
    // ---- fixed-max softmax: p = exp((S - 64)/8), no reductions in-tile ----
#pragma unroll
    for (int i = 0; i < 4; ++i)
#pragma unroll
      for (int r = 0; r < 4; ++r){
        float p = exp2f((S[i][r] - 64.f)*C1);
        S[i][r] = p;
        lsum += p;
      }
    // ---- P: C/D layout -> B-frags (hi-only), in-register ----
    bf16x8 ph0, ph1;
    exchange_hi(S, srcA, srcB, sel_hi, ph0, ph1);
    // ---- PV: O^T += T^T * P^T  (2-term: Th*P + Tl*P) ----
    __builtin_amdgcn_s_setprio(1);
#pragma unroll
    for (int ks = 0; ks < 2; ++ks){
      const int slot = ks*4 + gq;
      bf16x8 ph = ks ? ph1 : ph0;
#pragma unroll
      for (int db = 0; db < 4; ++db){
        bf16x8 vh_ = frag(&sTh[cur][0], db*16 + cl, slot);
        bf16x8 vl_ = frag(&sTl[cur][0], db*16 + cl, slot);
        accO[db] = __builtin_amdgcn_mfma_f32_16x16x32_bf16(vh_, ph, accO[db], 0, 0, 0);
        accO[db] = __builtin_amdgcn_mfma_f32_16x16x32_bf16(vl_, ph, accO[db], 0, 0, 0);
      }
    }
    __builtin_amdgcn_s_setprio(0);
    // ---- iteration epilogue ----
    if (kt == 31){
      float lt = lsum;
      lt += __shfl_xor(lt, 16);
      lt += __shfl_xor(lt, 32);
      const float inv = 1.f / lt;
      f32x4 vals[4];
#pragma unroll
      for (int db = 0; db < 4; ++db)
#pragma unroll
        for (int r = 0; r < 4; ++r) vals[db][r] = accO[db][r]*inv;
      if (t < 127){
        exchange(vals, srcA, srcB, sel_hi, qfh[0], qfh[1], qfl[0], qfl[1]);
        lsum = 0.f;
#pragma unroll
        for (int db = 0; db < 4; ++db) accO[db] = f32x4{0,0,0,0};
      } else {
        const int b = bh >> 4, h = bh & 15;
        const size_t row = (size_t)b*2048 + q;
#pragma unroll
        for (int db = 0; db < 4; ++db){
          u16x4 h4, l4;
#pragma unroll
          for (int r = 0; r < 4; ++r){ u16 a_, b_; fsplit(vals[db][r], a_, b_); h4[r] = a_; l4[r] = b_; }
          size_t ix = row*1024 + h*64 + db*16 + gq*4;
          *(u16x4*)(Oh + ix) = h4;
          *(u16x4*)(Ol + ix) = l4;
        }
      }
    }
    __syncthreads();
  }
}

extern "C" void kernel_launch(void* const* d_in, const int* in_sizes, int n_in,
                              void* d_out, int out_size, void* d_ws, size_t ws_size,
                              hipStream_t stream) {
  (void)in_sizes; (void)n_in; (void)out_size; (void)ws_size;
  const float* query = (const float*)d_in[0];
  const float* key   = (const float*)d_in[1];
  const float* value = (const float*)d_in[2];
  const float* Wq = (const float*)d_in[3];
  const float* bq = (const float*)d_in[4];
  const float* Wk = (const float*)d_in[5];
  const float* bk = (const float*)d_in[6];
  const float* Wv = (const float*)d_in[7];
  const float* bv = (const float*)d_in[8];
  const float* Wo = (const float*)d_in[9];
  const float* bo = (const float*)d_in[10];
  const float* gamma = (const float*)d_in[11];
  const float* beta  = (const float*)d_in[12];
  float* out = (float*)d_out;

  char* ws = (char*)d_ws;
  const size_t MB = 1024*1024;
  u16* inq_h = (u16*)(ws + 0*MB),  *inq_l = (u16*)(ws + 8*MB);
  u16* ink_h = (u16*)(ws + 16*MB), *ink_l = (u16*)(ws + 24*MB);
  u16* inv_h = (u16*)(ws + 32*MB), *inv_l = (u16*)(ws + 40*MB);
  u16* wq_h = (u16*)(ws + 48*MB), *wq_l = (u16*)(ws + 50*MB);
  u16* wk_h = (u16*)(ws + 52*MB), *wk_l = (u16*)(ws + 54*MB);
  u16* wv_h = (u16*)(ws + 56*MB), *wv_l = (u16*)(ws + 58*MB);
  u16* wo_h = (u16*)(ws + 60*MB), *wo_l = (u16*)(ws + 62*MB);
  u16* Qh  = (u16*)(ws + 64*MB),  *Ql  = (u16*)(ws + 72*MB);
  u16* Kh  = (u16*)(ws + 80*MB),  *Kl  = (u16*)(ws + 88*MB);
  u16* Kth = (u16*)(ws + 96*MB),  *Ktl = (u16*)(ws + 104*MB);
  u16* Vth = (u16*)(ws + 112*MB), *Vtl = (u16*)(ws + 120*MB);
  u16* Oh = inq_h, *Ol = inq_l;    // reuse: inq dead after proj<0>

  const int n4 = 4096*1024/4;
  k_split_in<<<dim3(2048), dim3(256), 0, stream>>>(query, inq_h, inq_l, n4);
  k_split_in<<<dim3(2048), dim3(256), 0, stream>>>(key,   ink_h, ink_l, n4);
  k_split_in<<<dim3(2048), dim3(256), 0, stream>>>(value, inv_h, inv_l, n4);
  k_wsplit<<<dim3(32,32), dim3(256), 0, stream>>>(Wq, wq_h, wq_l);
  k_wsplit<<<dim3(32,32), dim3(256), 0, stream>>>(Wk, wk_h, wk_l);
  k_wsplit<<<dim3(32,32), dim3(256), 0, stream>>>(Wv, wv_h, wv_l);
  k_wsplit<<<dim3(32,32), dim3(256), 0, stream>>>(Wo, wo_h, wo_l);

  k_proj<0><<<dim3(16,32), dim3(256), 0, stream>>>(inq_h, inq_l, wq_h, wq_l, bq, gamma, beta,
                                                   Qh, Ql, nullptr, nullptr, nullptr);
  k_proj<1><<<dim3(16,32), dim3(256), 0, stream>>>(ink_h, ink_l, wk_h, wk_l, bk, gamma, beta,
                                                   Kh, Kl, Kth, Ktl, nullptr);
  k_proj<2><<<dim3(16,32), dim3(256), 0, stream>>>(inv_h, inv_l, wv_h, wv_l, bv, nullptr, nullptr,
                                                   nullptr, nullptr, Vth, Vtl, nullptr);

  k_hopfield<<<dim3(512), dim3(512), 0, stream>>>(Qh, Ql, Kh, Kth, Ktl, Vth, Vtl, Oh, Ol);

  k_proj<3><<<dim3(16,32), dim3(256), 0, stream>>>(Oh, Ol, wo_h, wo_l, bo, nullptr, nullptr,
                                                   nullptr, nullptr, nullptr, nullptr, out);
}

// Round 8
// 472.361 us; speedup vs baseline: 1.3582x; 1.1059x over previous
//
#include <hip/hip_runtime.h>

typedef unsigned short u16;
typedef __attribute__((ext_vector_type(8))) short bf16x8;
typedef __attribute__((ext_vector_type(4))) float f32x4;
typedef __attribute__((ext_vector_type(4))) u16 u16x4;

#define C1 0.18033688011112042f   // log2(e)/8  (folds the 1/sqrt(64) score scale)

#define GLDS(g, l) __builtin_amdgcn_global_load_lds( \
    (const __attribute__((address_space(1))) void*)(g), \
    (__attribute__((address_space(3))) void*)(l), 16, 0, 0)

__device__ __forceinline__ float fastexp2(float x){
  float r;
  asm("v_exp_f32 %0, %1" : "=v"(r) : "v"(x));
  return r;
}

__device__ __forceinline__ u16 f2bf(float x){
  unsigned u = __float_as_uint(x);
  u += 0x7fffu + ((u >> 16) & 1u);
  return (u16)(u >> 16);
}
__device__ __forceinline__ float bf2f(u16 h){ return __uint_as_float(((unsigned)h) << 16); }
__device__ __forceinline__ void fsplit(float x, u16 &h, u16 &l){
  h = f2bf(x);
  l = f2bf(x - bf2f(h));
}

// RTNE pack of (x0,x1) -> u32 {bf16(x1):bf16(x0)}, plus lo-residual pack.
__device__ __forceinline__ void pksplit(float x0, float x1, unsigned &h, unsigned &l){
  unsigned r0 = __float_as_uint(x0); r0 += 0x7fffu + ((r0 >> 16) & 1u);
  unsigned r1 = __float_as_uint(x1); r1 += 0x7fffu + ((r1 >> 16) & 1u);
  h = (r0 >> 16) | (r1 & 0xffff0000u);
  float y0 = x0 - __uint_as_float(r0 & 0xffff0000u);
  float y1 = x1 - __uint_as_float(r1 & 0xffff0000u);
  unsigned s0 = __float_as_uint(y0); s0 += 0x7fffu + ((s0 >> 16) & 1u);
  unsigned s1 = __float_as_uint(y1); s1 += 0x7fffu + ((s1 >> 16) & 1u);
  l = (s0 >> 16) | (s1 & 0xffff0000u);
}

// hi-only RTNE pack of (x0,x1) -> u32 {bf16(x1):bf16(x0)}.
__device__ __forceinline__ unsigned pkhi(float x0, float x1){
  unsigned r0 = __float_as_uint(x0); r0 += 0x7fffu + ((r0 >> 16) & 1u);
  unsigned r1 = __float_as_uint(x1); r1 += 0x7fffu + ((r1 >> 16) & 1u);
  return (r0 >> 16) | (r1 & 0xffff0000u);
}

// LDS slot swizzle: bank-spread for b128 reads. Bit (r>>3)&1 separates rows
// r and r+8 (same lane cl-group) that the (r&7) XOR alone left colliding.
__device__ __forceinline__ int swz(int slot, int r){
  return slot ^ (r & 7) ^ ((r >> 3) & 1);
}

// Stage a [ROWS][64]-bf16 tile (row = 128B) into LDS with XOR-swizzled 16B slots
// (register-staged variant, used by the projection GEMMs).
template<int ROWS, int NT>
__device__ __forceinline__ void stage_tile(bf16x8* lds, const u16* __restrict__ g,
                                           size_t row0, int ldg, int col0, int tid){
#pragma unroll
  for (int p = 0; p < (ROWS*8)/NT; ++p){
    int idx = tid + p*NT;
    int r = idx >> 3, slot = idx & 7;
    bf16x8 v = *(const bf16x8*)(g + (row0 + (size_t)r)*(size_t)ldg + col0 + slot*8);
    lds[r*8 + swz(slot, r)] = v;
  }
}

__device__ __forceinline__ bf16x8 frag(const bf16x8* lds, int r, int slot){
  return lds[r*8 + swz(slot, r)];
}

// split-bf16 3-term product: X*Y ~= Xh*Yh + Xh*Yl + Xl*Yh   (fp32 accumulate)
__device__ __forceinline__ f32x4 mfma3(bf16x8 xh, bf16x8 xl, bf16x8 yh, bf16x8 yl, f32x4 c){
  c = __builtin_amdgcn_mfma_f32_16x16x32_bf16(xh, yh, c, 0, 0, 0);
  c = __builtin_amdgcn_mfma_f32_16x16x32_bf16(xh, yl, c, 0, 0, 0);
  c = __builtin_amdgcn_mfma_f32_16x16x32_bf16(xl, yh, c, 0, 0, 0);
  return c;
}

// ---- C/D-layout -> B-fragment relayout via 4-lane shuffle --------------------
// Input : lane (cl,gq) holds X[q=cl][u = a*16 + gq*4 + r] as f32 (a=0..3, r=0..3).
// Output: (oh0,ol0) = hi/lo bf16x8 of X[q=cl][u = gq*8 + j], (oh1,ol1) for u=32+...
// Word f=ks*4+c: source lane gq_s = 2*(gq&1)+(c>>1); packed word t = ks*4 +
// 2*(gq>>1) + (c&1) -> shuffle both t0/t0+2 candidates, select by dest gq>>1.
__device__ __forceinline__ void exchange(const f32x4* X, int srcA, int srcB, bool sel_hi,
                                         bf16x8& oh0, bf16x8& oh1, bf16x8& ol0, bf16x8& ol1)
{
  unsigned hi[8], lo[8];
#pragma unroll
  for (int a = 0; a < 4; ++a)
#pragma unroll
    for (int b0 = 0; b0 < 2; ++b0)
      pksplit(X[a][2*b0], X[a][2*b0+1], hi[a*2+b0], lo[a*2+b0]);
  unsigned OH[8], OL[8];
#pragma unroll
  for (int f = 0; f < 8; ++f){
    const int t0 = (f>>2)*4 + (f&1);
    const int sl = ((f&3)>>1) ? srcB : srcA;
    unsigned h0 = (unsigned)__shfl((int)hi[t0],     sl, 64);
    unsigned h2 = (unsigned)__shfl((int)hi[t0 + 2], sl, 64);
    unsigned l0_ = (unsigned)__shfl((int)lo[t0],     sl, 64);
    unsigned l2_ = (unsigned)__shfl((int)lo[t0 + 2], sl, 64);
    OH[f] = sel_hi ? h2 : h0;
    OL[f] = sel_hi ? l2_ : l0_;
  }
  union U { unsigned u[4]; bf16x8 b; };
  U a0, a1, b0_, b1_;
#pragma unroll
  for (int c = 0; c < 4; ++c){ a0.u[c]=OH[c]; a1.u[c]=OH[4+c]; b0_.u[c]=OL[c]; b1_.u[c]=OL[4+c]; }
  oh0=a0.b; oh1=a1.b; ol0=b0_.b; ol1=b1_.b;
}

// hi-only variant (for P: bf16 precision suffices)
__device__ __forceinline__ void exchange_hi(const f32x4* X, int srcA, int srcB, bool sel_hi,
                                            bf16x8& oh0, bf16x8& oh1)
{
  unsigned hi[8];
#pragma unroll
  for (int a = 0; a < 4; ++a)
#pragma unroll
    for (int b0 = 0; b0 < 2; ++b0)
      hi[a*2+b0] = pkhi(X[a][2*b0], X[a][2*b0+1]);
  unsigned OH[8];
#pragma unroll
  for (int f = 0; f < 8; ++f){
    const int t0 = (f>>2)*4 + (f&1);
    const int sl = ((f&3)>>1) ? srcB : srcA;
    unsigned h0 = (unsigned)__shfl((int)hi[t0],     sl, 64);
    unsigned h2 = (unsigned)__shfl((int)hi[t0 + 2], sl, 64);
    OH[f] = sel_hi ? h2 : h0;
  }
  union U { unsigned u[4]; bf16x8 b; };
  U a0, a1;
#pragma unroll
  for (int c = 0; c < 4; ++c){ a0.u[c]=OH[c]; a1.u[c]=OH[4+c]; }
  oh0=a0.b; oh1=a1.b;
}

// ---------------- elementwise split: fp32 -> (hi,lo) bf16 ----------------
__global__ void __launch_bounds__(256) k_split_in(const float* __restrict__ x,
                                                  u16* __restrict__ hh, u16* __restrict__ ll, int n4){
  for (int i = blockIdx.x*256 + threadIdx.x; i < n4; i += gridDim.x*256){
    float4 v = ((const float4*)x)[i];
    float a[4] = {v.x, v.y, v.z, v.w};
    u16x4 h, l;
#pragma unroll
    for (int j = 0; j < 4; ++j){ u16 p, q; fsplit(a[j], p, q); h[j] = p; l[j] = q; }
    *(u16x4*)(hh + (size_t)i*4) = h;
    *(u16x4*)(ll + (size_t)i*4) = l;
  }
}

// ---------------- weight transpose + split: W[k][n] -> Wt[n][k] hi/lo ----------------
__global__ void __launch_bounds__(256) k_wsplit(const float* __restrict__ W,
                                                u16* __restrict__ Th, u16* __restrict__ Tl){
  __shared__ float t[32][33];
  int tx = threadIdx.x & 31, ty = threadIdx.x >> 5;      // 32 x 8
  int n0 = blockIdx.x*32, k0 = blockIdx.y*32;
#pragma unroll
  for (int i = 0; i < 4; ++i)
    t[ty + 8*i][tx] = W[(size_t)(k0 + ty + 8*i)*1024 + n0 + tx];
  __syncthreads();
#pragma unroll
  for (int i = 0; i < 4; ++i){
    int n = n0 + ty + 8*i, k = k0 + tx;
    u16 a, b; fsplit(t[tx][ty + 8*i], a, b);
    Th[(size_t)n*1024 + k] = a;
    Tl[(size_t)n*1024 + k] = b;
  }
}

// ---------------- projection / output GEMM ----------------
// C(4096x1024) = A(4096x1024) * Bt^T (+bias), tile 128x64, 4 waves x (32 rows x 64 cols)
// MODE 0: Q  -> LN, natural head-major split write
// MODE 1: K  -> LN, natural + transposed split writes
// MODE 2: V  -> transposed split write
// MODE 3: out-> fp32 write to d_out
template<int MODE>
__global__ void __launch_bounds__(256, 3) k_proj(
    const u16* __restrict__ Ah, const u16* __restrict__ Al,
    const u16* __restrict__ Bh, const u16* __restrict__ Bl,
    const float* __restrict__ bias, const float* __restrict__ gamma, const float* __restrict__ beta,
    u16* __restrict__ Nh, u16* __restrict__ Nl,
    u16* __restrict__ Th, u16* __restrict__ Tl,
    float* __restrict__ Fo)
{
  __shared__ bf16x8 sAh[128*8], sAl[128*8], sBh[64*8], sBl[64*8];
  const int tid = threadIdx.x, lane = tid & 63, w = tid >> 6;
  const int cl = lane & 15, gq = lane >> 4;
  const int nt = blockIdx.x, mt = blockIdx.y;
  f32x4 acc[2][4] = {};
  for (int kt = 0; kt < 16; ++kt){
    __syncthreads();
    stage_tile<128,256>(sAh, Ah, (size_t)mt*128, 1024, kt*64, tid);
    stage_tile<128,256>(sAl, Al, (size_t)mt*128, 1024, kt*64, tid);
    stage_tile<64,256>(sBh, Bh, (size_t)nt*64, 1024, kt*64, tid);
    stage_tile<64,256>(sBl, Bl, (size_t)nt*64, 1024, kt*64, tid);
    __syncthreads();
#pragma unroll
    for (int ks = 0; ks < 2; ++ks){
      const int slot = ks*4 + gq;
      bf16x8 ah0 = frag(sAh, w*32 + cl, slot);
      bf16x8 al0 = frag(sAl, w*32 + cl, slot);
      bf16x8 ah1 = frag(sAh, w*32 + 16 + cl, slot);
      bf16x8 al1 = frag(sAl, w*32 + 16 + cl, slot);
#pragma unroll
      for (int f = 0; f < 4; ++f){
        bf16x8 bh_ = frag(sBh, f*16 + cl, slot);
        bf16x8 bl_ = frag(sBl, f*16 + cl, slot);
        acc[0][f] = mfma3(ah0, al0, bh_, bl_, acc[0][f]);
        acc[1][f] = mfma3(ah1, al1, bh_, bl_, acc[1][f]);
      }
    }
  }
  float bv[4];
#pragma unroll
  for (int f = 0; f < 4; ++f) bv[f] = bias[nt*64 + f*16 + cl];
  float gm[4], bt[4];
  if constexpr (MODE <= 1){
#pragma unroll
    for (int f = 0; f < 4; ++f){ gm[f] = gamma[f*16 + cl]; bt[f] = beta[f*16 + cl]; }
  }
#pragma unroll
  for (int mi = 0; mi < 2; ++mi){
    float v[4][4];
#pragma unroll
    for (int f = 0; f < 4; ++f)
#pragma unroll
      for (int r = 0; r < 4; ++r) v[f][r] = acc[mi][f][r] + bv[f];
    if constexpr (MODE <= 1){
#pragma unroll
      for (int r = 0; r < 4; ++r){
        float s1 = v[0][r] + v[1][r] + v[2][r] + v[3][r];
        float s2 = v[0][r]*v[0][r] + v[1][r]*v[1][r] + v[2][r]*v[2][r] + v[3][r]*v[3][r];
#pragma unroll
        for (int d = 1; d < 16; d <<= 1){ s1 += __shfl_xor(s1, d); s2 += __shfl_xor(s2, d); }
        float mu = s1 * (1.f/64.f);
        float var = s2 * (1.f/64.f) - mu*mu;
        float rs = rsqrtf(var + 1e-5f);
#pragma unroll
        for (int f = 0; f < 4; ++f) v[f][r] = (v[f][r] - mu)*rs*gm[f] + bt[f];
      }
    }
    const int mrow = mt*128 + w*32 + mi*16 + gq*4;   // + r
    if constexpr (MODE == 3){
#pragma unroll
      for (int f = 0; f < 4; ++f)
#pragma unroll
        for (int r = 0; r < 4; ++r)
          Fo[(size_t)(mrow + r)*1024 + nt*64 + f*16 + cl] = v[f][r];
    } else {
      const int b = mrow >> 11, srow = mrow & 2047;
      const size_t hb = (size_t)(b*16 + nt);          // head-major (b*16 + head)
      if constexpr (MODE <= 1){
#pragma unroll
        for (int f = 0; f < 4; ++f)
#pragma unroll
          for (int r = 0; r < 4; ++r){
            u16 h_, l_; fsplit(v[f][r], h_, l_);
            size_t ix = (hb*2048 + srow + r)*64 + f*16 + cl;
            Nh[ix] = h_; Nl[ix] = l_;
          }
      }
      if constexpr (MODE == 1 || MODE == 2){
#pragma unroll
        for (int f = 0; f < 4; ++f){
          u16x4 h4, l4;
#pragma unroll
          for (int r = 0; r < 4; ++r){ u16 a_, b_; fsplit(v[f][r], a_, b_); h4[r] = a_; l4[r] = b_; }
          size_t ix = (hb*64 + f*16 + cl)*2048 + srow;
          *(u16x4*)(Th + ix) = h4;
          *(u16x4*)(Tl + ix) = l4;
        }
      }
    }
  }
}

// ---------------- fused Hopfield attention: all 4 iterations in one launch ----------------
// Block = 512 thr (8 waves), owns (bh, 128 q rows). Grid 512 = 2 blocks/CU.
// FIXED-MAX softmax (scores in [-64,64] deterministically -> m=64).
// K bf16 hi-only in LDS; P bf16 hi-only. Update iterations (it<3): PV uses
// Kt-hi ONLY (q_new error ~6e-4, second-order on P). Final iteration: full
// V hi/lo for output precision. l accumulated per-lane, reduced per iteration.
__global__ void __launch_bounds__(512, 4) k_hopfield(
    const u16* __restrict__ Qh, const u16* __restrict__ Ql,
    const u16* __restrict__ Kh,
    const u16* __restrict__ Kth,
    const u16* __restrict__ Vth, const u16* __restrict__ Vtl,
    u16* __restrict__ Oh, u16* __restrict__ Ol)
{
  __shared__ bf16x8 sKh[2][512], sTh[2][512], sTl[2][512];
  const int tid = threadIdx.x, lane = tid & 63, w = tid >> 6;
  const int cl = lane & 15, gq = lane >> 4;
  int flat = blockIdx.x;
  flat = (flat & 7)*64 + (flat >> 3);              // XCD swizzle (512 % 8 == 0: bijective)
  const int bh = flat >> 4, qt = flat & 15;
  const size_t base = (size_t)bh * (2048*64);
  const int q = qt*128 + w*16 + cl;

  // staging geometry: thread stages slot idx=tid of each 64x64 tile; source column
  // pre-swizzled so the lane-linear LDS write yields the swizzled layout.
  const int sr = tid >> 3, ss = swz(tid & 7, sr);
  const size_t offK = base + (size_t)sr*64 + ss*8;      // + kt*4096
  const size_t offT = base + (size_t)sr*2048 + ss*8;    // + kt*64
  const int wslot = w << 6;                             // wave's LDS chunk (bf16x8 units)

  // q fragments (B-operand layout), live in registers across all 4 iterations
  bf16x8 qfh[2], qfl[2];
#pragma unroll
  for (int ks = 0; ks < 2; ++ks){
    size_t ix = base + (size_t)q*64 + ks*32 + gq*8;
    qfh[ks] = *(const bf16x8*)(Qh + ix);
    qfl[ks] = *(const bf16x8*)(Ql + ix);
  }

  const int srcA = cl + ((gq & 1) << 5);   // shuffle source lanes for exchange()
  const int srcB = srcA + 16;
  const bool sel_hi = gq >= 2;             // dest-side select: t-offset = 2*(gq>>1)

  float lsum = 0.f;                        // per-lane partial softmax denominator
  f32x4 accO[4] = {};

  // prologue: stage tile 0 (it=0 -> T source is Kt, hi only)
  GLDS(Kh  + offK, &sKh[0][wslot]);
  GLDS(Kth + offT, &sTh[0][wslot]);
  __syncthreads();

  for (int t = 0; t < 128; ++t){
    const int cur = t & 1, kt = t & 31;
    const bool fin = (t >= 96);
    if (t < 127){
      const int nt_ = t + 1, nb = nt_ & 1, nit = nt_ >> 5, nkt = nt_ & 31;
      const size_t oK = offK + (size_t)nkt*4096;
      const size_t oT = offT + (size_t)nkt*64;
      GLDS(Kh + oK, &sKh[nb][wslot]);
      if (nit < 3){
        GLDS(Kth + oT, &sTh[nb][wslot]);
      } else {
        GLDS(Vth + oT, &sTh[nb][wslot]);
        GLDS(Vtl + oT, &sTl[nb][wslot]);
      }
    }
    // ---- QK^T: St[kv][q] = Kh * (Qh + Ql) ----
    f32x4 S[4] = {};
    __builtin_amdgcn_s_setprio(1);
#pragma unroll
    for (int ks = 0; ks < 2; ++ks){
      const int slot = ks*4 + gq;
#pragma unroll
      for (int i = 0; i < 4; ++i){
        bf16x8 kh_ = frag(&sKh[cur][0], i*16 + cl, slot);
        S[i] = __builtin_amdgcn_mfma_f32_16x16x32_bf16(kh_, qfh[ks], S[i], 0, 0, 0);
        S[i] = __builtin_amdgcn_mfma_f32_16x16x32_bf16(kh_, qfl[ks], S[i], 0, 0, 0);
      }
    }
    __builtin_amdgcn_s_setprio(0);
    // ---- fixed-max softmax: p = exp2((S - 64)*C1), no reductions in-tile ----
#pragma unroll
    for (int i = 0; i < 4; ++i)
#pragma unroll
      for (int r = 0; r < 4; ++r){
        float p = fastexp2((S[i][r] - 64.f)*C1);
        S[i][r] = p;
        lsum += p;
      }
    // ---- P: C/D layout -> B-frags (hi-only), in-register ----
    bf16x8 ph0, ph1;
    exchange_hi(S, srcA, srcB, sel_hi, ph0, ph1);
    // ---- PV: O^T += T^T * P^T ----
    __builtin_amdgcn_s_setprio(1);
    if (fin){
#pragma unroll
      for (int ks = 0; ks < 2; ++ks){
        const int slot = ks*4 + gq;
        bf16x8 ph = ks ? ph1 : ph0;
#pragma unroll
        for (int db = 0; db < 4; ++db){
          bf16x8 vh_ = frag(&sTh[cur][0], db*16 + cl, slot);
          bf16x8 vl_ = frag(&sTl[cur][0], db*16 + cl, slot);
          accO[db] = __builtin_amdgcn_mfma_f32_16x16x32_bf16(vh_, ph, accO[db], 0, 0, 0);
          accO[db] = __builtin_amdgcn_mfma_f32_16x16x32_bf16(vl_, ph, accO[db], 0, 0, 0);
        }
      }
    } else {
#pragma unroll
      for (int ks = 0; ks < 2; ++ks){
        const int slot = ks*4 + gq;
        bf16x8 ph = ks ? ph1 : ph0;
#pragma unroll
        for (int db = 0; db < 4; ++db){
          bf16x8 vh_ = frag(&sTh[cur][0], db*16 + cl, slot);
          accO[db] = __builtin_amdgcn_mfma_f32_16x16x32_bf16(vh_, ph, accO[db], 0, 0, 0);
        }
      }
    }
    __builtin_amdgcn_s_setprio(0);
    // ---- iteration epilogue ----
    if (kt == 31){
      float lt = lsum;
      lt += __shfl_xor(lt, 16);
      lt += __shfl_xor(lt, 32);
      const float inv = 1.f / lt;
      f32x4 vals[4];
#pragma unroll
      for (int db = 0; db < 4; ++db)
#pragma unroll
        for (int r = 0; r < 4; ++r) vals[db][r] = accO[db][r]*inv;
      if (t < 127){
        exchange(vals, srcA, srcB, sel_hi, qfh[0], qfh[1], qfl[0], qfl[1]);
        lsum = 0.f;
#pragma unroll
        for (int db = 0; db < 4; ++db) accO[db] = f32x4{0,0,0,0};
      } else {
        const int b = bh >> 4, h = bh & 15;
        const size_t row = (size_t)b*2048 + q;
#pragma unroll
        for (int db = 0; db < 4; ++db){
          u16x4 h4, l4;
#pragma unroll
          for (int r = 0; r < 4; ++r){ u16 a_, b_; fsplit(vals[db][r], a_, b_); h4[r] = a_; l4[r] = b_; }
          size_t ix = row*1024 + h*64 + db*16 + gq*4;
          *(u16x4*)(Oh + ix) = h4;
          *(u16x4*)(Ol + ix) = l4;
        }
      }
    }
    __syncthreads();
  }
}

extern "C" void kernel_launch(void* const* d_in, const int* in_sizes, int n_in,
                              void* d_out, int out_size, void* d_ws, size_t ws_size,
                              hipStream_t stream) {
  (void)in_sizes; (void)n_in; (void)out_size; (void)ws_size;
  const float* query = (const float*)d_in[0];
  const float* key   = (const float*)d_in[1];
  const float* value = (const float*)d_in[2];
  const float* Wq = (const float*)d_in[3];
  const float* bq = (const float*)d_in[4];
  const float* Wk = (const float*)d_in[5];
  const float* bk = (const float*)d_in[6];
  const float* Wv = (const float*)d_in[7];
  const float* bv = (const float*)d_in[8];
  const float* Wo = (const float*)d_in[9];
  const float* bo = (const float*)d_in[10];
  const float* gamma = (const float*)d_in[11];
  const float* beta  = (const float*)d_in[12];
  float* out = (float*)d_out;

  char* ws = (char*)d_ws;
  const size_t MB = 1024*1024;
  u16* inq_h = (u16*)(ws + 0*MB),  *inq_l = (u16*)(ws + 8*MB);
  u16* ink_h = (u16*)(ws + 16*MB), *ink_l = (u16*)(ws + 24*MB);
  u16* inv_h = (u16*)(ws + 32*MB), *inv_l = (u16*)(ws + 40*MB);
  u16* wq_h = (u16*)(ws + 48*MB), *wq_l = (u16*)(ws + 50*MB);
  u16* wk_h = (u16*)(ws + 52*MB), *wk_l = (u16*)(ws + 54*MB);
  u16* wv_h = (u16*)(ws + 56*MB), *wv_l = (u16*)(ws + 58*MB);
  u16* wo_h = (u16*)(ws + 60*MB), *wo_l = (u16*)(ws + 62*MB);
  u16* Qh  = (u16*)(ws + 64*MB),  *Ql  = (u16*)(ws + 72*MB);
  u16* Kh  = (u16*)(ws + 80*MB),  *Kl  = (u16*)(ws + 88*MB);
  u16* Kth = (u16*)(ws + 96*MB),  *Ktl = (u16*)(ws + 104*MB);
  u16* Vth = (u16*)(ws + 112*MB), *Vtl = (u16*)(ws + 120*MB);
  u16* Oh = inq_h, *Ol = inq_l;    // reuse: inq dead after proj<0>

  const int n4 = 4096*1024/4;
  k_split_in<<<dim3(2048), dim3(256), 0, stream>>>(query, inq_h, inq_l, n4);
  k_split_in<<<dim3(2048), dim3(256), 0, stream>>>(key,   ink_h, ink_l, n4);
  k_split_in<<<dim3(2048), dim3(256), 0, stream>>>(value, inv_h, inv_l, n4);
  k_wsplit<<<dim3(32,32), dim3(256), 0, stream>>>(Wq, wq_h, wq_l);
  k_wsplit<<<dim3(32,32), dim3(256), 0, stream>>>(Wk, wk_h, wk_l);
  k_wsplit<<<dim3(32,32), dim3(256), 0, stream>>>(Wv, wv_h, wv_l);
  k_wsplit<<<dim3(32,32), dim3(256), 0, stream>>>(Wo, wo_h, wo_l);

  k_proj<0><<<dim3(16,32), dim3(256), 0, stream>>>(inq_h, inq_l, wq_h, wq_l, bq, gamma, beta,
                                                   Qh, Ql, nullptr, nullptr, nullptr);
  k_proj<1><<<dim3(16,32), dim3(256), 0, stream>>>(ink_h, ink_l, wk_h, wk_l, bk, gamma, beta,
                                                   Kh, Kl, Kth, Ktl, nullptr);
  k_proj<2><<<dim3(16,32), dim3(256), 0, stream>>>(inv_h, inv_l, wv_h, wv_l, bv, nullptr, nullptr,
                                                   nullptr, nullptr, Vth, Vtl, nullptr);

  k_hopfield<<<dim3(512), dim3(512), 0, stream>>>(Qh, Ql, Kh, Kth, Vth, Vtl, Oh, Ol);

  k_proj<3><<<dim3(16,32), dim3(256), 0, stream>>>(Oh, Ol, wo_h, wo_l, bo, nullptr, nullptr,
                                                   nullptr, nullptr, nullptr, nullptr, out);
}

// Round 9
// 437.891 us; speedup vs baseline: 1.4652x; 1.0787x over previous
//
#include <hip/hip_runtime.h>

typedef unsigned short u16;
typedef __attribute__((ext_vector_type(8))) short bf16x8;
typedef __attribute__((ext_vector_type(4))) float f32x4;
typedef __attribute__((ext_vector_type(4))) u16 u16x4;

#define C1 0.18033688011112042f   // log2(e)/8  (folds the 1/sqrt(64) score scale)

#define GLDS(g, l) __builtin_amdgcn_global_load_lds( \
    (const __attribute__((address_space(1))) void*)(g), \
    (__attribute__((address_space(3))) void*)(l), 16, 0, 0)

__device__ __forceinline__ float fastexp2(float x){
  float r;
  asm("v_exp_f32 %0, %1" : "=v"(r) : "v"(x));
  return r;
}

// packed f32x2 -> bf16x2 (low16 = bf16(x0), high16 = bf16(x1)), 1 VALU op
__device__ __forceinline__ unsigned cvtpk(float x0, float x1){
  unsigned r;
  asm("v_cvt_pk_bf16_f32 %0, %1, %2" : "=v"(r) : "v"(x0), "v"(x1));
  return r;
}

__device__ __forceinline__ u16 f2bf(float x){
  unsigned u = __float_as_uint(x);
  u += 0x7fffu + ((u >> 16) & 1u);
  return (u16)(u >> 16);
}
__device__ __forceinline__ float bf2f(u16 h){ return __uint_as_float(((unsigned)h) << 16); }
__device__ __forceinline__ void fsplit(float x, u16 &h, u16 &l){
  h = f2bf(x);
  l = f2bf(x - bf2f(h));
}

// RTNE pack of (x0,x1) -> u32 {bf16(x1):bf16(x0)}, plus lo-residual pack.
__device__ __forceinline__ void pksplit(float x0, float x1, unsigned &h, unsigned &l){
  unsigned r0 = __float_as_uint(x0); r0 += 0x7fffu + ((r0 >> 16) & 1u);
  unsigned r1 = __float_as_uint(x1); r1 += 0x7fffu + ((r1 >> 16) & 1u);
  h = (r0 >> 16) | (r1 & 0xffff0000u);
  float y0 = x0 - __uint_as_float(r0 & 0xffff0000u);
  float y1 = x1 - __uint_as_float(r1 & 0xffff0000u);
  unsigned s0 = __float_as_uint(y0); s0 += 0x7fffu + ((s0 >> 16) & 1u);
  unsigned s1 = __float_as_uint(y1); s1 += 0x7fffu + ((s1 >> 16) & 1u);
  l = (s0 >> 16) | (s1 & 0xffff0000u);
}

// LDS slot swizzle (round 5-7 pattern: empirically the low-conflict one).
__device__ __forceinline__ int swz(int slot, int r){
  return slot ^ (r & 7);
}

// Stage a [ROWS][64]-bf16 tile (row = 128B) into LDS with XOR-swizzled 16B slots
// (register-staged variant, used by the projection GEMMs).
template<int ROWS, int NT>
__device__ __forceinline__ void stage_tile(bf16x8* lds, const u16* __restrict__ g,
                                           size_t row0, int ldg, int col0, int tid){
#pragma unroll
  for (int p = 0; p < (ROWS*8)/NT; ++p){
    int idx = tid + p*NT;
    int r = idx >> 3, slot = idx & 7;
    bf16x8 v = *(const bf16x8*)(g + (row0 + (size_t)r)*(size_t)ldg + col0 + slot*8);
    lds[r*8 + swz(slot, r)] = v;
  }
}

__device__ __forceinline__ bf16x8 frag(const bf16x8* lds, int r, int slot){
  return lds[r*8 + swz(slot, r)];
}

// split-bf16 3-term product: X*Y ~= Xh*Yh + Xh*Yl + Xl*Yh   (fp32 accumulate)
__device__ __forceinline__ f32x4 mfma3(bf16x8 xh, bf16x8 xl, bf16x8 yh, bf16x8 yl, f32x4 c){
  c = __builtin_amdgcn_mfma_f32_16x16x32_bf16(xh, yh, c, 0, 0, 0);
  c = __builtin_amdgcn_mfma_f32_16x16x32_bf16(xh, yl, c, 0, 0, 0);
  c = __builtin_amdgcn_mfma_f32_16x16x32_bf16(xl, yh, c, 0, 0, 0);
  return c;
}

// ---- C/D-layout -> B-fragment relayout via 4-lane shuffle --------------------
// Input : lane (cl,gq) holds X[q=cl][u = a*16 + gq*4 + r] as f32 (a=0..3, r=0..3).
// Output: (oh0,ol0) = hi/lo bf16x8 of X[q=cl][u = gq*8 + j], (oh1,ol1) for u=32+...
// Word f=ks*4+c: source lane gq_s = 2*(gq&1)+(c>>1); packed word t = ks*4 +
// 2*(gq>>1) + (c&1) -> shuffle both t0/t0+2 candidates, select by dest gq>>1.
__device__ __forceinline__ void exchange(const f32x4* X, int srcA, int srcB, bool sel_hi,
                                         bf16x8& oh0, bf16x8& oh1, bf16x8& ol0, bf16x8& ol1)
{
  unsigned hi[8], lo[8];
#pragma unroll
  for (int a = 0; a < 4; ++a)
#pragma unroll
    for (int b0 = 0; b0 < 2; ++b0)
      pksplit(X[a][2*b0], X[a][2*b0+1], hi[a*2+b0], lo[a*2+b0]);
  unsigned OH[8], OL[8];
#pragma unroll
  for (int f = 0; f < 8; ++f){
    const int t0 = (f>>2)*4 + (f&1);
    const int sl = ((f&3)>>1) ? srcB : srcA;
    unsigned h0 = (unsigned)__shfl((int)hi[t0],     sl, 64);
    unsigned h2 = (unsigned)__shfl((int)hi[t0 + 2], sl, 64);
    unsigned l0_ = (unsigned)__shfl((int)lo[t0],     sl, 64);
    unsigned l2_ = (unsigned)__shfl((int)lo[t0 + 2], sl, 64);
    OH[f] = sel_hi ? h2 : h0;
    OL[f] = sel_hi ? l2_ : l0_;
  }
  union U { unsigned u[4]; bf16x8 b; };
  U a0, a1, b0_, b1_;
#pragma unroll
  for (int c = 0; c < 4; ++c){ a0.u[c]=OH[c]; a1.u[c]=OH[4+c]; b0_.u[c]=OL[c]; b1_.u[c]=OL[4+c]; }
  oh0=a0.b; oh1=a1.b; ol0=b0_.b; ol1=b1_.b;
}

// hi-only variant (for P: bf16 precision suffices); cvt_pk = 1 VALU per pair
__device__ __forceinline__ void exchange_hi(const f32x4* X, int srcA, int srcB, bool sel_hi,
                                            bf16x8& oh0, bf16x8& oh1)
{
  unsigned hi[8];
#pragma unroll
  for (int a = 0; a < 4; ++a)
#pragma unroll
    for (int b0 = 0; b0 < 2; ++b0)
      hi[a*2+b0] = cvtpk(X[a][2*b0], X[a][2*b0+1]);
  unsigned OH[8];
#pragma unroll
  for (int f = 0; f < 8; ++f){
    const int t0 = (f>>2)*4 + (f&1);
    const int sl = ((f&3)>>1) ? srcB : srcA;
    unsigned h0 = (unsigned)__shfl((int)hi[t0],     sl, 64);
    unsigned h2 = (unsigned)__shfl((int)hi[t0 + 2], sl, 64);
    OH[f] = sel_hi ? h2 : h0;
  }
  union U { unsigned u[4]; bf16x8 b; };
  U a0, a1;
#pragma unroll
  for (int c = 0; c < 4; ++c){ a0.u[c]=OH[c]; a1.u[c]=OH[4+c]; }
  oh0=a0.b; oh1=a1.b;
}

// ---------------- elementwise split: fp32 -> (hi,lo) bf16 ----------------
__global__ void __launch_bounds__(256) k_split_in(const float* __restrict__ x,
                                                  u16* __restrict__ hh, u16* __restrict__ ll, int n4){
  for (int i = blockIdx.x*256 + threadIdx.x; i < n4; i += gridDim.x*256){
    float4 v = ((const float4*)x)[i];
    float a[4] = {v.x, v.y, v.z, v.w};
    u16x4 h, l;
#pragma unroll
    for (int j = 0; j < 4; ++j){ u16 p, q; fsplit(a[j], p, q); h[j] = p; l[j] = q; }
    *(u16x4*)(hh + (size_t)i*4) = h;
    *(u16x4*)(ll + (size_t)i*4) = l;
  }
}

// ---------------- weight transpose + split: W[k][n] -> Wt[n][k] hi/lo ----------------
__global__ void __launch_bounds__(256) k_wsplit(const float* __restrict__ W,
                                                u16* __restrict__ Th, u16* __restrict__ Tl){
  __shared__ float t[32][33];
  int tx = threadIdx.x & 31, ty = threadIdx.x >> 5;      // 32 x 8
  int n0 = blockIdx.x*32, k0 = blockIdx.y*32;
#pragma unroll
  for (int i = 0; i < 4; ++i)
    t[ty + 8*i][tx] = W[(size_t)(k0 + ty + 8*i)*1024 + n0 + tx];
  __syncthreads();
#pragma unroll
  for (int i = 0; i < 4; ++i){
    int n = n0 + ty + 8*i, k = k0 + tx;
    u16 a, b; fsplit(t[tx][ty + 8*i], a, b);
    Th[(size_t)n*1024 + k] = a;
    Tl[(size_t)n*1024 + k] = b;
  }
}

// ---------------- projection / output GEMM ----------------
// C(4096x1024) = A(4096x1024) * Bt^T (+bias), tile 128x64, 4 waves x (32 rows x 64 cols)
// MODE 0: Q  -> LN, natural head-major split write
// MODE 1: K  -> LN, natural + transposed split writes
// MODE 2: V  -> transposed split write
// MODE 3: out-> fp32 write to d_out
template<int MODE>
__global__ void __launch_bounds__(256, 3) k_proj(
    const u16* __restrict__ Ah, const u16* __restrict__ Al,
    const u16* __restrict__ Bh, const u16* __restrict__ Bl,
    const float* __restrict__ bias, const float* __restrict__ gamma, const float* __restrict__ beta,
    u16* __restrict__ Nh, u16* __restrict__ Nl,
    u16* __restrict__ Th, u16* __restrict__ Tl,
    float* __restrict__ Fo)
{
  __shared__ bf16x8 sAh[128*8], sAl[128*8], sBh[64*8], sBl[64*8];
  const int tid = threadIdx.x, lane = tid & 63, w = tid >> 6;
  const int cl = lane & 15, gq = lane >> 4;
  const int nt = blockIdx.x, mt = blockIdx.y;
  f32x4 acc[2][4] = {};
  for (int kt = 0; kt < 16; ++kt){
    __syncthreads();
    stage_tile<128,256>(sAh, Ah, (size_t)mt*128, 1024, kt*64, tid);
    stage_tile<128,256>(sAl, Al, (size_t)mt*128, 1024, kt*64, tid);
    stage_tile<64,256>(sBh, Bh, (size_t)nt*64, 1024, kt*64, tid);
    stage_tile<64,256>(sBl, Bl, (size_t)nt*64, 1024, kt*64, tid);
    __syncthreads();
#pragma unroll
    for (int ks = 0; ks < 2; ++ks){
      const int slot = ks*4 + gq;
      bf16x8 ah0 = frag(sAh, w*32 + cl, slot);
      bf16x8 al0 = frag(sAl, w*32 + cl, slot);
      bf16x8 ah1 = frag(sAh, w*32 + 16 + cl, slot);
      bf16x8 al1 = frag(sAl, w*32 + 16 + cl, slot);
#pragma unroll
      for (int f = 0; f < 4; ++f){
        bf16x8 bh_ = frag(sBh, f*16 + cl, slot);
        bf16x8 bl_ = frag(sBl, f*16 + cl, slot);
        acc[0][f] = mfma3(ah0, al0, bh_, bl_, acc[0][f]);
        acc[1][f] = mfma3(ah1, al1, bh_, bl_, acc[1][f]);
      }
    }
  }
  float bv[4];
#pragma unroll
  for (int f = 0; f < 4; ++f) bv[f] = bias[nt*64 + f*16 + cl];
  float gm[4], bt[4];
  if constexpr (MODE <= 1){
#pragma unroll
    for (int f = 0; f < 4; ++f){ gm[f] = gamma[f*16 + cl]; bt[f] = beta[f*16 + cl]; }
  }
#pragma unroll
  for (int mi = 0; mi < 2; ++mi){
    float v[4][4];
#pragma unroll
    for (int f = 0; f < 4; ++f)
#pragma unroll
      for (int r = 0; r < 4; ++r) v[f][r] = acc[mi][f][r] + bv[f];
    if constexpr (MODE <= 1){
#pragma unroll
      for (int r = 0; r < 4; ++r){
        float s1 = v[0][r] + v[1][r] + v[2][r] + v[3][r];
        float s2 = v[0][r]*v[0][r] + v[1][r]*v[1][r] + v[2][r]*v[2][r] + v[3][r]*v[3][r];
#pragma unroll
        for (int d = 1; d < 16; d <<= 1){ s1 += __shfl_xor(s1, d); s2 += __shfl_xor(s2, d); }
        float mu = s1 * (1.f/64.f);
        float var = s2 * (1.f/64.f) - mu*mu;
        float rs = rsqrtf(var + 1e-5f);
#pragma unroll
        for (int f = 0; f < 4; ++f) v[f][r] = (v[f][r] - mu)*rs*gm[f] + bt[f];
      }
    }
    const int mrow = mt*128 + w*32 + mi*16 + gq*4;   // + r
    if constexpr (MODE == 3){
#pragma unroll
      for (int f = 0; f < 4; ++f)
#pragma unroll
        for (int r = 0; r < 4; ++r)
          Fo[(size_t)(mrow + r)*1024 + nt*64 + f*16 + cl] = v[f][r];
    } else {
      const int b = mrow >> 11, srow = mrow & 2047;
      const size_t hb = (size_t)(b*16 + nt);          // head-major (b*16 + head)
      if constexpr (MODE <= 1){
#pragma unroll
        for (int f = 0; f < 4; ++f)
#pragma unroll
          for (int r = 0; r < 4; ++r){
            u16 h_, l_; fsplit(v[f][r], h_, l_);
            size_t ix = (hb*2048 + srow + r)*64 + f*16 + cl;
            Nh[ix] = h_; Nl[ix] = l_;
          }
      }
      if constexpr (MODE == 1 || MODE == 2){
#pragma unroll
        for (int f = 0; f < 4; ++f){
          u16x4 h4, l4;
#pragma unroll
          for (int r = 0; r < 4; ++r){ u16 a_, b_; fsplit(v[f][r], a_, b_); h4[r] = a_; l4[r] = b_; }
          size_t ix = (hb*64 + f*16 + cl)*2048 + srow;
          *(u16x4*)(Th + ix) = h4;
          *(u16x4*)(Tl + ix) = l4;
        }
      }
    }
  }
}

// ---------------- fused Hopfield attention: all 4 iterations in one launch ----------------
// Block = 512 thr (8 waves), owns (bh, 128 q rows). Grid 512 = 2 blocks/CU.
// FIXED-MAX softmax (scores in [-64,64] deterministically -> m=64).
// K bf16 hi-only in LDS; P bf16 hi-only. Update iterations (it<3): PV uses
// Kt-hi ONLY (q_new error ~6e-4, second-order on P). Final iteration: full
// V hi/lo for output precision. l accumulated per-lane, reduced per iteration.
__global__ void __launch_bounds__(512, 4) k_hopfield(
    const u16* __restrict__ Qh, const u16* __restrict__ Ql,
    const u16* __restrict__ Kh,
    const u16* __restrict__ Kth,
    const u16* __restrict__ Vth, const u16* __restrict__ Vtl,
    u16* __restrict__ Oh, u16* __restrict__ Ol)
{
  __shared__ bf16x8 sKh[2][512], sTh[2][512], sTl[2][512];
  const int tid = threadIdx.x, lane = tid & 63, w = tid >> 6;
  const int cl = lane & 15, gq = lane >> 4;
  int flat = blockIdx.x;
  flat = (flat & 7)*64 + (flat >> 3);              // XCD swizzle (512 % 8 == 0: bijective)
  const int bh = flat >> 4, qt = flat & 15;
  const size_t base = (size_t)bh * (2048*64);
  const int q = qt*128 + w*16 + cl;

  // staging geometry: thread stages slot idx=tid of each 64x64 tile; source column
  // pre-swizzled so the lane-linear LDS write yields the swizzled layout.
  const int sr = tid >> 3, ss = swz(tid & 7, sr);
  const size_t offK = base + (size_t)sr*64 + ss*8;      // + kt*4096
  const size_t offT = base + (size_t)sr*2048 + ss*8;    // + kt*64
  const int wslot = w << 6;                             // wave's LDS chunk (bf16x8 units)

  // q fragments (B-operand layout), live in registers across all 4 iterations
  bf16x8 qfh[2], qfl[2];
#pragma unroll
  for (int ks = 0; ks < 2; ++ks){
    size_t ix = base + (size_t)q*64 + ks*32 + gq*8;
    qfh[ks] = *(const bf16x8*)(Qh + ix);
    qfl[ks] = *(const bf16x8*)(Ql + ix);
  }

  const int srcA = cl + ((gq & 1) << 5);   // shuffle source lanes for exchange()
  const int srcB = srcA + 16;
  const bool sel_hi = gq >= 2;             // dest-side select: t-offset = 2*(gq>>1)

  float lsum = 0.f;                        // per-lane partial softmax denominator
  f32x4 accO[4] = {};

  // prologue: stage tile 0 (it=0 -> T source is Kt, hi only)
  GLDS(Kh  + offK, &sKh[0][wslot]);
  GLDS(Kth + offT, &sTh[0][wslot]);
  __syncthreads();

  for (int t = 0; t < 128; ++t){
    const int cur = t & 1, kt = t & 31;
    const bool fin = (t >= 96);
    if (t < 127){
      const int nt_ = t + 1, nb = nt_ & 1, nit = nt_ >> 5, nkt = nt_ & 31;
      const size_t oK = offK + (size_t)nkt*4096;
      const size_t oT = offT + (size_t)nkt*64;
      GLDS(Kh + oK, &sKh[nb][wslot]);
      if (nit < 3){
        GLDS(Kth + oT, &sTh[nb][wslot]);
      } else {
        GLDS(Vth + oT, &sTh[nb][wslot]);
        GLDS(Vtl + oT, &sTl[nb][wslot]);
      }
    }
    // ---- QK^T: St[kv][q] = Kh * (Qh + Ql) ----
    f32x4 S[4] = {};
    __builtin_amdgcn_s_setprio(1);
#pragma unroll
    for (int ks = 0; ks < 2; ++ks){
      const int slot = ks*4 + gq;
#pragma unroll
      for (int i = 0; i < 4; ++i){
        bf16x8 kh_ = frag(&sKh[cur][0], i*16 + cl, slot);
        S[i] = __builtin_amdgcn_mfma_f32_16x16x32_bf16(kh_, qfh[ks], S[i], 0, 0, 0);
        S[i] = __builtin_amdgcn_mfma_f32_16x16x32_bf16(kh_, qfl[ks], S[i], 0, 0, 0);
      }
    }
    __builtin_amdgcn_s_setprio(0);
    // ---- fixed-max softmax: p = exp2((S - 64)*C1), no reductions in-tile ----
#pragma unroll
    for (int i = 0; i < 4; ++i)
#pragma unroll
      for (int r = 0; r < 4; ++r){
        float p = fastexp2((S[i][r] - 64.f)*C1);
        S[i][r] = p;
        lsum += p;
      }
    // ---- P: C/D layout -> B-frags (hi-only), in-register ----
    bf16x8 ph0, ph1;
    exchange_hi(S, srcA, srcB, sel_hi, ph0, ph1);
    // ---- PV: O^T += T^T * P^T ----
    __builtin_amdgcn_s_setprio(1);
    if (fin){
#pragma unroll
      for (int ks = 0; ks < 2; ++ks){
        const int slot = ks*4 + gq;
        bf16x8 ph = ks ? ph1 : ph0;
#pragma unroll
        for (int db = 0; db < 4; ++db){
          bf16x8 vh_ = frag(&sTh[cur][0], db*16 + cl, slot);
          bf16x8 vl_ = frag(&sTl[cur][0], db*16 + cl, slot);
          accO[db] = __builtin_amdgcn_mfma_f32_16x16x32_bf16(vh_, ph, accO[db], 0, 0, 0);
          accO[db] = __builtin_amdgcn_mfma_f32_16x16x32_bf16(vl_, ph, accO[db], 0, 0, 0);
        }
      }
    } else {
#pragma unroll
      for (int ks = 0; ks < 2; ++ks){
        const int slot = ks*4 + gq;
        bf16x8 ph = ks ? ph1 : ph0;
#pragma unroll
        for (int db = 0; db < 4; ++db){
          bf16x8 vh_ = frag(&sTh[cur][0], db*16 + cl, slot);
          accO[db] = __builtin_amdgcn_mfma_f32_16x16x32_bf16(vh_, ph, accO[db], 0, 0, 0);
        }
      }
    }
    __builtin_amdgcn_s_setprio(0);
    // ---- iteration epilogue ----
    if (kt == 31){
      float lt = lsum;
      lt += __shfl_xor(lt, 16);
      lt += __shfl_xor(lt, 32);
      const float inv = 1.f / lt;
      f32x4 vals[4];
#pragma unroll
      for (int db = 0; db < 4; ++db)
#pragma unroll
        for (int r = 0; r < 4; ++r) vals[db][r] = accO[db][r]*inv;
      if (t < 127){
        exchange(vals, srcA, srcB, sel_hi, qfh[0], qfh[1], qfl[0], qfl[1]);
        lsum = 0.f;
#pragma unroll
        for (int db = 0; db < 4; ++db) accO[db] = f32x4{0,0,0,0};
      } else {
        const int b = bh >> 4, h = bh & 15;
        const size_t row = (size_t)b*2048 + q;
#pragma unroll
        for (int db = 0; db < 4; ++db){
          u16x4 h4, l4;
#pragma unroll
          for (int r = 0; r < 4; ++r){ u16 a_, b_; fsplit(vals[db][r], a_, b_); h4[r] = a_; l4[r] = b_; }
          size_t ix = row*1024 + h*64 + db*16 + gq*4;
          *(u16x4*)(Oh + ix) = h4;
          *(u16x4*)(Ol + ix) = l4;
        }
      }
    }
    __syncthreads();
  }
}

extern "C" void kernel_launch(void* const* d_in, const int* in_sizes, int n_in,
                              void* d_out, int out_size, void* d_ws, size_t ws_size,
                              hipStream_t stream) {
  (void)in_sizes; (void)n_in; (void)out_size; (void)ws_size;
  const float* query = (const float*)d_in[0];
  const float* key   = (const float*)d_in[1];
  const float* value = (const float*)d_in[2];
  const float* Wq = (const float*)d_in[3];
  const float* bq = (const float*)d_in[4];
  const float* Wk = (const float*)d_in[5];
  const float* bk = (const float*)d_in[6];
  const float* Wv = (const float*)d_in[7];
  const float* bv = (const float*)d_in[8];
  const float* Wo = (const float*)d_in[9];
  const float* bo = (const float*)d_in[10];
  const float* gamma = (const float*)d_in[11];
  const float* beta  = (const float*)d_in[12];
  float* out = (float*)d_out;

  char* ws = (char*)d_ws;
  const size_t MB = 1024*1024;
  u16* inq_h = (u16*)(ws + 0*MB),  *inq_l = (u16*)(ws + 8*MB);
  u16* ink_h = (u16*)(ws + 16*MB), *ink_l = (u16*)(ws + 24*MB);
  u16* inv_h = (u16*)(ws + 32*MB), *inv_l = (u16*)(ws + 40*MB);
  u16* wq_h = (u16*)(ws + 48*MB), *wq_l = (u16*)(ws + 50*MB);
  u16* wk_h = (u16*)(ws + 52*MB), *wk_l = (u16*)(ws + 54*MB);
  u16* wv_h = (u16*)(ws + 56*MB), *wv_l = (u16*)(ws + 58*MB);
  u16* wo_h = (u16*)(ws + 60*MB), *wo_l = (u16*)(ws + 62*MB);
  u16* Qh  = (u16*)(ws + 64*MB),  *Ql  = (u16*)(ws + 72*MB);
  u16* Kh  = (u16*)(ws + 80*MB),  *Kl  = (u16*)(ws + 88*MB);
  u16* Kth = (u16*)(ws + 96*MB),  *Ktl = (u16*)(ws + 104*MB);
  u16* Vth = (u16*)(ws + 112*MB), *Vtl = (u16*)(ws + 120*MB);
  u16* Oh = inq_h, *Ol = inq_l;    // reuse: inq dead after proj<0>

  const int n4 = 4096*1024/4;
  k_split_in<<<dim3(2048), dim3(256), 0, stream>>>(query, inq_h, inq_l, n4);
  k_split_in<<<dim3(2048), dim3(256), 0, stream>>>(key,   ink_h, ink_l, n4);
  k_split_in<<<dim3(2048), dim3(256), 0, stream>>>(value, inv_h, inv_l, n4);
  k_wsplit<<<dim3(32,32), dim3(256), 0, stream>>>(Wq, wq_h, wq_l);
  k_wsplit<<<dim3(32,32), dim3(256), 0, stream>>>(Wk, wk_h, wk_l);
  k_wsplit<<<dim3(32,32), dim3(256), 0, stream>>>(Wv, wv_h, wv_l);
  k_wsplit<<<dim3(32,32), dim3(256), 0, stream>>>(Wo, wo_h, wo_l);

  k_proj<0><<<dim3(16,32), dim3(256), 0, stream>>>(inq_h, inq_l, wq_h, wq_l, bq, gamma, beta,
                                                   Qh, Ql, nullptr, nullptr, nullptr);
  k_proj<1><<<dim3(16,32), dim3(256), 0, stream>>>(ink_h, ink_l, wk_h, wk_l, bk, gamma, beta,
                                                   Kh, Kl, Kth, Ktl, nullptr);
  k_proj<2><<<dim3(16,32), dim3(256), 0, stream>>>(inv_h, inv_l, wv_h, wv_l, bv, nullptr, nullptr,
                                                   nullptr, nullptr, Vth, Vtl, nullptr);

  k_hopfield<<<dim3(512), dim3(512), 0, stream>>>(Qh, Ql, Kh, Kth, Vth, Vtl, Oh, Ol);

  k_proj<3><<<dim3(16,32), dim3(256), 0, stream>>>(Oh, Ol, wo_h, wo_l, bo, nullptr, nullptr,
                                                   nullptr, nullptr, nullptr, nullptr, out);
}

// Round 10
// 428.208 us; speedup vs baseline: 1.4983x; 1.0226x over previous
//
#include <hip/hip_runtime.h>

typedef unsigned short u16;
typedef __attribute__((ext_vector_type(8))) short bf16x8;
typedef __attribute__((ext_vector_type(4))) short bf16x4;
typedef __attribute__((ext_vector_type(4))) float f32x4;
typedef __attribute__((ext_vector_type(4))) u16 u16x4;

#define C1 0.18033688011112042f   // log2(e)/8  (folds the 1/sqrt(64) score scale)

#if __has_builtin(__builtin_amdgcn_mfma_f32_16x16x16bf16_1k)
#define HAVE_MFMA16 1
#else
#define HAVE_MFMA16 0
#endif

#define GLDS(g, l) __builtin_amdgcn_global_load_lds( \
    (const __attribute__((address_space(1))) void*)(g), \
    (__attribute__((address_space(3))) void*)(l), 16, 0, 0)

__device__ __forceinline__ float fastexp2(float x){
  float r;
  asm("v_exp_f32 %0, %1" : "=v"(r) : "v"(x));
  return r;
}

// packed f32x2 -> bf16x2 (low16 = bf16(x0), high16 = bf16(x1)), 1 VALU op
__device__ __forceinline__ unsigned cvtpk(float x0, float x1){
  unsigned r;
  asm("v_cvt_pk_bf16_f32 %0, %1, %2" : "=v"(r) : "v"(x0), "v"(x1));
  return r;
}

__device__ __forceinline__ bf16x4 pk4(float x0, float x1, float x2, float x3){
  union { unsigned u[2]; bf16x4 b; } o;
  o.u[0] = cvtpk(x0, x1);
  o.u[1] = cvtpk(x2, x3);
  return o.b;
}

__device__ __forceinline__ u16 f2bf(float x){
  unsigned u = __float_as_uint(x);
  u += 0x7fffu + ((u >> 16) & 1u);
  return (u16)(u >> 16);
}
__device__ __forceinline__ float bf2f(u16 h){ return __uint_as_float(((unsigned)h) << 16); }
__device__ __forceinline__ void fsplit(float x, u16 &h, u16 &l){
  h = f2bf(x);
  l = f2bf(x - bf2f(h));
}

// RTNE pack of (x0,x1) -> u32 {bf16(x1):bf16(x0)}, plus lo-residual pack.
__device__ __forceinline__ void pksplit(float x0, float x1, unsigned &h, unsigned &l){
  unsigned r0 = __float_as_uint(x0); r0 += 0x7fffu + ((r0 >> 16) & 1u);
  unsigned r1 = __float_as_uint(x1); r1 += 0x7fffu + ((r1 >> 16) & 1u);
  h = (r0 >> 16) | (r1 & 0xffff0000u);
  float y0 = x0 - __uint_as_float(r0 & 0xffff0000u);
  float y1 = x1 - __uint_as_float(r1 & 0xffff0000u);
  unsigned s0 = __float_as_uint(y0); s0 += 0x7fffu + ((s0 >> 16) & 1u);
  unsigned s1 = __float_as_uint(y1); s1 += 0x7fffu + ((s1 >> 16) & 1u);
  l = (s0 >> 16) | (s1 & 0xffff0000u);
}

// LDS slot swizzle (round 5-9 pattern: empirically the low-conflict one).
__device__ __forceinline__ int swz(int slot, int r){
  return slot ^ (r & 7);
}

// Stage a [ROWS][64]-bf16 tile (row = 128B) into LDS with XOR-swizzled 16B slots
// (register-staged variant, used by the projection GEMMs).
template<int ROWS, int NT>
__device__ __forceinline__ void stage_tile(bf16x8* lds, const u16* __restrict__ g,
                                           size_t row0, int ldg, int col0, int tid){
#pragma unroll
  for (int p = 0; p < (ROWS*8)/NT; ++p){
    int idx = tid + p*NT;
    int r = idx >> 3, slot = idx & 7;
    bf16x8 v = *(const bf16x8*)(g + (row0 + (size_t)r)*(size_t)ldg + col0 + slot*8);
    lds[r*8 + swz(slot, r)] = v;
  }
}

__device__ __forceinline__ bf16x8 frag(const bf16x8* lds, int r, int slot){
  return lds[r*8 + swz(slot, r)];
}

// b64 sub-fragment: half (0/1) of the 16B slot -> 4 bf16 (A-operand of 16x16x16)
__device__ __forceinline__ bf16x4 frag64(const bf16x8* lds, int r, int slot, int half){
  return ((const bf16x4*)&lds[r*8 + swz(slot, r)])[half];
}

// split-bf16 3-term product: X*Y ~= Xh*Yh + Xh*Yl + Xl*Yh   (fp32 accumulate)
__device__ __forceinline__ f32x4 mfma3(bf16x8 xh, bf16x8 xl, bf16x8 yh, bf16x8 yl, f32x4 c){
  c = __builtin_amdgcn_mfma_f32_16x16x32_bf16(xh, yh, c, 0, 0, 0);
  c = __builtin_amdgcn_mfma_f32_16x16x32_bf16(xh, yl, c, 0, 0, 0);
  c = __builtin_amdgcn_mfma_f32_16x16x32_bf16(xl, yh, c, 0, 0, 0);
  return c;
}

// ---- C/D-layout -> B-fragment relayout via 4-lane shuffle --------------------
// (used only for the q-rebuild at iteration ends, 4x per kernel)
// Input : lane (cl,gq) holds X[q=cl][u = a*16 + gq*4 + r] as f32 (a=0..3, r=0..3).
// Output: (oh0,ol0) = hi/lo bf16x8 of X[q=cl][u = gq*8 + j], (oh1,ol1) for u=32+...
__device__ __forceinline__ void exchange(const f32x4* X, int srcA, int srcB, bool sel_hi,
                                         bf16x8& oh0, bf16x8& oh1, bf16x8& ol0, bf16x8& ol1)
{
  unsigned hi[8], lo[8];
#pragma unroll
  for (int a = 0; a < 4; ++a)
#pragma unroll
    for (int b0 = 0; b0 < 2; ++b0)
      pksplit(X[a][2*b0], X[a][2*b0+1], hi[a*2+b0], lo[a*2+b0]);
  unsigned OH[8], OL[8];
#pragma unroll
  for (int f = 0; f < 8; ++f){
    const int t0 = (f>>2)*4 + (f&1);
    const int sl = ((f&3)>>1) ? srcB : srcA;
    unsigned h0 = (unsigned)__shfl((int)hi[t0],     sl, 64);
    unsigned h2 = (unsigned)__shfl((int)hi[t0 + 2], sl, 64);
    unsigned l0_ = (unsigned)__shfl((int)lo[t0],     sl, 64);
    unsigned l2_ = (unsigned)__shfl((int)lo[t0 + 2], sl, 64);
    OH[f] = sel_hi ? h2 : h0;
    OL[f] = sel_hi ? l2_ : l0_;
  }
  union U { unsigned u[4]; bf16x8 b; };
  U a0, a1, b0_, b1_;
#pragma unroll
  for (int c = 0; c < 4; ++c){ a0.u[c]=OH[c]; a1.u[c]=OH[4+c]; b0_.u[c]=OL[c]; b1_.u[c]=OL[4+c]; }
  oh0=a0.b; oh1=a1.b; ol0=b0_.b; ol1=b1_.b;
}

#if !HAVE_MFMA16
// hi-only variant (fallback PV path: P bf16, B-frag of 16x16x32)
__device__ __forceinline__ void exchange_hi(const f32x4* X, int srcA, int srcB, bool sel_hi,
                                            bf16x8& oh0, bf16x8& oh1)
{
  unsigned hi[8];
#pragma unroll
  for (int a = 0; a < 4; ++a)
#pragma unroll
    for (int b0 = 0; b0 < 2; ++b0)
      hi[a*2+b0] = cvtpk(X[a][2*b0], X[a][2*b0+1]);
  unsigned OH[8];
#pragma unroll
  for (int f = 0; f < 8; ++f){
    const int t0 = (f>>2)*4 + (f&1);
    const int sl = ((f&3)>>1) ? srcB : srcA;
    unsigned h0 = (unsigned)__shfl((int)hi[t0],     sl, 64);
    unsigned h2 = (unsigned)__shfl((int)hi[t0 + 2], sl, 64);
    OH[f] = sel_hi ? h2 : h0;
  }
  union U { unsigned u[4]; bf16x8 b; };
  U a0, a1;
#pragma unroll
  for (int c = 0; c < 4; ++c){ a0.u[c]=OH[c]; a1.u[c]=OH[4+c]; }
  oh0=a0.b; oh1=a1.b;
}
#endif

// ---------------- elementwise split: fp32 -> (hi,lo) bf16 ----------------
__global__ void __launch_bounds__(256) k_split_in(const float* __restrict__ x,
                                                  u16* __restrict__ hh, u16* __restrict__ ll, int n4){
  for (int i = blockIdx.x*256 + threadIdx.x; i < n4; i += gridDim.x*256){
    float4 v = ((const float4*)x)[i];
    float a[4] = {v.x, v.y, v.z, v.w};
    u16x4 h, l;
#pragma unroll
    for (int j = 0; j < 4; ++j){ u16 p, q; fsplit(a[j], p, q); h[j] = p; l[j] = q; }
    *(u16x4*)(hh + (size_t)i*4) = h;
    *(u16x4*)(ll + (size_t)i*4) = l;
  }
}

// ---------------- weight transpose + split: W[k][n] -> Wt[n][k] hi/lo ----------------
__global__ void __launch_bounds__(256) k_wsplit(const float* __restrict__ W,
                                                u16* __restrict__ Th, u16* __restrict__ Tl){
  __shared__ float t[32][33];
  int tx = threadIdx.x & 31, ty = threadIdx.x >> 5;      // 32 x 8
  int n0 = blockIdx.x*32, k0 = blockIdx.y*32;
#pragma unroll
  for (int i = 0; i < 4; ++i)
    t[ty + 8*i][tx] = W[(size_t)(k0 + ty + 8*i)*1024 + n0 + tx];
  __syncthreads();
#pragma unroll
  for (int i = 0; i < 4; ++i){
    int n = n0 + ty + 8*i, k = k0 + tx;
    u16 a, b; fsplit(t[tx][ty + 8*i], a, b);
    Th[(size_t)n*1024 + k] = a;
    Tl[(size_t)n*1024 + k] = b;
  }
}

// ---------------- projection / output GEMM ----------------
// C(4096x1024) = A(4096x1024) * Bt^T (+bias), tile 128x64, 4 waves x (32 rows x 64 cols)
// MODE 0: Q  -> LN, natural head-major split write
// MODE 1: K  -> LN, natural + transposed split writes
// MODE 2: V  -> transposed split write
// MODE 3: out-> fp32 write to d_out
template<int MODE>
__global__ void __launch_bounds__(256, 3) k_proj(
    const u16* __restrict__ Ah, const u16* __restrict__ Al,
    const u16* __restrict__ Bh, const u16* __restrict__ Bl,
    const float* __restrict__ bias, const float* __restrict__ gamma, const float* __restrict__ beta,
    u16* __restrict__ Nh, u16* __restrict__ Nl,
    u16* __restrict__ Th, u16* __restrict__ Tl,
    float* __restrict__ Fo)
{
  __shared__ bf16x8 sAh[128*8], sAl[128*8], sBh[64*8], sBl[64*8];
  const int tid = threadIdx.x, lane = tid & 63, w = tid >> 6;
  const int cl = lane & 15, gq = lane >> 4;
  const int nt = blockIdx.x, mt = blockIdx.y;
  f32x4 acc[2][4] = {};
  for (int kt = 0; kt < 16; ++kt){
    __syncthreads();
    stage_tile<128,256>(sAh, Ah, (size_t)mt*128, 1024, kt*64, tid);
    stage_tile<128,256>(sAl, Al, (size_t)mt*128, 1024, kt*64, tid);
    stage_tile<64,256>(sBh, Bh, (size_t)nt*64, 1024, kt*64, tid);
    stage_tile<64,256>(sBl, Bl, (size_t)nt*64, 1024, kt*64, tid);
    __syncthreads();
#pragma unroll
    for (int ks = 0; ks < 2; ++ks){
      const int slot = ks*4 + gq;
      bf16x8 ah0 = frag(sAh, w*32 + cl, slot);
      bf16x8 al0 = frag(sAl, w*32 + cl, slot);
      bf16x8 ah1 = frag(sAh, w*32 + 16 + cl, slot);
      bf16x8 al1 = frag(sAl, w*32 + 16 + cl, slot);
#pragma unroll
      for (int f = 0; f < 4; ++f){
        bf16x8 bh_ = frag(sBh, f*16 + cl, slot);
        bf16x8 bl_ = frag(sBl, f*16 + cl, slot);
        acc[0][f] = mfma3(ah0, al0, bh_, bl_, acc[0][f]);
        acc[1][f] = mfma3(ah1, al1, bh_, bl_, acc[1][f]);
      }
    }
  }
  float bv[4];
#pragma unroll
  for (int f = 0; f < 4; ++f) bv[f] = bias[nt*64 + f*16 + cl];
  float gm[4], bt[4];
  if constexpr (MODE <= 1){
#pragma unroll
    for (int f = 0; f < 4; ++f){ gm[f] = gamma[f*16 + cl]; bt[f] = beta[f*16 + cl]; }
  }
#pragma unroll
  for (int mi = 0; mi < 2; ++mi){
    float v[4][4];
#pragma unroll
    for (int f = 0; f < 4; ++f)
#pragma unroll
      for (int r = 0; r < 4; ++r) v[f][r] = acc[mi][f][r] + bv[f];
    if constexpr (MODE <= 1){
#pragma unroll
      for (int r = 0; r < 4; ++r){
        float s1 = v[0][r] + v[1][r] + v[2][r] + v[3][r];
        float s2 = v[0][r]*v[0][r] + v[1][r]*v[1][r] + v[2][r]*v[2][r] + v[3][r]*v[3][r];
#pragma unroll
        for (int d = 1; d < 16; d <<= 1){ s1 += __shfl_xor(s1, d); s2 += __shfl_xor(s2, d); }
        float mu = s1 * (1.f/64.f);
        float var = s2 * (1.f/64.f) - mu*mu;
        float rs = rsqrtf(var + 1e-5f);
#pragma unroll
        for (int f = 0; f < 4; ++f) v[f][r] = (v[f][r] - mu)*rs*gm[f] + bt[f];
      }
    }
    const int mrow = mt*128 + w*32 + mi*16 + gq*4;   // + r
    if constexpr (MODE == 3){
#pragma unroll
      for (int f = 0; f < 4; ++f)
#pragma unroll
        for (int r = 0; r < 4; ++r)
          Fo[(size_t)(mrow + r)*1024 + nt*64 + f*16 + cl] = v[f][r];
    } else {
      const int b = mrow >> 11, srow = mrow & 2047;
      const size_t hb = (size_t)(b*16 + nt);          // head-major (b*16 + head)
      if constexpr (MODE <= 1){
#pragma unroll
        for (int f = 0; f < 4; ++f)
#pragma unroll
          for (int r = 0; r < 4; ++r){
            u16 h_, l_; fsplit(v[f][r], h_, l_);
            size_t ix = (hb*2048 + srow + r)*64 + f*16 + cl;
            Nh[ix] = h_; Nl[ix] = l_;
          }
      }
      if constexpr (MODE == 1 || MODE == 2){
#pragma unroll
        for (int f = 0; f < 4; ++f){
          u16x4 h4, l4;
#pragma unroll
          for (int r = 0; r < 4; ++r){ u16 a_, b_; fsplit(v[f][r], a_, b_); h4[r] = a_; l4[r] = b_; }
          size_t ix = (hb*64 + f*16 + cl)*2048 + srow;
          *(u16x4*)(Th + ix) = h4;
          *(u16x4*)(Tl + ix) = l4;
        }
      }
    }
  }
}

// ---------------- fused Hopfield attention: all 4 iterations in one launch ----------------
// Block = 512 thr (8 waves), owns (bh, 128 q rows). Grid 512 = 2 blocks/CU.
// FIXED-MAX softmax (scores in [-64,64] deterministically -> m=64).
// K bf16 hi-only in LDS; P bf16 hi-only. PV uses 16x16x16 MFMA: the QK C/D
// layout (lane holds P[kv=a*16+gq*4+r][q=cl]) IS the native K=16 B-fragment
// (k = gq*4+e) -> NO cross-lane P relayout. T-operand read as b64 sub-frags:
// kv = (2a+(gq>>1))*8 + (gq&1)*4 + e == 16a + gq*4 + e.
// Update iters (it<3): PV on Kt-hi only. Final: full V hi/lo.
__global__ void __launch_bounds__(512, 4) k_hopfield(
    const u16* __restrict__ Qh, const u16* __restrict__ Ql,
    const u16* __restrict__ Kh,
    const u16* __restrict__ Kth,
    const u16* __restrict__ Vth, const u16* __restrict__ Vtl,
    u16* __restrict__ Oh, u16* __restrict__ Ol)
{
  __shared__ bf16x8 sKh[2][512], sTh[2][512], sTl[2][512];
  const int tid = threadIdx.x, lane = tid & 63, w = tid >> 6;
  const int cl = lane & 15, gq = lane >> 4;
  int flat = blockIdx.x;
  flat = (flat & 7)*64 + (flat >> 3);              // XCD swizzle (512 % 8 == 0: bijective)
  const int bh = flat >> 4, qt = flat & 15;
  const size_t base = (size_t)bh * (2048*64);
  const int q = qt*128 + w*16 + cl;

  // staging geometry: thread stages slot idx=tid of each 64x64 tile; source column
  // pre-swizzled so the lane-linear LDS write yields the swizzled layout.
  const int sr = tid >> 3, ss = swz(tid & 7, sr);
  const size_t offK = base + (size_t)sr*64 + ss*8;      // + kt*4096
  const size_t offT = base + (size_t)sr*2048 + ss*8;    // + kt*64
  const int wslot = w << 6;                             // wave's LDS chunk (bf16x8 units)

  // q fragments (B-operand layout), live in registers across all 4 iterations
  bf16x8 qfh[2], qfl[2];
#pragma unroll
  for (int ks = 0; ks < 2; ++ks){
    size_t ix = base + (size_t)q*64 + ks*32 + gq*8;
    qfh[ks] = *(const bf16x8*)(Qh + ix);
    qfl[ks] = *(const bf16x8*)(Ql + ix);
  }

  const int srcA = cl + ((gq & 1) << 5);   // shuffle source lanes for exchange()
  const int srcB = srcA + 16;
  const bool sel_hi = gq >= 2;             // dest-side select: t-offset = 2*(gq>>1)

  float lsum = 0.f;                        // per-lane partial softmax denominator
  f32x4 accO[4] = {};

  // prologue: stage tile 0 (it=0 -> T source is Kt, hi only)
  GLDS(Kh  + offK, &sKh[0][wslot]);
  GLDS(Kth + offT, &sTh[0][wslot]);
  __syncthreads();

  for (int t = 0; t < 128; ++t){
    const int cur = t & 1, kt = t & 31;
    const bool fin = (t >= 96);
    if (t < 127){
      const int nt_ = t + 1, nb = nt_ & 1, nit = nt_ >> 5, nkt = nt_ & 31;
      const size_t oK = offK + (size_t)nkt*4096;
      const size_t oT = offT + (size_t)nkt*64;
      GLDS(Kh + oK, &sKh[nb][wslot]);
      if (nit < 3){
        GLDS(Kth + oT, &sTh[nb][wslot]);
      } else {
        GLDS(Vth + oT, &sTh[nb][wslot]);
        GLDS(Vtl + oT, &sTl[nb][wslot]);
      }
    }
    // ---- QK^T: St[kv][q] = Kh * (Qh + Ql) ----
    f32x4 S[4] = {};
    __builtin_amdgcn_s_setprio(1);
#pragma unroll
    for (int ks = 0; ks < 2; ++ks){
      const int slot = ks*4 + gq;
#pragma unroll
      for (int i = 0; i < 4; ++i){
        bf16x8 kh_ = frag(&sKh[cur][0], i*16 + cl, slot);
        S[i] = __builtin_amdgcn_mfma_f32_16x16x32_bf16(kh_, qfh[ks], S[i], 0, 0, 0);
        S[i] = __builtin_amdgcn_mfma_f32_16x16x32_bf16(kh_, qfl[ks], S[i], 0, 0, 0);
      }
    }
    __builtin_amdgcn_s_setprio(0);
    // ---- fixed-max softmax: p = exp2((S - 64)*C1), no reductions in-tile ----
#pragma unroll
    for (int i = 0; i < 4; ++i)
#pragma unroll
      for (int r = 0; r < 4; ++r){
        float p = fastexp2((S[i][r] - 64.f)*C1);
        S[i][r] = p;
        lsum += p;
      }
#if HAVE_MFMA16
    // ---- P already in native 16x16x16 B-frag layout: pack only ----
    bf16x4 pf[4];
#pragma unroll
    for (int a = 0; a < 4; ++a)
      pf[a] = pk4(S[a][0], S[a][1], S[a][2], S[a][3]);
    // ---- PV: O^T += T^T * P^T via 16x16x16, b64 T-subfrags ----
    __builtin_amdgcn_s_setprio(1);
    if (fin){
#pragma unroll
      for (int db = 0; db < 4; ++db)
#pragma unroll
        for (int a = 0; a < 4; ++a){
          bf16x4 vh_ = frag64(&sTh[cur][0], db*16 + cl, 2*a + (gq>>1), gq&1);
          bf16x4 vl_ = frag64(&sTl[cur][0], db*16 + cl, 2*a + (gq>>1), gq&1);
          accO[db] = __builtin_amdgcn_mfma_f32_16x16x16bf16_1k(vh_, pf[a], accO[db], 0, 0, 0);
          accO[db] = __builtin_amdgcn_mfma_f32_16x16x16bf16_1k(vl_, pf[a], accO[db], 0, 0, 0);
        }
    } else {
#pragma unroll
      for (int db = 0; db < 4; ++db)
#pragma unroll
        for (int a = 0; a < 4; ++a){
          bf16x4 vh_ = frag64(&sTh[cur][0], db*16 + cl, 2*a + (gq>>1), gq&1);
          accO[db] = __builtin_amdgcn_mfma_f32_16x16x16bf16_1k(vh_, pf[a], accO[db], 0, 0, 0);
        }
    }
    __builtin_amdgcn_s_setprio(0);
#else
    // ---- fallback: shuffle P into 16x16x32 B-frags ----
    bf16x8 ph0, ph1;
    exchange_hi(S, srcA, srcB, sel_hi, ph0, ph1);
    __builtin_amdgcn_s_setprio(1);
#pragma unroll
    for (int ks = 0; ks < 2; ++ks){
      const int slot = ks*4 + gq;
      bf16x8 ph = ks ? ph1 : ph0;
#pragma unroll
      for (int db = 0; db < 4; ++db){
        bf16x8 vh_ = frag(&sTh[cur][0], db*16 + cl, slot);
        accO[db] = __builtin_amdgcn_mfma_f32_16x16x32_bf16(vh_, ph, accO[db], 0, 0, 0);
        if (fin){
          bf16x8 vl_ = frag(&sTl[cur][0], db*16 + cl, slot);
          accO[db] = __builtin_amdgcn_mfma_f32_16x16x32_bf16(vl_, ph, accO[db], 0, 0, 0);
        }
      }
    }
    __builtin_amdgcn_s_setprio(0);
#endif
    // ---- iteration epilogue ----
    if (kt == 31){
      float lt = lsum;
      lt += __shfl_xor(lt, 16);
      lt += __shfl_xor(lt, 32);
      const float inv = 1.f / lt;
      f32x4 vals[4];
#pragma unroll
      for (int db = 0; db < 4; ++db)
#pragma unroll
        for (int r = 0; r < 4; ++r) vals[db][r] = accO[db][r]*inv;
      if (t < 127){
        exchange(vals, srcA, srcB, sel_hi, qfh[0], qfh[1], qfl[0], qfl[1]);
        lsum = 0.f;
#pragma unroll
        for (int db = 0; db < 4; ++db) accO[db] = f32x4{0,0,0,0};
      } else {
        const int b = bh >> 4, h = bh & 15;
        const size_t row = (size_t)b*2048 + q;
#pragma unroll
        for (int db = 0; db < 4; ++db){
          u16x4 h4, l4;
#pragma unroll
          for (int r = 0; r < 4; ++r){ u16 a_, b_; fsplit(vals[db][r], a_, b_); h4[r] = a_; l4[r] = b_; }
          size_t ix = row*1024 + h*64 + db*16 + gq*4;
          *(u16x4*)(Oh + ix) = h4;
          *(u16x4*)(Ol + ix) = l4;
        }
      }
    }
    __syncthreads();
  }
}

extern "C" void kernel_launch(void* const* d_in, const int* in_sizes, int n_in,
                              void* d_out, int out_size, void* d_ws, size_t ws_size,
                              hipStream_t stream) {
  (void)in_sizes; (void)n_in; (void)out_size; (void)ws_size;
  const float* query = (const float*)d_in[0];
  const float* key   = (const float*)d_in[1];
  const float* value = (const float*)d_in[2];
  const float* Wq = (const float*)d_in[3];
  const float* bq = (const float*)d_in[4];
  const float* Wk = (const float*)d_in[5];
  const float* bk = (const float*)d_in[6];
  const float* Wv = (const float*)d_in[7];
  const float* bv = (const float*)d_in[8];
  const float* Wo = (const float*)d_in[9];
  const float* bo = (const float*)d_in[10];
  const float* gamma = (const float*)d_in[11];
  const float* beta  = (const float*)d_in[12];
  float* out = (float*)d_out;

  char* ws = (char*)d_ws;
  const size_t MB = 1024*1024;
  u16* inq_h = (u16*)(ws + 0*MB),  *inq_l = (u16*)(ws + 8*MB);
  u16* ink_h = (u16*)(ws + 16*MB), *ink_l = (u16*)(ws + 24*MB);
  u16* inv_h = (u16*)(ws + 32*MB), *inv_l = (u16*)(ws + 40*MB);
  u16* wq_h = (u16*)(ws + 48*MB), *wq_l = (u16*)(ws + 50*MB);
  u16* wk_h = (u16*)(ws + 52*MB), *wk_l = (u16*)(ws + 54*MB);
  u16* wv_h = (u16*)(ws + 56*MB), *wv_l = (u16*)(ws + 58*MB);
  u16* wo_h = (u16*)(ws + 60*MB), *wo_l = (u16*)(ws + 62*MB);
  u16* Qh  = (u16*)(ws + 64*MB),  *Ql  = (u16*)(ws + 72*MB);
  u16* Kh  = (u16*)(ws + 80*MB),  *Kl  = (u16*)(ws + 88*MB);
  u16* Kth = (u16*)(ws + 96*MB),  *Ktl = (u16*)(ws + 104*MB);
  u16* Vth = (u16*)(ws + 112*MB), *Vtl = (u16*)(ws + 120*MB);
  u16* Oh = inq_h, *Ol = inq_l;    // reuse: inq dead after proj<0>

  const int n4 = 4096*1024/4;
  k_split_in<<<dim3(2048), dim3(256), 0, stream>>>(query, inq_h, inq_l, n4);
  k_split_in<<<dim3(2048), dim3(256), 0, stream>>>(key,   ink_h, ink_l, n4);
  k_split_in<<<dim3(2048), dim3(256), 0, stream>>>(value, inv_h, inv_l, n4);
  k_wsplit<<<dim3(32,32), dim3(256), 0, stream>>>(Wq, wq_h, wq_l);
  k_wsplit<<<dim3(32,32), dim3(256), 0, stream>>>(Wk, wk_h, wk_l);
  k_wsplit<<<dim3(32,32), dim3(256), 0, stream>>>(Wv, wv_h, wv_l);
  k_wsplit<<<dim3(32,32), dim3(256), 0, stream>>>(Wo, wo_h, wo_l);

  k_proj<0><<<dim3(16,32), dim3(256), 0, stream>>>(inq_h, inq_l, wq_h, wq_l, bq, gamma, beta,
                                                   Qh, Ql, nullptr, nullptr, nullptr);
  k_proj<1><<<dim3(16,32), dim3(256), 0, stream>>>(ink_h, ink_l, wk_h, wk_l, bk, gamma, beta,
                                                   Kh, Kl, Kth, Ktl, nullptr);
  k_proj<2><<<dim3(16,32), dim3(256), 0, stream>>>(inv_h, inv_l, wv_h, wv_l, bv, nullptr, nullptr,
                                                   nullptr, nullptr, Vth, Vtl, nullptr);

  k_hopfield<<<dim3(512), dim3(512), 0, stream>>>(Qh, Ql, Kh, Kth, Vth, Vtl, Oh, Ol);

  k_proj<3><<<dim3(16,32), dim3(256), 0, stream>>>(Oh, Ol, wo_h, wo_l, bo, nullptr, nullptr,
                                                   nullptr, nullptr, nullptr, nullptr, out);
}

// Round 11
// 410.959 us; speedup vs baseline: 1.5612x; 1.0420x over previous
//
#include <hip/hip_runtime.h>

typedef unsigned short u16;
typedef __attribute__((ext_vector_type(8))) short bf16x8;
typedef __attribute__((ext_vector_type(4))) short bf16x4;
typedef __attribute__((ext_vector_type(4))) float f32x4;
typedef __attribute__((ext_vector_type(4))) u16 u16x4;

#define C1 0.18033688011112042f   // log2(e)/8  (folds the 1/sqrt(64) score scale)

#define GLDS(g, l) __builtin_amdgcn_global_load_lds( \
    (const __attribute__((address_space(1))) void*)(g), \
    (__attribute__((address_space(3))) void*)(l), 16, 0, 0)

__device__ __forceinline__ float fastexp2(float x){
  float r;
  asm("v_exp_f32 %0, %1" : "=v"(r) : "v"(x));
  return r;
}

// packed f32x2 -> bf16x2 (low16 = bf16(x0), high16 = bf16(x1)), 1 VALU op
__device__ __forceinline__ unsigned cvtpk(float x0, float x1){
  unsigned r;
  asm("v_cvt_pk_bf16_f32 %0, %1, %2" : "=v"(r) : "v"(x0), "v"(x1));
  return r;
}

__device__ __forceinline__ bf16x4 pk4(float x0, float x1, float x2, float x3){
  union { unsigned u[2]; bf16x4 b; } o;
  o.u[0] = cvtpk(x0, x1);
  o.u[1] = cvtpk(x2, x3);
  return o.b;
}

__device__ __forceinline__ u16 f2bf(float x){
  unsigned u = __float_as_uint(x);
  u += 0x7fffu + ((u >> 16) & 1u);
  return (u16)(u >> 16);
}
__device__ __forceinline__ float bf2f(u16 h){ return __uint_as_float(((unsigned)h) << 16); }
__device__ __forceinline__ void fsplit(float x, u16 &h, u16 &l){
  h = f2bf(x);
  l = f2bf(x - bf2f(h));
}

// RTNE pack of (x0,x1) -> u32 {bf16(x1):bf16(x0)}, plus lo-residual pack.
__device__ __forceinline__ void pksplit(float x0, float x1, unsigned &h, unsigned &l){
  unsigned r0 = __float_as_uint(x0); r0 += 0x7fffu + ((r0 >> 16) & 1u);
  unsigned r1 = __float_as_uint(x1); r1 += 0x7fffu + ((r1 >> 16) & 1u);
  h = (r0 >> 16) | (r1 & 0xffff0000u);
  float y0 = x0 - __uint_as_float(r0 & 0xffff0000u);
  float y1 = x1 - __uint_as_float(r1 & 0xffff0000u);
  unsigned s0 = __float_as_uint(y0); s0 += 0x7fffu + ((s0 >> 16) & 1u);
  unsigned s1 = __float_as_uint(y1); s1 += 0x7fffu + ((s1 >> 16) & 1u);
  l = (s0 >> 16) | (s1 & 0xffff0000u);
}

// LDS slot swizzle (involution per row; empirically the low-conflict pattern).
__device__ __forceinline__ int swz(int slot, int r){
  return slot ^ (r & 7);
}

__device__ __forceinline__ bf16x8 frag(const bf16x8* lds, int r, int slot){
  return lds[r*8 + swz(slot, r)];
}

// b64 sub-fragment (A-operand of 16x16x16). Data is stored half-swapped by
// row-bit-3 (see k_proj T-writes) so quarter-wave lanes cover all 32 banks.
__device__ __forceinline__ bf16x4 frag64(const bf16x8* lds, int r, int slot, int half){
  return ((const bf16x4*)&lds[r*8 + swz(slot, r)])[half ^ ((r >> 3) & 1)];
}

// GLDS tile staging: linear LDS dest (wave chunk + lane*16), inverse-swizzled
// global source column -> LDS position swz(c) holds data column c (rule #21).
template<int ROWS>
__device__ __forceinline__ void stage_glds(bf16x8* lds, const u16* __restrict__ g,
                                           size_t row0, int ldg, int col0, int tid, int w){
#pragma unroll
  for (int p = 0; p < ROWS/32; ++p){
    int idx = p*256 + tid;
    int r = idx >> 3, slot = idx & 7;
    int ss = swz(slot, r);
    GLDS(g + (row0 + (size_t)r)*(size_t)ldg + col0 + ss*8, &lds[p*256 + (w<<6)]);
  }
}

// split-bf16 3-term product: X*Y ~= Xh*Yh + Xh*Yl + Xl*Yh   (fp32 accumulate)
__device__ __forceinline__ f32x4 mfma3(bf16x8 xh, bf16x8 xl, bf16x8 yh, bf16x8 yl, f32x4 c){
  c = __builtin_amdgcn_mfma_f32_16x16x32_bf16(xh, yh, c, 0, 0, 0);
  c = __builtin_amdgcn_mfma_f32_16x16x32_bf16(xh, yl, c, 0, 0, 0);
  c = __builtin_amdgcn_mfma_f32_16x16x32_bf16(xl, yh, c, 0, 0, 0);
  return c;
}

// ---- C/D-layout -> B-fragment relayout via 4-lane shuffle --------------------
// (used only for the q-rebuild at iteration ends, 4x per kernel)
__device__ __forceinline__ void exchange(const f32x4* X, int srcA, int srcB, bool sel_hi,
                                         bf16x8& oh0, bf16x8& oh1, bf16x8& ol0, bf16x8& ol1)
{
  unsigned hi[8], lo[8];
#pragma unroll
  for (int a = 0; a < 4; ++a)
#pragma unroll
    for (int b0 = 0; b0 < 2; ++b0)
      pksplit(X[a][2*b0], X[a][2*b0+1], hi[a*2+b0], lo[a*2+b0]);
  unsigned OH[8], OL[8];
#pragma unroll
  for (int f = 0; f < 8; ++f){
    const int t0 = (f>>2)*4 + (f&1);
    const int sl = ((f&3)>>1) ? srcB : srcA;
    unsigned h0 = (unsigned)__shfl((int)hi[t0],     sl, 64);
    unsigned h2 = (unsigned)__shfl((int)hi[t0 + 2], sl, 64);
    unsigned l0_ = (unsigned)__shfl((int)lo[t0],     sl, 64);
    unsigned l2_ = (unsigned)__shfl((int)lo[t0 + 2], sl, 64);
    OH[f] = sel_hi ? h2 : h0;
    OL[f] = sel_hi ? l2_ : l0_;
  }
  union U { unsigned u[4]; bf16x8 b; };
  U a0, a1, b0_, b1_;
#pragma unroll
  for (int c = 0; c < 4; ++c){ a0.u[c]=OH[c]; a1.u[c]=OH[4+c]; b0_.u[c]=OL[c]; b1_.u[c]=OL[4+c]; }
  oh0=a0.b; oh1=a1.b; ol0=b0_.b; ol1=b1_.b;
}

// ---------------- elementwise split: fp32 -> (hi,lo) bf16 ----------------
__global__ void __launch_bounds__(256) k_split_in(const float* __restrict__ x,
                                                  u16* __restrict__ hh, u16* __restrict__ ll, int n4){
  for (int i = blockIdx.x*256 + threadIdx.x; i < n4; i += gridDim.x*256){
    float4 v = ((const float4*)x)[i];
    float a[4] = {v.x, v.y, v.z, v.w};
    u16x4 h, l;
#pragma unroll
    for (int j = 0; j < 4; ++j){ u16 p, q; fsplit(a[j], p, q); h[j] = p; l[j] = q; }
    *(u16x4*)(hh + (size_t)i*4) = h;
    *(u16x4*)(ll + (size_t)i*4) = l;
  }
}

// ---------------- weight transpose + split: W[k][n] -> Wt[n][k] hi/lo ----------------
__global__ void __launch_bounds__(256) k_wsplit(const float* __restrict__ W,
                                                u16* __restrict__ Th, u16* __restrict__ Tl){
  __shared__ float t[32][33];
  int tx = threadIdx.x & 31, ty = threadIdx.x >> 5;      // 32 x 8
  int n0 = blockIdx.x*32, k0 = blockIdx.y*32;
#pragma unroll
  for (int i = 0; i < 4; ++i)
    t[ty + 8*i][tx] = W[(size_t)(k0 + ty + 8*i)*1024 + n0 + tx];
  __syncthreads();
#pragma unroll
  for (int i = 0; i < 4; ++i){
    int n = n0 + ty + 8*i, k = k0 + tx;
    u16 a, b; fsplit(t[tx][ty + 8*i], a, b);
    Th[(size_t)n*1024 + k] = a;
    Tl[(size_t)n*1024 + k] = b;
  }
}

// ---------------- projection / output GEMM ----------------
// C(4096x1024) = A(4096x1024) * Bt^T (+bias), tile 128x64, 4 waves x (32 rows x 64 cols)
// Staging via global_load_lds (linear dest + inverse-swizzled source).
// MODE 0: Q  -> LN, natural head-major split write
// MODE 1: K  -> LN, natural + transposed split writes (T half-swapped by kv bit 2)
// MODE 2: V  -> transposed split write (half-swapped)
// MODE 3: out-> fp32 write to d_out
template<int MODE>
__global__ void __launch_bounds__(256, 3) k_proj(
    const u16* __restrict__ Ah, const u16* __restrict__ Al,
    const u16* __restrict__ Bh, const u16* __restrict__ Bl,
    const float* __restrict__ bias, const float* __restrict__ gamma, const float* __restrict__ beta,
    u16* __restrict__ Nh, u16* __restrict__ Nl,
    u16* __restrict__ Th, u16* __restrict__ Tl,
    float* __restrict__ Fo)
{
  __shared__ bf16x8 sAh[128*8], sAl[128*8], sBh[64*8], sBl[64*8];
  const int tid = threadIdx.x, lane = tid & 63, w = tid >> 6;
  const int cl = lane & 15, gq = lane >> 4;
  const int nt = blockIdx.x, mt = blockIdx.y;
  f32x4 acc[2][4] = {};
  for (int kt = 0; kt < 16; ++kt){
    __syncthreads();
    stage_glds<128>(sAh, Ah, (size_t)mt*128, 1024, kt*64, tid, w);
    stage_glds<128>(sAl, Al, (size_t)mt*128, 1024, kt*64, tid, w);
    stage_glds<64>(sBh, Bh, (size_t)nt*64, 1024, kt*64, tid, w);
    stage_glds<64>(sBl, Bl, (size_t)nt*64, 1024, kt*64, tid, w);
    __syncthreads();
#pragma unroll
    for (int ks = 0; ks < 2; ++ks){
      const int slot = ks*4 + gq;
      bf16x8 ah0 = frag(sAh, w*32 + cl, slot);
      bf16x8 al0 = frag(sAl, w*32 + cl, slot);
      bf16x8 ah1 = frag(sAh, w*32 + 16 + cl, slot);
      bf16x8 al1 = frag(sAl, w*32 + 16 + cl, slot);
#pragma unroll
      for (int f = 0; f < 4; ++f){
        bf16x8 bh_ = frag(sBh, f*16 + cl, slot);
        bf16x8 bl_ = frag(sBl, f*16 + cl, slot);
        acc[0][f] = mfma3(ah0, al0, bh_, bl_, acc[0][f]);
        acc[1][f] = mfma3(ah1, al1, bh_, bl_, acc[1][f]);
      }
    }
  }
  float bv[4];
#pragma unroll
  for (int f = 0; f < 4; ++f) bv[f] = bias[nt*64 + f*16 + cl];
  float gm[4], bt[4];
  if constexpr (MODE <= 1){
#pragma unroll
    for (int f = 0; f < 4; ++f){ gm[f] = gamma[f*16 + cl]; bt[f] = beta[f*16 + cl]; }
  }
#pragma unroll
  for (int mi = 0; mi < 2; ++mi){
    float v[4][4];
#pragma unroll
    for (int f = 0; f < 4; ++f)
#pragma unroll
      for (int r = 0; r < 4; ++r) v[f][r] = acc[mi][f][r] + bv[f];
    if constexpr (MODE <= 1){
#pragma unroll
      for (int r = 0; r < 4; ++r){
        float s1 = v[0][r] + v[1][r] + v[2][r] + v[3][r];
        float s2 = v[0][r]*v[0][r] + v[1][r]*v[1][r] + v[2][r]*v[2][r] + v[3][r]*v[3][r];
#pragma unroll
        for (int d = 1; d < 16; d <<= 1){ s1 += __shfl_xor(s1, d); s2 += __shfl_xor(s2, d); }
        float mu = s1 * (1.f/64.f);
        float var = s2 * (1.f/64.f) - mu*mu;
        float rs = rsqrtf(var + 1e-5f);
#pragma unroll
        for (int f = 0; f < 4; ++f) v[f][r] = (v[f][r] - mu)*rs*gm[f] + bt[f];
      }
    }
    const int mrow = mt*128 + w*32 + mi*16 + gq*4;   // + r
    if constexpr (MODE == 3){
#pragma unroll
      for (int f = 0; f < 4; ++f)
#pragma unroll
        for (int r = 0; r < 4; ++r)
          Fo[(size_t)(mrow + r)*1024 + nt*64 + f*16 + cl] = v[f][r];
    } else {
      const int b = mrow >> 11, srow = mrow & 2047;
      const size_t hb = (size_t)(b*16 + nt);          // head-major (b*16 + head)
      if constexpr (MODE <= 1){
#pragma unroll
        for (int f = 0; f < 4; ++f)
#pragma unroll
          for (int r = 0; r < 4; ++r){
            u16 h_, l_; fsplit(v[f][r], h_, l_);
            size_t ix = (hb*2048 + srow + r)*64 + f*16 + cl;
            Nh[ix] = h_; Nl[ix] = l_;
          }
      }
      if constexpr (MODE == 1 || MODE == 2){
        // T row d = f*16+cl: store kv-half swapped by d bit 3 -> bank-spread b64 reads
        const int srow_sw = srow ^ (((cl >> 3) & 1) << 2);
#pragma unroll
        for (int f = 0; f < 4; ++f){
          u16x4 h4, l4;
#pragma unroll
          for (int r = 0; r < 4; ++r){ u16 a_, b_; fsplit(v[f][r], a_, b_); h4[r] = a_; l4[r] = b_; }
          size_t ix = (hb*64 + f*16 + cl)*2048 + srow_sw;
          *(u16x4*)(Th + ix) = h4;
          *(u16x4*)(Tl + ix) = l4;
        }
      }
    }
  }
}

// ---------------- fused Hopfield attention: all 4 iterations in one launch ----------------
// Block = 512 thr (8 waves), owns (bh, 128 q rows). Grid 512 = 2 blocks/CU.
// FIXED-MAX softmax (scores in [-64,64] deterministically -> m=64).
// K bf16 hi-only in LDS; P bf16 hi-only. PV uses 16x16x16 MFMA: the QK C/D
// layout (lane holds P[kv=a*16+gq*4+r][q=cl]) IS the native K=16 B-fragment
// (k = gq*4+e) -> NO cross-lane P relayout. T-operand read as b64 sub-frags
// with half-swapped storage (bank-spread). Update iters: PV on Kt-hi only.
// Final iteration: full V hi/lo.
__global__ void __launch_bounds__(512, 4) k_hopfield(
    const u16* __restrict__ Qh, const u16* __restrict__ Ql,
    const u16* __restrict__ Kh,
    const u16* __restrict__ Kth,
    const u16* __restrict__ Vth, const u16* __restrict__ Vtl,
    u16* __restrict__ Oh, u16* __restrict__ Ol)
{
  __shared__ bf16x8 sKh[2][512], sTh[2][512], sTl[2][512];
  const int tid = threadIdx.x, lane = tid & 63, w = tid >> 6;
  const int cl = lane & 15, gq = lane >> 4;
  int flat = blockIdx.x;
  flat = (flat & 7)*64 + (flat >> 3);              // XCD swizzle (512 % 8 == 0: bijective)
  const int bh = flat >> 4, qt = flat & 15;
  const size_t base = (size_t)bh * (2048*64);
  const int q = qt*128 + w*16 + cl;

  // staging geometry: thread stages slot idx=tid of each 64x64 tile; source column
  // pre-swizzled so the lane-linear LDS write yields the swizzled layout.
  const int sr = tid >> 3, ss = swz(tid & 7, sr);
  const size_t offK = base + (size_t)sr*64 + ss*8;      // + kt*4096
  const size_t offT = base + (size_t)sr*2048 + ss*8;    // + kt*64
  const int wslot = w << 6;                             // wave's LDS chunk (bf16x8 units)

  // q fragments (B-operand layout), live in registers across all 4 iterations
  bf16x8 qfh[2], qfl[2];
#pragma unroll
  for (int ks = 0; ks < 2; ++ks){
    size_t ix = base + (size_t)q*64 + ks*32 + gq*8;
    qfh[ks] = *(const bf16x8*)(Qh + ix);
    qfl[ks] = *(const bf16x8*)(Ql + ix);
  }

  const int srcA = cl + ((gq & 1) << 5);   // shuffle source lanes for exchange()
  const int srcB = srcA + 16;
  const bool sel_hi = gq >= 2;             // dest-side select: t-offset = 2*(gq>>1)

  float lsum = 0.f;                        // per-lane partial softmax denominator
  f32x4 accO[4] = {};

  // prologue: stage tile 0 (it=0 -> T source is Kt, hi only)
  GLDS(Kh  + offK, &sKh[0][wslot]);
  GLDS(Kth + offT, &sTh[0][wslot]);
  __syncthreads();

  for (int t = 0; t < 128; ++t){
    const int cur = t & 1, kt = t & 31;
    const bool fin = (t >= 96);
    if (t < 127){
      const int nt_ = t + 1, nb = nt_ & 1, nit = nt_ >> 5, nkt = nt_ & 31;
      const size_t oK = offK + (size_t)nkt*4096;
      const size_t oT = offT + (size_t)nkt*64;
      GLDS(Kh + oK, &sKh[nb][wslot]);
      if (nit < 3){
        GLDS(Kth + oT, &sTh[nb][wslot]);
      } else {
        GLDS(Vth + oT, &sTh[nb][wslot]);
        GLDS(Vtl + oT, &sTl[nb][wslot]);
      }
    }
    // ---- QK^T: St[kv][q] = Kh * (Qh + Ql) ----
    f32x4 S[4] = {};
    __builtin_amdgcn_s_setprio(1);
#pragma unroll
    for (int ks = 0; ks < 2; ++ks){
      const int slot = ks*4 + gq;
#pragma unroll
      for (int i = 0; i < 4; ++i){
        bf16x8 kh_ = frag(&sKh[cur][0], i*16 + cl, slot);
        S[i] = __builtin_amdgcn_mfma_f32_16x16x32_bf16(kh_, qfh[ks], S[i], 0, 0, 0);
        S[i] = __builtin_amdgcn_mfma_f32_16x16x32_bf16(kh_, qfl[ks], S[i], 0, 0, 0);
      }
    }
    __builtin_amdgcn_s_setprio(0);
    // ---- fixed-max softmax: p = exp2((S - 64)*C1), no reductions in-tile ----
#pragma unroll
    for (int i = 0; i < 4; ++i)
#pragma unroll
      for (int r = 0; r < 4; ++r){
        float p = fastexp2((S[i][r] - 64.f)*C1);
        S[i][r] = p;
        lsum += p;
      }
    // ---- P already in native 16x16x16 B-frag layout: pack only ----
    bf16x4 pf[4];
#pragma unroll
    for (int a = 0; a < 4; ++a)
      pf[a] = pk4(S[a][0], S[a][1], S[a][2], S[a][3]);
    // ---- PV: O^T += T^T * P^T via 16x16x16, b64 T-subfrags ----
    __builtin_amdgcn_s_setprio(1);
    if (fin){
#pragma unroll
      for (int db = 0; db < 4; ++db)
#pragma unroll
        for (int a = 0; a < 4; ++a){
          bf16x4 vh_ = frag64(&sTh[cur][0], db*16 + cl, 2*a + (gq>>1), gq&1);
          bf16x4 vl_ = frag64(&sTl[cur][0], db*16 + cl, 2*a + (gq>>1), gq&1);
          accO[db] = __builtin_amdgcn_mfma_f32_16x16x16bf16_1k(vh_, pf[a], accO[db], 0, 0, 0);
          accO[db] = __builtin_amdgcn_mfma_f32_16x16x16bf16_1k(vl_, pf[a], accO[db], 0, 0, 0);
        }
    } else {
#pragma unroll
      for (int db = 0; db < 4; ++db)
#pragma unroll
        for (int a = 0; a < 4; ++a){
          bf16x4 vh_ = frag64(&sTh[cur][0], db*16 + cl, 2*a + (gq>>1), gq&1);
          accO[db] = __builtin_amdgcn_mfma_f32_16x16x16bf16_1k(vh_, pf[a], accO[db], 0, 0, 0);
        }
    }
    __builtin_amdgcn_s_setprio(0);
    // ---- iteration epilogue ----
    if (kt == 31){
      float lt = lsum;
      lt += __shfl_xor(lt, 16);
      lt += __shfl_xor(lt, 32);
      const float inv = 1.f / lt;
      f32x4 vals[4];
#pragma unroll
      for (int db = 0; db < 4; ++db)
#pragma unroll
        for (int r = 0; r < 4; ++r) vals[db][r] = accO[db][r]*inv;
      if (t < 127){
        exchange(vals, srcA, srcB, sel_hi, qfh[0], qfh[1], qfl[0], qfl[1]);
        lsum = 0.f;
#pragma unroll
        for (int db = 0; db < 4; ++db) accO[db] = f32x4{0,0,0,0};
      } else {
        const int b = bh >> 4, h = bh & 15;
        const size_t row = (size_t)b*2048 + q;
#pragma unroll
        for (int db = 0; db < 4; ++db){
          u16x4 h4, l4;
#pragma unroll
          for (int r = 0; r < 4; ++r){ u16 a_, b_; fsplit(vals[db][r], a_, b_); h4[r] = a_; l4[r] = b_; }
          size_t ix = row*1024 + h*64 + db*16 + gq*4;
          *(u16x4*)(Oh + ix) = h4;
          *(u16x4*)(Ol + ix) = l4;
        }
      }
    }
    __syncthreads();
  }
}

extern "C" void kernel_launch(void* const* d_in, const int* in_sizes, int n_in,
                              void* d_out, int out_size, void* d_ws, size_t ws_size,
                              hipStream_t stream) {
  (void)in_sizes; (void)n_in; (void)out_size; (void)ws_size;
  const float* query = (const float*)d_in[0];
  const float* key   = (const float*)d_in[1];
  const float* value = (const float*)d_in[2];
  const float* Wq = (const float*)d_in[3];
  const float* bq = (const float*)d_in[4];
  const float* Wk = (const float*)d_in[5];
  const float* bk = (const float*)d_in[6];
  const float* Wv = (const float*)d_in[7];
  const float* bv = (const float*)d_in[8];
  const float* Wo = (const float*)d_in[9];
  const float* bo = (const float*)d_in[10];
  const float* gamma = (const float*)d_in[11];
  const float* beta  = (const float*)d_in[12];
  float* out = (float*)d_out;

  char* ws = (char*)d_ws;
  const size_t MB = 1024*1024;
  u16* inq_h = (u16*)(ws + 0*MB),  *inq_l = (u16*)(ws + 8*MB);
  u16* ink_h = (u16*)(ws + 16*MB), *ink_l = (u16*)(ws + 24*MB);
  u16* inv_h = (u16*)(ws + 32*MB), *inv_l = (u16*)(ws + 40*MB);
  u16* wq_h = (u16*)(ws + 48*MB), *wq_l = (u16*)(ws + 50*MB);
  u16* wk_h = (u16*)(ws + 52*MB), *wk_l = (u16*)(ws + 54*MB);
  u16* wv_h = (u16*)(ws + 56*MB), *wv_l = (u16*)(ws + 58*MB);
  u16* wo_h = (u16*)(ws + 60*MB), *wo_l = (u16*)(ws + 62*MB);
  u16* Qh  = (u16*)(ws + 64*MB),  *Ql  = (u16*)(ws + 72*MB);
  u16* Kh  = (u16*)(ws + 80*MB),  *Kl  = (u16*)(ws + 88*MB);
  u16* Kth = (u16*)(ws + 96*MB),  *Ktl = (u16*)(ws + 104*MB);
  u16* Vth = (u16*)(ws + 112*MB), *Vtl = (u16*)(ws + 120*MB);
  u16* Oh = inq_h, *Ol = inq_l;    // reuse: inq dead after proj<0>

  const int n4 = 4096*1024/4;
  k_split_in<<<dim3(2048), dim3(256), 0, stream>>>(query, inq_h, inq_l, n4);
  k_split_in<<<dim3(2048), dim3(256), 0, stream>>>(key,   ink_h, ink_l, n4);
  k_split_in<<<dim3(2048), dim3(256), 0, stream>>>(value, inv_h, inv_l, n4);
  k_wsplit<<<dim3(32,32), dim3(256), 0, stream>>>(Wq, wq_h, wq_l);
  k_wsplit<<<dim3(32,32), dim3(256), 0, stream>>>(Wk, wk_h, wk_l);
  k_wsplit<<<dim3(32,32), dim3(256), 0, stream>>>(Wv, wv_h, wv_l);
  k_wsplit<<<dim3(32,32), dim3(256), 0, stream>>>(Wo, wo_h, wo_l);

  k_proj<0><<<dim3(16,32), dim3(256), 0, stream>>>(inq_h, inq_l, wq_h, wq_l, bq, gamma, beta,
                                                   Qh, Ql, nullptr, nullptr, nullptr);
  k_proj<1><<<dim3(16,32), dim3(256), 0, stream>>>(ink_h, ink_l, wk_h, wk_l, bk, gamma, beta,
                                                   Kh, Kl, Kth, Ktl, nullptr);
  k_proj<2><<<dim3(16,32), dim3(256), 0, stream>>>(inv_h, inv_l, wv_h, wv_l, bv, nullptr, nullptr,
                                                   nullptr, nullptr, Vth, Vtl, nullptr);

  k_hopfield<<<dim3(512), dim3(512), 0, stream>>>(Qh, Ql, Kh, Kth, Vth, Vtl, Oh, Ol);

  k_proj<3><<<dim3(16,32), dim3(256), 0, stream>>>(Oh, Ol, wo_h, wo_l, bo, nullptr, nullptr,
                                                   nullptr, nullptr, nullptr, nullptr, out);
}

// Round 12
// 370.975 us; speedup vs baseline: 1.7294x; 1.1078x over previous
//
#include <hip/hip_runtime.h>

typedef unsigned short u16;
typedef __attribute__((ext_vector_type(8))) short bf16x8;
typedef __attribute__((ext_vector_type(4))) short bf16x4;
typedef __attribute__((ext_vector_type(4))) float f32x4;
typedef __attribute__((ext_vector_type(4))) u16 u16x4;

#define C1 0.18033688011112042f   // log2(e)/8  (folds the 1/sqrt(64) score scale)

#define GLDS(g, l) __builtin_amdgcn_global_load_lds( \
    (const __attribute__((address_space(1))) void*)(g), \
    (__attribute__((address_space(3))) void*)(l), 16, 0, 0)

__device__ __forceinline__ float fastexp2(float x){
  float r;
  asm("v_exp_f32 %0, %1" : "=v"(r) : "v"(x));
  return r;
}

// packed f32x2 -> bf16x2 (low16 = bf16(x0), high16 = bf16(x1)), 1 VALU op
__device__ __forceinline__ unsigned cvtpk(float x0, float x1){
  unsigned r;
  asm("v_cvt_pk_bf16_f32 %0, %1, %2" : "=v"(r) : "v"(x0), "v"(x1));
  return r;
}

__device__ __forceinline__ bf16x4 pk4(float x0, float x1, float x2, float x3){
  union { unsigned u[2]; bf16x4 b; } o;
  o.u[0] = cvtpk(x0, x1);
  o.u[1] = cvtpk(x2, x3);
  return o.b;
}

__device__ __forceinline__ u16 f2bf(float x){
  unsigned u = __float_as_uint(x);
  u += 0x7fffu + ((u >> 16) & 1u);
  return (u16)(u >> 16);
}
__device__ __forceinline__ float bf2f(u16 h){ return __uint_as_float(((unsigned)h) << 16); }
__device__ __forceinline__ void fsplit(float x, u16 &h, u16 &l){
  h = f2bf(x);
  l = f2bf(x - bf2f(h));
}

// RTNE pack of (x0,x1) -> u32 {bf16(x1):bf16(x0)}, plus lo-residual pack.
__device__ __forceinline__ void pksplit(float x0, float x1, unsigned &h, unsigned &l){
  unsigned r0 = __float_as_uint(x0); r0 += 0x7fffu + ((r0 >> 16) & 1u);
  unsigned r1 = __float_as_uint(x1); r1 += 0x7fffu + ((r1 >> 16) & 1u);
  h = (r0 >> 16) | (r1 & 0xffff0000u);
  float y0 = x0 - __uint_as_float(r0 & 0xffff0000u);
  float y1 = x1 - __uint_as_float(r1 & 0xffff0000u);
  unsigned s0 = __float_as_uint(y0); s0 += 0x7fffu + ((s0 >> 16) & 1u);
  unsigned s1 = __float_as_uint(y1); s1 += 0x7fffu + ((s1 >> 16) & 1u);
  l = (s0 >> 16) | (s1 & 0xffff0000u);
}

// LDS slot swizzle (involution per row; empirically the low-conflict pattern).
__device__ __forceinline__ int swz(int slot, int r){
  return slot ^ (r & 7);
}

__device__ __forceinline__ bf16x8 frag(const bf16x8* lds, int r, int slot){
  return lds[r*8 + swz(slot, r)];
}

// b64 sub-fragment (A-operand of 16x16x16). Data is stored half-swapped by
// row-bit-3 (see k_proj T-writes) so quarter-wave lanes cover all 32 banks.
__device__ __forceinline__ bf16x4 frag64(const bf16x8* lds, int r, int slot, int half){
  return ((const bf16x4*)&lds[r*8 + swz(slot, r)])[half ^ ((r >> 3) & 1)];
}

// GLDS tile staging: linear LDS dest (wave chunk + lane*16), inverse-swizzled
// global source column -> LDS position swz(c) holds data column c (rule #21).
template<int ROWS>
__device__ __forceinline__ void stage_glds(bf16x8* lds, const u16* __restrict__ g,
                                           size_t row0, int ldg, int col0, int tid, int w){
#pragma unroll
  for (int p = 0; p < ROWS/32; ++p){
    int idx = p*256 + tid;
    int r = idx >> 3, slot = idx & 7;
    int ss = swz(slot, r);
    GLDS(g + (row0 + (size_t)r)*(size_t)ldg + col0 + ss*8, &lds[p*256 + (w<<6)]);
  }
}

// split-bf16 3-term product: X*Y ~= Xh*Yh + Xh*Yl + Xl*Yh   (fp32 accumulate)
__device__ __forceinline__ f32x4 mfma3(bf16x8 xh, bf16x8 xl, bf16x8 yh, bf16x8 yl, f32x4 c){
  c = __builtin_amdgcn_mfma_f32_16x16x32_bf16(xh, yh, c, 0, 0, 0);
  c = __builtin_amdgcn_mfma_f32_16x16x32_bf16(xh, yl, c, 0, 0, 0);
  c = __builtin_amdgcn_mfma_f32_16x16x32_bf16(xl, yh, c, 0, 0, 0);
  return c;
}

// ---- C/D-layout -> B-fragment relayout via 4-lane shuffle (hi-only) ----------
// (used only for the q-rebuild at iteration ends, 4x per kernel)
// Input : lane (cl,gq) holds X[q=cl][u = a*16 + gq*4 + r] as f32 (a=0..3, r=0..3).
// Output: oh0 = bf16x8 of X[q=cl][u = gq*8 + j], oh1 for u = 32 + gq*8 + j.
// Word f=ks*4+c: source lane gq_s = 2*(gq&1)+(c>>1); packed word t = ks*4 +
// 2*(gq>>1) + (c&1) -> shuffle both t0/t0+2 candidates, select by dest gq>>1.
__device__ __forceinline__ void exchange_hi(const f32x4* X, int srcA, int srcB, bool sel_hi,
                                            bf16x8& oh0, bf16x8& oh1)
{
  unsigned hi[8];
#pragma unroll
  for (int a = 0; a < 4; ++a)
#pragma unroll
    for (int b0 = 0; b0 < 2; ++b0)
      hi[a*2+b0] = cvtpk(X[a][2*b0], X[a][2*b0+1]);
  unsigned OH[8];
#pragma unroll
  for (int f = 0; f < 8; ++f){
    const int t0 = (f>>2)*4 + (f&1);
    const int sl = ((f&3)>>1) ? srcB : srcA;
    unsigned h0 = (unsigned)__shfl((int)hi[t0],     sl, 64);
    unsigned h2 = (unsigned)__shfl((int)hi[t0 + 2], sl, 64);
    OH[f] = sel_hi ? h2 : h0;
  }
  union U { unsigned u[4]; bf16x8 b; };
  U a0, a1;
#pragma unroll
  for (int c = 0; c < 4; ++c){ a0.u[c]=OH[c]; a1.u[c]=OH[4+c]; }
  oh0=a0.b; oh1=a1.b;
}

// ---------------- elementwise split: fp32 -> (hi,lo) bf16 ----------------
__global__ void __launch_bounds__(256) k_split_in(const float* __restrict__ x,
                                                  u16* __restrict__ hh, u16* __restrict__ ll, int n4){
  for (int i = blockIdx.x*256 + threadIdx.x; i < n4; i += gridDim.x*256){
    float4 v = ((const float4*)x)[i];
    float a[4] = {v.x, v.y, v.z, v.w};
    u16x4 h, l;
#pragma unroll
    for (int j = 0; j < 4; ++j){ u16 p, q; fsplit(a[j], p, q); h[j] = p; l[j] = q; }
    *(u16x4*)(hh + (size_t)i*4) = h;
    *(u16x4*)(ll + (size_t)i*4) = l;
  }
}

// ---------------- weight transpose + split: W[k][n] -> Wt[n][k] hi/lo ----------------
__global__ void __launch_bounds__(256) k_wsplit(const float* __restrict__ W,
                                                u16* __restrict__ Th, u16* __restrict__ Tl){
  __shared__ float t[32][33];
  int tx = threadIdx.x & 31, ty = threadIdx.x >> 5;      // 32 x 8
  int n0 = blockIdx.x*32, k0 = blockIdx.y*32;
#pragma unroll
  for (int i = 0; i < 4; ++i)
    t[ty + 8*i][tx] = W[(size_t)(k0 + ty + 8*i)*1024 + n0 + tx];
  __syncthreads();
#pragma unroll
  for (int i = 0; i < 4; ++i){
    int n = n0 + ty + 8*i, k = k0 + tx;
    u16 a, b; fsplit(t[tx][ty + 8*i], a, b);
    Th[(size_t)n*1024 + k] = a;
    Tl[(size_t)n*1024 + k] = b;
  }
}

// ---------------- projection / output GEMM ----------------
// C(4096x1024) = A(4096x1024) * Bt^T (+bias), tile 128x64, 4 waves x (32 rows x 64 cols)
// Staging via global_load_lds (linear dest + inverse-swizzled source).
// MODE 0: Q  -> LN, natural head-major split write
// MODE 1: K  -> LN, natural + transposed split writes (T half-swapped by kv bit 2)
// MODE 2: V  -> transposed split write (half-swapped)
// MODE 3: out-> fp32 write to d_out
template<int MODE>
__global__ void __launch_bounds__(256, 3) k_proj(
    const u16* __restrict__ Ah, const u16* __restrict__ Al,
    const u16* __restrict__ Bh, const u16* __restrict__ Bl,
    const float* __restrict__ bias, const float* __restrict__ gamma, const float* __restrict__ beta,
    u16* __restrict__ Nh, u16* __restrict__ Nl,
    u16* __restrict__ Th, u16* __restrict__ Tl,
    float* __restrict__ Fo)
{
  __shared__ bf16x8 sAh[128*8], sAl[128*8], sBh[64*8], sBl[64*8];
  const int tid = threadIdx.x, lane = tid & 63, w = tid >> 6;
  const int cl = lane & 15, gq = lane >> 4;
  const int nt = blockIdx.x, mt = blockIdx.y;
  f32x4 acc[2][4] = {};
  for (int kt = 0; kt < 16; ++kt){
    __syncthreads();
    stage_glds<128>(sAh, Ah, (size_t)mt*128, 1024, kt*64, tid, w);
    stage_glds<128>(sAl, Al, (size_t)mt*128, 1024, kt*64, tid, w);
    stage_glds<64>(sBh, Bh, (size_t)nt*64, 1024, kt*64, tid, w);
    stage_glds<64>(sBl, Bl, (size_t)nt*64, 1024, kt*64, tid, w);
    __syncthreads();
#pragma unroll
    for (int ks = 0; ks < 2; ++ks){
      const int slot = ks*4 + gq;
      bf16x8 ah0 = frag(sAh, w*32 + cl, slot);
      bf16x8 al0 = frag(sAl, w*32 + cl, slot);
      bf16x8 ah1 = frag(sAh, w*32 + 16 + cl, slot);
      bf16x8 al1 = frag(sAl, w*32 + 16 + cl, slot);
#pragma unroll
      for (int f = 0; f < 4; ++f){
        bf16x8 bh_ = frag(sBh, f*16 + cl, slot);
        bf16x8 bl_ = frag(sBl, f*16 + cl, slot);
        acc[0][f] = mfma3(ah0, al0, bh_, bl_, acc[0][f]);
        acc[1][f] = mfma3(ah1, al1, bh_, bl_, acc[1][f]);
      }
    }
  }
  float bv[4];
#pragma unroll
  for (int f = 0; f < 4; ++f) bv[f] = bias[nt*64 + f*16 + cl];
  float gm[4], bt[4];
  if constexpr (MODE <= 1){
#pragma unroll
    for (int f = 0; f < 4; ++f){ gm[f] = gamma[f*16 + cl]; bt[f] = beta[f*16 + cl]; }
  }
#pragma unroll
  for (int mi = 0; mi < 2; ++mi){
    float v[4][4];
#pragma unroll
    for (int f = 0; f < 4; ++f)
#pragma unroll
      for (int r = 0; r < 4; ++r) v[f][r] = acc[mi][f][r] + bv[f];
    if constexpr (MODE <= 1){
#pragma unroll
      for (int r = 0; r < 4; ++r){
        float s1 = v[0][r] + v[1][r] + v[2][r] + v[3][r];
        float s2 = v[0][r]*v[0][r] + v[1][r]*v[1][r] + v[2][r]*v[2][r] + v[3][r]*v[3][r];
#pragma unroll
        for (int d = 1; d < 16; d <<= 1){ s1 += __shfl_xor(s1, d); s2 += __shfl_xor(s2, d); }
        float mu = s1 * (1.f/64.f);
        float var = s2 * (1.f/64.f) - mu*mu;
        float rs = rsqrtf(var + 1e-5f);
#pragma unroll
        for (int f = 0; f < 4; ++f) v[f][r] = (v[f][r] - mu)*rs*gm[f] + bt[f];
      }
    }
    const int mrow = mt*128 + w*32 + mi*16 + gq*4;   // + r
    if constexpr (MODE == 3){
#pragma unroll
      for (int f = 0; f < 4; ++f)
#pragma unroll
        for (int r = 0; r < 4; ++r)
          Fo[(size_t)(mrow + r)*1024 + nt*64 + f*16 + cl] = v[f][r];
    } else {
      const int b = mrow >> 11, srow = mrow & 2047;
      const size_t hb = (size_t)(b*16 + nt);          // head-major (b*16 + head)
      if constexpr (MODE <= 1){
#pragma unroll
        for (int f = 0; f < 4; ++f)
#pragma unroll
          for (int r = 0; r < 4; ++r){
            u16 h_, l_; fsplit(v[f][r], h_, l_);
            size_t ix = (hb*2048 + srow + r)*64 + f*16 + cl;
            Nh[ix] = h_; Nl[ix] = l_;
          }
      }
      if constexpr (MODE == 1 || MODE == 2){
        // T row d = f*16+cl: store kv-half swapped by d bit 3 -> bank-spread b64 reads
        const int srow_sw = srow ^ (((cl >> 3) & 1) << 2);
#pragma unroll
        for (int f = 0; f < 4; ++f){
          u16x4 h4, l4;
#pragma unroll
          for (int r = 0; r < 4; ++r){ u16 a_, b_; fsplit(v[f][r], a_, b_); h4[r] = a_; l4[r] = b_; }
          size_t ix = (hb*64 + f*16 + cl)*2048 + srow_sw;
          *(u16x4*)(Th + ix) = h4;
          *(u16x4*)(Tl + ix) = l4;
        }
      }
    }
  }
}

// ---------------- fused Hopfield attention: all 4 iterations in one launch ----------------
// Block = 512 thr (8 waves), owns (bh, 128 q rows). Grid 512 = 2 blocks/CU.
// FIXED-MAX softmax (scores in [-64,64] deterministically -> m=64).
// Q, K, P all bf16 hi-only in the QK/softmax path (dS rms ~1.3e-2 -> dP/P ~0.2%,
// below P-bf16 quantization; l-normalization cancels common-mode). PV uses
// 16x16x16 MFMA: the QK C/D layout IS the native K=16 B-fragment -> NO cross-
// lane P relayout. T-operand read as b64 sub-frags with half-swapped storage
// (bank-spread). Update iters: PV on Kt-hi only. Final iteration: full V hi/lo.
__global__ void __launch_bounds__(512, 4) k_hopfield(
    const u16* __restrict__ Qh,
    const u16* __restrict__ Kh,
    const u16* __restrict__ Kth,
    const u16* __restrict__ Vth, const u16* __restrict__ Vtl,
    u16* __restrict__ Oh, u16* __restrict__ Ol)
{
  __shared__ bf16x8 sKh[2][512], sTh[2][512], sTl[2][512];
  const int tid = threadIdx.x, lane = tid & 63, w = tid >> 6;
  const int cl = lane & 15, gq = lane >> 4;
  int flat = blockIdx.x;
  flat = (flat & 7)*64 + (flat >> 3);              // XCD swizzle (512 % 8 == 0: bijective)
  const int bh = flat >> 4, qt = flat & 15;
  const size_t base = (size_t)bh * (2048*64);
  const int q = qt*128 + w*16 + cl;

  // staging geometry: thread stages slot idx=tid of each 64x64 tile; source column
  // pre-swizzled so the lane-linear LDS write yields the swizzled layout.
  const int sr = tid >> 3, ss = swz(tid & 7, sr);
  const size_t offK = base + (size_t)sr*64 + ss*8;      // + kt*4096
  const size_t offT = base + (size_t)sr*2048 + ss*8;    // + kt*64
  const int wslot = w << 6;                             // wave's LDS chunk (bf16x8 units)

  // q fragments (B-operand layout, hi-only), live across all 4 iterations
  bf16x8 qfh[2];
#pragma unroll
  for (int ks = 0; ks < 2; ++ks)
    qfh[ks] = *(const bf16x8*)(Qh + base + (size_t)q*64 + ks*32 + gq*8);

  const int srcA = cl + ((gq & 1) << 5);   // shuffle source lanes for exchange_hi()
  const int srcB = srcA + 16;
  const bool sel_hi = gq >= 2;             // dest-side select: t-offset = 2*(gq>>1)

  float lsum = 0.f;                        // per-lane partial softmax denominator
  f32x4 accO[4] = {};

  // prologue: stage tile 0 (it=0 -> T source is Kt, hi only)
  GLDS(Kh  + offK, &sKh[0][wslot]);
  GLDS(Kth + offT, &sTh[0][wslot]);
  __syncthreads();

  for (int t = 0; t < 128; ++t){
    const int cur = t & 1, kt = t & 31;
    const bool fin = (t >= 96);
    if (t < 127){
      const int nt_ = t + 1, nb = nt_ & 1, nit = nt_ >> 5, nkt = nt_ & 31;
      const size_t oK = offK + (size_t)nkt*4096;
      const size_t oT = offT + (size_t)nkt*64;
      GLDS(Kh + oK, &sKh[nb][wslot]);
      if (nit < 3){
        GLDS(Kth + oT, &sTh[nb][wslot]);
      } else {
        GLDS(Vth + oT, &sTh[nb][wslot]);
        GLDS(Vtl + oT, &sTl[nb][wslot]);
      }
    }
    // ---- QK^T: St[kv][q] = Kh * Qh (hi-only both sides) ----
    f32x4 S[4] = {};
    __builtin_amdgcn_s_setprio(1);
#pragma unroll
    for (int ks = 0; ks < 2; ++ks){
      const int slot = ks*4 + gq;
#pragma unroll
      for (int i = 0; i < 4; ++i){
        bf16x8 kh_ = frag(&sKh[cur][0], i*16 + cl, slot);
        S[i] = __builtin_amdgcn_mfma_f32_16x16x32_bf16(kh_, qfh[ks], S[i], 0, 0, 0);
      }
    }
    __builtin_amdgcn_s_setprio(0);
    // ---- fixed-max softmax: p = exp2((S - 64)*C1), no reductions in-tile ----
#pragma unroll
    for (int i = 0; i < 4; ++i)
#pragma unroll
      for (int r = 0; r < 4; ++r){
        float p = fastexp2((S[i][r] - 64.f)*C1);
        S[i][r] = p;
        lsum += p;
      }
    // ---- P already in native 16x16x16 B-frag layout: pack only ----
    bf16x4 pf[4];
#pragma unroll
    for (int a = 0; a < 4; ++a)
      pf[a] = pk4(S[a][0], S[a][1], S[a][2], S[a][3]);
    // ---- PV: O^T += T^T * P^T via 16x16x16, b64 T-subfrags ----
    __builtin_amdgcn_s_setprio(1);
    if (fin){
#pragma unroll
      for (int db = 0; db < 4; ++db)
#pragma unroll
        for (int a = 0; a < 4; ++a){
          bf16x4 vh_ = frag64(&sTh[cur][0], db*16 + cl, 2*a + (gq>>1), gq&1);
          bf16x4 vl_ = frag64(&sTl[cur][0], db*16 + cl, 2*a + (gq>>1), gq&1);
          accO[db] = __builtin_amdgcn_mfma_f32_16x16x16bf16_1k(vh_, pf[a], accO[db], 0, 0, 0);
          accO[db] = __builtin_amdgcn_mfma_f32_16x16x16bf16_1k(vl_, pf[a], accO[db], 0, 0, 0);
        }
    } else {
#pragma unroll
      for (int db = 0; db < 4; ++db)
#pragma unroll
        for (int a = 0; a < 4; ++a){
          bf16x4 vh_ = frag64(&sTh[cur][0], db*16 + cl, 2*a + (gq>>1), gq&1);
          accO[db] = __builtin_amdgcn_mfma_f32_16x16x16bf16_1k(vh_, pf[a], accO[db], 0, 0, 0);
        }
    }
    __builtin_amdgcn_s_setprio(0);
    // ---- iteration epilogue ----
    if (kt == 31){
      float lt = lsum;
      lt += __shfl_xor(lt, 16);
      lt += __shfl_xor(lt, 32);
      const float inv = 1.f / lt;
      f32x4 vals[4];
#pragma unroll
      for (int db = 0; db < 4; ++db)
#pragma unroll
        for (int r = 0; r < 4; ++r) vals[db][r] = accO[db][r]*inv;
      if (t < 127){
        exchange_hi(vals, srcA, srcB, sel_hi, qfh[0], qfh[1]);
        lsum = 0.f;
#pragma unroll
        for (int db = 0; db < 4; ++db) accO[db] = f32x4{0,0,0,0};
      } else {
        const int b = bh >> 4, h = bh & 15;
        const size_t row = (size_t)b*2048 + q;
#pragma unroll
        for (int db = 0; db < 4; ++db){
          u16x4 h4, l4;
#pragma unroll
          for (int r = 0; r < 4; ++r){ u16 a_, b_; fsplit(vals[db][r], a_, b_); h4[r] = a_; l4[r] = b_; }
          size_t ix = row*1024 + h*64 + db*16 + gq*4;
          *(u16x4*)(Oh + ix) = h4;
          *(u16x4*)(Ol + ix) = l4;
        }
      }
    }
    __syncthreads();
  }
}

extern "C" void kernel_launch(void* const* d_in, const int* in_sizes, int n_in,
                              void* d_out, int out_size, void* d_ws, size_t ws_size,
                              hipStream_t stream) {
  (void)in_sizes; (void)n_in; (void)out_size; (void)ws_size;
  const float* query = (const float*)d_in[0];
  const float* key   = (const float*)d_in[1];
  const float* value = (const float*)d_in[2];
  const float* Wq = (const float*)d_in[3];
  const float* bq = (const float*)d_in[4];
  const float* Wk = (const float*)d_in[5];
  const float* bk = (const float*)d_in[6];
  const float* Wv = (const float*)d_in[7];
  const float* bv = (const float*)d_in[8];
  const float* Wo = (const float*)d_in[9];
  const float* bo = (const float*)d_in[10];
  const float* gamma = (const float*)d_in[11];
  const float* beta  = (const float*)d_in[12];
  float* out = (float*)d_out;

  char* ws = (char*)d_ws;
  const size_t MB = 1024*1024;
  u16* inq_h = (u16*)(ws + 0*MB),  *inq_l = (u16*)(ws + 8*MB);
  u16* ink_h = (u16*)(ws + 16*MB), *ink_l = (u16*)(ws + 24*MB);
  u16* inv_h = (u16*)(ws + 32*MB), *inv_l = (u16*)(ws + 40*MB);
  u16* wq_h = (u16*)(ws + 48*MB), *wq_l = (u16*)(ws + 50*MB);
  u16* wk_h = (u16*)(ws + 52*MB), *wk_l = (u16*)(ws + 54*MB);
  u16* wv_h = (u16*)(ws + 56*MB), *wv_l = (u16*)(ws + 58*MB);
  u16* wo_h = (u16*)(ws + 60*MB), *wo_l = (u16*)(ws + 62*MB);
  u16* Qh  = (u16*)(ws + 64*MB),  *Ql  = (u16*)(ws + 72*MB);
  u16* Kh  = (u16*)(ws + 80*MB),  *Kl  = (u16*)(ws + 88*MB);
  u16* Kth = (u16*)(ws + 96*MB),  *Ktl = (u16*)(ws + 104*MB);
  u16* Vth = (u16*)(ws + 112*MB), *Vtl = (u16*)(ws + 120*MB);
  u16* Oh = inq_h, *Ol = inq_l;    // reuse: inq dead after proj<0>

  const int n4 = 4096*1024/4;
  k_split_in<<<dim3(2048), dim3(256), 0, stream>>>(query, inq_h, inq_l, n4);
  k_split_in<<<dim3(2048), dim3(256), 0, stream>>>(key,   ink_h, ink_l, n4);
  k_split_in<<<dim3(2048), dim3(256), 0, stream>>>(value, inv_h, inv_l, n4);
  k_wsplit<<<dim3(32,32), dim3(256), 0, stream>>>(Wq, wq_h, wq_l);
  k_wsplit<<<dim3(32,32), dim3(256), 0, stream>>>(Wk, wk_h, wk_l);
  k_wsplit<<<dim3(32,32), dim3(256), 0, stream>>>(Wv, wv_h, wv_l);
  k_wsplit<<<dim3(32,32), dim3(256), 0, stream>>>(Wo, wo_h, wo_l);

  k_proj<0><<<dim3(16,32), dim3(256), 0, stream>>>(inq_h, inq_l, wq_h, wq_l, bq, gamma, beta,
                                                   Qh, Ql, nullptr, nullptr, nullptr);
  k_proj<1><<<dim3(16,32), dim3(256), 0, stream>>>(ink_h, ink_l, wk_h, wk_l, bk, gamma, beta,
                                                   Kh, Kl, Kth, Ktl, nullptr);
  k_proj<2><<<dim3(16,32), dim3(256), 0, stream>>>(inv_h, inv_l, wv_h, wv_l, bv, nullptr, nullptr,
                                                   nullptr, nullptr, Vth, Vtl, nullptr);

  k_hopfield<<<dim3(512), dim3(512), 0, stream>>>(Qh, Kh, Kth, Vth, Vtl, Oh, Ol);

  k_proj<3><<<dim3(16,32), dim3(256), 0, stream>>>(Oh, Ol, wo_h, wo_l, bo, nullptr, nullptr,
                                                   nullptr, nullptr, nullptr, nullptr, out);
}

// Round 13
// 349.860 us; speedup vs baseline: 1.8338x; 1.0604x over previous
//
#include <hip/hip_runtime.h>

typedef unsigned short u16;
typedef __attribute__((ext_vector_type(8))) short bf16x8;
typedef __attribute__((ext_vector_type(4))) short bf16x4;
typedef __attribute__((ext_vector_type(4))) float f32x4;
typedef __attribute__((ext_vector_type(4))) u16 u16x4;

#define C1 0.18033688011112042f   // log2(e)/8  (folds the 1/sqrt(64) score scale)

#define GLDS(g, l) __builtin_amdgcn_global_load_lds( \
    (const __attribute__((address_space(1))) void*)(g), \
    (__attribute__((address_space(3))) void*)(l), 16, 0, 0)

__device__ __forceinline__ float fastexp2(float x){
  float r;
  asm("v_exp_f32 %0, %1" : "=v"(r) : "v"(x));
  return r;
}

// packed f32x2 -> bf16x2 (low16 = bf16(x0), high16 = bf16(x1)), 1 VALU op
__device__ __forceinline__ unsigned cvtpk(float x0, float x1){
  unsigned r;
  asm("v_cvt_pk_bf16_f32 %0, %1, %2" : "=v"(r) : "v"(x0), "v"(x1));
  return r;
}

__device__ __forceinline__ bf16x4 pk4(float x0, float x1, float x2, float x3){
  union { unsigned u[2]; bf16x4 b; } o;
  o.u[0] = cvtpk(x0, x1);
  o.u[1] = cvtpk(x2, x3);
  return o.b;
}

__device__ __forceinline__ u16 f2bf(float x){
  unsigned u = __float_as_uint(x);
  u += 0x7fffu + ((u >> 16) & 1u);
  return (u16)(u >> 16);
}
__device__ __forceinline__ float bf2f(u16 h){ return __uint_as_float(((unsigned)h) << 16); }
__device__ __forceinline__ void fsplit(float x, u16 &h, u16 &l){
  h = f2bf(x);
  l = f2bf(x - bf2f(h));
}

// LDS slot swizzle (involution per row; empirically the low-conflict pattern).
__device__ __forceinline__ int swz(int slot, int r){
  return slot ^ (r & 7);
}

__device__ __forceinline__ bf16x8 frag(const bf16x8* lds, int r, int slot){
  return lds[r*8 + swz(slot, r)];
}

// b64 sub-fragment (A-operand of 16x16x16). Data is stored half-swapped by
// row-bit-3 (see k_proj T-writes) so quarter-wave lanes cover all 32 banks.
__device__ __forceinline__ bf16x4 frag64(const bf16x8* lds, int r, int slot, int half){
  return ((const bf16x4*)&lds[r*8 + swz(slot, r)])[half ^ ((r >> 3) & 1)];
}

// GLDS tile staging: linear LDS dest (wave chunk + lane*16), inverse-swizzled
// global source column -> LDS position swz(c) holds data column c (rule #21).
template<int ROWS>
__device__ __forceinline__ void stage_glds(bf16x8* lds, const u16* __restrict__ g,
                                           size_t row0, int ldg, int col0, int tid, int w){
#pragma unroll
  for (int p = 0; p < ROWS/32; ++p){
    int idx = p*256 + tid;
    int r = idx >> 3, slot = idx & 7;
    int ss = swz(slot, r);
    GLDS(g + (row0 + (size_t)r)*(size_t)ldg + col0 + ss*8, &lds[p*256 + (w<<6)]);
  }
}

// split-bf16 3-term product: X*Y ~= Xh*Yh + Xh*Yl + Xl*Yh   (fp32 accumulate)
__device__ __forceinline__ f32x4 mfma3(bf16x8 xh, bf16x8 xl, bf16x8 yh, bf16x8 yl, f32x4 c){
  c = __builtin_amdgcn_mfma_f32_16x16x32_bf16(xh, yh, c, 0, 0, 0);
  c = __builtin_amdgcn_mfma_f32_16x16x32_bf16(xh, yl, c, 0, 0, 0);
  c = __builtin_amdgcn_mfma_f32_16x16x32_bf16(xl, yh, c, 0, 0, 0);
  return c;
}

// ---- C/D-layout -> B-fragment relayout via 4-lane shuffle (hi-only) ----------
// (used only for the q-rebuild at iteration ends, 4x per kernel)
// Input : lane (cl,gq) holds X[q=cl][u = a*16 + gq*4 + r] as f32 (a=0..3, r=0..3).
// Output: oh0 = bf16x8 of X[q=cl][u = gq*8 + j], oh1 for u = 32 + gq*8 + j.
// Word f=ks*4+c: source lane gq_s = 2*(gq&1)+(c>>1); packed word t = ks*4 +
// 2*(gq>>1) + (c&1) -> shuffle both t0/t0+2 candidates, select by dest gq>>1.
__device__ __forceinline__ void exchange_hi(const f32x4* X, int srcA, int srcB, bool sel_hi,
                                            bf16x8& oh0, bf16x8& oh1)
{
  unsigned hi[8];
#pragma unroll
  for (int a = 0; a < 4; ++a)
#pragma unroll
    for (int b0 = 0; b0 < 2; ++b0)
      hi[a*2+b0] = cvtpk(X[a][2*b0], X[a][2*b0+1]);
  unsigned OH[8];
#pragma unroll
  for (int f = 0; f < 8; ++f){
    const int t0 = (f>>2)*4 + (f&1);
    const int sl = ((f&3)>>1) ? srcB : srcA;
    unsigned h0 = (unsigned)__shfl((int)hi[t0],     sl, 64);
    unsigned h2 = (unsigned)__shfl((int)hi[t0 + 2], sl, 64);
    OH[f] = sel_hi ? h2 : h0;
  }
  union U { unsigned u[4]; bf16x8 b; };
  U a0, a1;
#pragma unroll
  for (int c = 0; c < 4; ++c){ a0.u[c]=OH[c]; a1.u[c]=OH[4+c]; }
  oh0=a0.b; oh1=a1.b;
}

// ---------------- elementwise split (fused over q/k/v): fp32 -> (hi,lo) bf16 ----------------
__global__ void __launch_bounds__(256) k_split3(
    const float* __restrict__ xq, const float* __restrict__ xk, const float* __restrict__ xv,
    u16* __restrict__ qh, u16* __restrict__ ql,
    u16* __restrict__ kh, u16* __restrict__ kl,
    u16* __restrict__ vh, u16* __restrict__ vl, int n4){
  const int which = blockIdx.y;
  const float* x = which == 0 ? xq : which == 1 ? xk : xv;
  u16* hh = which == 0 ? qh : which == 1 ? kh : vh;
  u16* ll = which == 0 ? ql : which == 1 ? kl : vl;
  for (int i = blockIdx.x*256 + threadIdx.x; i < n4; i += gridDim.x*256){
    float4 v = ((const float4*)x)[i];
    float a[4] = {v.x, v.y, v.z, v.w};
    u16x4 h, l;
#pragma unroll
    for (int j = 0; j < 4; ++j){ u16 p, q; fsplit(a[j], p, q); h[j] = p; l[j] = q; }
    *(u16x4*)(hh + (size_t)i*4) = h;
    *(u16x4*)(ll + (size_t)i*4) = l;
  }
}

// ---------------- weight transpose + split (fused over 4 weights) ----------------
__global__ void __launch_bounds__(256) k_wsplit4(
    const float* __restrict__ W0, const float* __restrict__ W1,
    const float* __restrict__ W2, const float* __restrict__ W3,
    u16* __restrict__ T0h, u16* __restrict__ T0l, u16* __restrict__ T1h, u16* __restrict__ T1l,
    u16* __restrict__ T2h, u16* __restrict__ T2l, u16* __restrict__ T3h, u16* __restrict__ T3l){
  const int which = blockIdx.z;
  const float* W = which == 0 ? W0 : which == 1 ? W1 : which == 2 ? W2 : W3;
  u16* Th = which == 0 ? T0h : which == 1 ? T1h : which == 2 ? T2h : T3h;
  u16* Tl = which == 0 ? T0l : which == 1 ? T1l : which == 2 ? T2l : T3l;
  __shared__ float t[32][33];
  int tx = threadIdx.x & 31, ty = threadIdx.x >> 5;      // 32 x 8
  int n0 = blockIdx.x*32, k0 = blockIdx.y*32;
#pragma unroll
  for (int i = 0; i < 4; ++i)
    t[ty + 8*i][tx] = W[(size_t)(k0 + ty + 8*i)*1024 + n0 + tx];
  __syncthreads();
#pragma unroll
  for (int i = 0; i < 4; ++i){
    int n = n0 + ty + 8*i, k = k0 + tx;
    u16 a, b; fsplit(t[tx][ty + 8*i], a, b);
    Th[(size_t)n*1024 + k] = a;
    Tl[(size_t)n*1024 + k] = b;
  }
}

// ---------------- projection / output GEMM ----------------
// C(4096x1024) = A(4096x1024) * Bt^T (+bias), tile 128x64, 4 waves x (32 rows x 64 cols)
// Staging via global_load_lds (linear dest + inverse-swizzled source).
// MODE 0: Q  -> LN, natural head-major write (HI ONLY — Ql is dead downstream)
// MODE 1: K  -> LN, natural + transposed writes (both HI ONLY; half-swapped T)
// MODE 2: V  -> transposed hi/lo split write (half-swapped)
// MODE 3: out-> fp32 write to d_out
template<int MODE>
__global__ void __launch_bounds__(256, 3) k_proj(
    const u16* __restrict__ Ah, const u16* __restrict__ Al,
    const u16* __restrict__ Bh, const u16* __restrict__ Bl,
    const float* __restrict__ bias, const float* __restrict__ gamma, const float* __restrict__ beta,
    u16* __restrict__ Nh,
    u16* __restrict__ Th, u16* __restrict__ Tl,
    float* __restrict__ Fo)
{
  __shared__ bf16x8 sAh[128*8], sAl[128*8], sBh[64*8], sBl[64*8];
  const int tid = threadIdx.x, lane = tid & 63, w = tid >> 6;
  const int cl = lane & 15, gq = lane >> 4;
  const int nt = blockIdx.x, mt = blockIdx.y;
  f32x4 acc[2][4] = {};
  for (int kt = 0; kt < 16; ++kt){
    __syncthreads();
    stage_glds<128>(sAh, Ah, (size_t)mt*128, 1024, kt*64, tid, w);
    stage_glds<128>(sAl, Al, (size_t)mt*128, 1024, kt*64, tid, w);
    stage_glds<64>(sBh, Bh, (size_t)nt*64, 1024, kt*64, tid, w);
    stage_glds<64>(sBl, Bl, (size_t)nt*64, 1024, kt*64, tid, w);
    __syncthreads();
#pragma unroll
    for (int ks = 0; ks < 2; ++ks){
      const int slot = ks*4 + gq;
      bf16x8 ah0 = frag(sAh, w*32 + cl, slot);
      bf16x8 al0 = frag(sAl, w*32 + cl, slot);
      bf16x8 ah1 = frag(sAh, w*32 + 16 + cl, slot);
      bf16x8 al1 = frag(sAl, w*32 + 16 + cl, slot);
#pragma unroll
      for (int f = 0; f < 4; ++f){
        bf16x8 bh_ = frag(sBh, f*16 + cl, slot);
        bf16x8 bl_ = frag(sBl, f*16 + cl, slot);
        acc[0][f] = mfma3(ah0, al0, bh_, bl_, acc[0][f]);
        acc[1][f] = mfma3(ah1, al1, bh_, bl_, acc[1][f]);
      }
    }
  }
  float bv[4];
#pragma unroll
  for (int f = 0; f < 4; ++f) bv[f] = bias[nt*64 + f*16 + cl];
  float gm[4], bt[4];
  if constexpr (MODE <= 1){
#pragma unroll
    for (int f = 0; f < 4; ++f){ gm[f] = gamma[f*16 + cl]; bt[f] = beta[f*16 + cl]; }
  }
#pragma unroll
  for (int mi = 0; mi < 2; ++mi){
    float v[4][4];
#pragma unroll
    for (int f = 0; f < 4; ++f)
#pragma unroll
      for (int r = 0; r < 4; ++r) v[f][r] = acc[mi][f][r] + bv[f];
    if constexpr (MODE <= 1){
#pragma unroll
      for (int r = 0; r < 4; ++r){
        float s1 = v[0][r] + v[1][r] + v[2][r] + v[3][r];
        float s2 = v[0][r]*v[0][r] + v[1][r]*v[1][r] + v[2][r]*v[2][r] + v[3][r]*v[3][r];
#pragma unroll
        for (int d = 1; d < 16; d <<= 1){ s1 += __shfl_xor(s1, d); s2 += __shfl_xor(s2, d); }
        float mu = s1 * (1.f/64.f);
        float var = s2 * (1.f/64.f) - mu*mu;
        float rs = rsqrtf(var + 1e-5f);
#pragma unroll
        for (int f = 0; f < 4; ++f) v[f][r] = (v[f][r] - mu)*rs*gm[f] + bt[f];
      }
    }
    const int mrow = mt*128 + w*32 + mi*16 + gq*4;   // + r
    if constexpr (MODE == 3){
#pragma unroll
      for (int f = 0; f < 4; ++f)
#pragma unroll
        for (int r = 0; r < 4; ++r)
          Fo[(size_t)(mrow + r)*1024 + nt*64 + f*16 + cl] = v[f][r];
    } else {
      const int b = mrow >> 11, srow = mrow & 2047;
      const size_t hb = (size_t)(b*16 + nt);          // head-major (b*16 + head)
      if constexpr (MODE <= 1){                       // natural write, hi only
#pragma unroll
        for (int f = 0; f < 4; ++f)
#pragma unroll
          for (int r = 0; r < 4; ++r)
            Nh[(hb*2048 + srow + r)*64 + f*16 + cl] = f2bf(v[f][r]);
      }
      if constexpr (MODE == 1){                       // transposed write, hi only
        const int srow_sw = srow ^ (((cl >> 3) & 1) << 2);
#pragma unroll
        for (int f = 0; f < 4; ++f){
          u16x4 h4;
#pragma unroll
          for (int r = 0; r < 4; ++r) h4[r] = f2bf(v[f][r]);
          *(u16x4*)(Th + (hb*64 + f*16 + cl)*2048 + srow_sw) = h4;
        }
      }
      if constexpr (MODE == 2){                       // transposed write, hi+lo
        const int srow_sw = srow ^ (((cl >> 3) & 1) << 2);
#pragma unroll
        for (int f = 0; f < 4; ++f){
          u16x4 h4, l4;
#pragma unroll
          for (int r = 0; r < 4; ++r){ u16 a_, b_; fsplit(v[f][r], a_, b_); h4[r] = a_; l4[r] = b_; }
          size_t ix = (hb*64 + f*16 + cl)*2048 + srow_sw;
          *(u16x4*)(Th + ix) = h4;
          *(u16x4*)(Tl + ix) = l4;
        }
      }
    }
  }
}

// ---------------- fused Hopfield attention: all 4 iterations in one launch ----------------
// Block = 512 thr (8 waves), owns (bh, 128 q rows). Grid 512 = 2 blocks/CU.
// FIXED-MAX softmax (scores in [-64,64] deterministically -> m=64).
// Q, K, P all bf16 hi-only in the QK/softmax path. PV uses 16x16x16 MFMA: the
// QK C/D layout IS the native K=16 B-fragment -> NO cross-lane P relayout.
// T-operand read as b64 sub-frags with half-swapped storage (bank-spread).
// Update iters: PV on Kt-hi only. Final iteration: full V hi/lo.
// t-loop unrolled x2 so cur is compile-time -> LDS addresses loop-invariant.
__global__ void __launch_bounds__(512, 4) k_hopfield(
    const u16* __restrict__ Qh,
    const u16* __restrict__ Kh,
    const u16* __restrict__ Kth,
    const u16* __restrict__ Vth, const u16* __restrict__ Vtl,
    u16* __restrict__ Oh, u16* __restrict__ Ol)
{
  __shared__ bf16x8 sKh[2][512], sTh[2][512], sTl[2][512];
  const int tid = threadIdx.x, lane = tid & 63, w = tid >> 6;
  const int cl = lane & 15, gq = lane >> 4;
  int flat = blockIdx.x;
  flat = (flat & 7)*64 + (flat >> 3);              // XCD swizzle (512 % 8 == 0: bijective)
  const int bh = flat >> 4, qt = flat & 15;
  const size_t base = (size_t)bh * (2048*64);
  const int q = qt*128 + w*16 + cl;

  // staging geometry: thread stages slot idx=tid of each 64x64 tile; source column
  // pre-swizzled so the lane-linear LDS write yields the swizzled layout.
  const int sr = tid >> 3, ss = swz(tid & 7, sr);
  const size_t offK = base + (size_t)sr*64 + ss*8;      // + kt*4096
  const size_t offT = base + (size_t)sr*2048 + ss*8;    // + kt*64
  const int wslot = w << 6;                             // wave's LDS chunk (bf16x8 units)

  // q fragments (B-operand layout, hi-only), live across all 4 iterations
  bf16x8 qfh[2];
#pragma unroll
  for (int ks = 0; ks < 2; ++ks)
    qfh[ks] = *(const bf16x8*)(Qh + base + (size_t)q*64 + ks*32 + gq*8);

  const int srcA = cl + ((gq & 1) << 5);   // shuffle source lanes for exchange_hi()
  const int srcB = srcA + 16;
  const bool sel_hi = gq >= 2;             // dest-side select: t-offset = 2*(gq>>1)

  float lsum = 0.f;                        // per-lane partial softmax denominator
  f32x4 accO[4] = {};

  // prologue: stage tile 0 (it=0 -> T source is Kt, hi only)
  GLDS(Kh  + offK, &sKh[0][wslot]);
  GLDS(Kth + offT, &sTh[0][wslot]);
  __syncthreads();

#pragma unroll 2
  for (int t = 0; t < 128; ++t){
    const int cur = t & 1, kt = t & 31;
    const bool fin = (t >= 96);
    if (t < 127){
      const int nt_ = t + 1, nb = nt_ & 1, nit = nt_ >> 5, nkt = nt_ & 31;
      const size_t oK = offK + (size_t)nkt*4096;
      const size_t oT = offT + (size_t)nkt*64;
      GLDS(Kh + oK, &sKh[nb][wslot]);
      if (nit < 3){
        GLDS(Kth + oT, &sTh[nb][wslot]);
      } else {
        GLDS(Vth + oT, &sTh[nb][wslot]);
        GLDS(Vtl + oT, &sTl[nb][wslot]);
      }
    }
    // ---- QK^T: St[kv][q] = Kh * Qh (hi-only both sides) ----
    f32x4 S[4] = {};
    __builtin_amdgcn_s_setprio(1);
#pragma unroll
    for (int ks = 0; ks < 2; ++ks){
      const int slot = ks*4 + gq;
#pragma unroll
      for (int i = 0; i < 4; ++i){
        bf16x8 kh_ = frag(&sKh[cur][0], i*16 + cl, slot);
        S[i] = __builtin_amdgcn_mfma_f32_16x16x32_bf16(kh_, qfh[ks], S[i], 0, 0, 0);
      }
    }
    __builtin_amdgcn_s_setprio(0);
    // ---- fixed-max softmax: p = exp2((S - 64)*C1), no reductions in-tile ----
#pragma unroll
    for (int i = 0; i < 4; ++i)
#pragma unroll
      for (int r = 0; r < 4; ++r){
        float p = fastexp2((S[i][r] - 64.f)*C1);
        S[i][r] = p;
        lsum += p;
      }
    // ---- P already in native 16x16x16 B-frag layout: pack only ----
    bf16x4 pf[4];
#pragma unroll
    for (int a = 0; a < 4; ++a)
      pf[a] = pk4(S[a][0], S[a][1], S[a][2], S[a][3]);
    // ---- PV: O^T += T^T * P^T via 16x16x16, b64 T-subfrags ----
    __builtin_amdgcn_s_setprio(1);
    if (fin){
#pragma unroll
      for (int db = 0; db < 4; ++db)
#pragma unroll
        for (int a = 0; a < 4; ++a){
          bf16x4 vh_ = frag64(&sTh[cur][0], db*16 + cl, 2*a + (gq>>1), gq&1);
          bf16x4 vl_ = frag64(&sTl[cur][0], db*16 + cl, 2*a + (gq>>1), gq&1);
          accO[db] = __builtin_amdgcn_mfma_f32_16x16x16bf16_1k(vh_, pf[a], accO[db], 0, 0, 0);
          accO[db] = __builtin_amdgcn_mfma_f32_16x16x16bf16_1k(vl_, pf[a], accO[db], 0, 0, 0);
        }
    } else {
#pragma unroll
      for (int db = 0; db < 4; ++db)
#pragma unroll
        for (int a = 0; a < 4; ++a){
          bf16x4 vh_ = frag64(&sTh[cur][0], db*16 + cl, 2*a + (gq>>1), gq&1);
          accO[db] = __builtin_amdgcn_mfma_f32_16x16x16bf16_1k(vh_, pf[a], accO[db], 0, 0, 0);
        }
    }
    __builtin_amdgcn_s_setprio(0);
    // ---- iteration epilogue ----
    if (kt == 31){
      float lt = lsum;
      lt += __shfl_xor(lt, 16);
      lt += __shfl_xor(lt, 32);
      const float inv = 1.f / lt;
      f32x4 vals[4];
#pragma unroll
      for (int db = 0; db < 4; ++db)
#pragma unroll
        for (int r = 0; r < 4; ++r) vals[db][r] = accO[db][r]*inv;
      if (t < 127){
        exchange_hi(vals, srcA, srcB, sel_hi, qfh[0], qfh[1]);
        lsum = 0.f;
#pragma unroll
        for (int db = 0; db < 4; ++db) accO[db] = f32x4{0,0,0,0};
      } else {
        const int b = bh >> 4, h = bh & 15;
        const size_t row = (size_t)b*2048 + q;
#pragma unroll
        for (int db = 0; db < 4; ++db){
          u16x4 h4, l4;
#pragma unroll
          for (int r = 0; r < 4; ++r){ u16 a_, b_; fsplit(vals[db][r], a_, b_); h4[r] = a_; l4[r] = b_; }
          size_t ix = row*1024 + h*64 + db*16 + gq*4;
          *(u16x4*)(Oh + ix) = h4;
          *(u16x4*)(Ol + ix) = l4;
        }
      }
    }
    __syncthreads();
  }
}

extern "C" void kernel_launch(void* const* d_in, const int* in_sizes, int n_in,
                              void* d_out, int out_size, void* d_ws, size_t ws_size,
                              hipStream_t stream) {
  (void)in_sizes; (void)n_in; (void)out_size; (void)ws_size;
  const float* query = (const float*)d_in[0];
  const float* key   = (const float*)d_in[1];
  const float* value = (const float*)d_in[2];
  const float* Wq = (const float*)d_in[3];
  const float* bq = (const float*)d_in[4];
  const float* Wk = (const float*)d_in[5];
  const float* bk = (const float*)d_in[6];
  const float* Wv = (const float*)d_in[7];
  const float* bv = (const float*)d_in[8];
  const float* Wo = (const float*)d_in[9];
  const float* bo = (const float*)d_in[10];
  const float* gamma = (const float*)d_in[11];
  const float* beta  = (const float*)d_in[12];
  float* out = (float*)d_out;

  char* ws = (char*)d_ws;
  const size_t MB = 1024*1024;
  u16* inq_h = (u16*)(ws + 0*MB),  *inq_l = (u16*)(ws + 8*MB);
  u16* ink_h = (u16*)(ws + 16*MB), *ink_l = (u16*)(ws + 24*MB);
  u16* inv_h = (u16*)(ws + 32*MB), *inv_l = (u16*)(ws + 40*MB);
  u16* wq_h = (u16*)(ws + 48*MB), *wq_l = (u16*)(ws + 50*MB);
  u16* wk_h = (u16*)(ws + 52*MB), *wk_l = (u16*)(ws + 54*MB);
  u16* wv_h = (u16*)(ws + 56*MB), *wv_l = (u16*)(ws + 58*MB);
  u16* wo_h = (u16*)(ws + 60*MB), *wo_l = (u16*)(ws + 62*MB);
  u16* Qh  = (u16*)(ws + 64*MB);
  u16* Kh  = (u16*)(ws + 80*MB);
  u16* Kth = (u16*)(ws + 96*MB);
  u16* Vth = (u16*)(ws + 112*MB), *Vtl = (u16*)(ws + 120*MB);
  u16* Oh = inq_h, *Ol = inq_l;    // reuse: inq dead after proj<0>

  const int n4 = 4096*1024/4;
  k_split3<<<dim3(1024, 3), dim3(256), 0, stream>>>(query, key, value,
                                                    inq_h, inq_l, ink_h, ink_l, inv_h, inv_l, n4);
  k_wsplit4<<<dim3(32,32,4), dim3(256), 0, stream>>>(Wq, Wk, Wv, Wo,
                                                     wq_h, wq_l, wk_h, wk_l,
                                                     wv_h, wv_l, wo_h, wo_l);

  k_proj<0><<<dim3(16,32), dim3(256), 0, stream>>>(inq_h, inq_l, wq_h, wq_l, bq, gamma, beta,
                                                   Qh, nullptr, nullptr, nullptr);
  k_proj<1><<<dim3(16,32), dim3(256), 0, stream>>>(ink_h, ink_l, wk_h, wk_l, bk, gamma, beta,
                                                   Kh, Kth, nullptr, nullptr);
  k_proj<2><<<dim3(16,32), dim3(256), 0, stream>>>(inv_h, inv_l, wv_h, wv_l, bv, nullptr, nullptr,
                                                   nullptr, Vth, Vtl, nullptr);

  k_hopfield<<<dim3(512), dim3(512), 0, stream>>>(Qh, Kh, Kth, Vth, Vtl, Oh, Ol);

  k_proj<3><<<dim3(16,32), dim3(256), 0, stream>>>(Oh, Ol, wo_h, wo_l, bo, nullptr, nullptr,
                                                   nullptr, nullptr, nullptr, out);
}

// Round 14
// 319.590 us; speedup vs baseline: 2.0075x; 1.0947x over previous
//
#include <hip/hip_runtime.h>

typedef unsigned short u16;
typedef __attribute__((ext_vector_type(8))) short bf16x8;
typedef __attribute__((ext_vector_type(4))) short bf16x4;
typedef __attribute__((ext_vector_type(4))) float f32x4;
typedef __attribute__((ext_vector_type(4))) u16 u16x4;

#define C1 0.18033688011112042f   // log2(e)/8  (folds the 1/sqrt(64) score scale)
#define NEGM (-64.0f*C1)          // fixed-max offset in exp2 domain

#define GLDS(g, l) __builtin_amdgcn_global_load_lds( \
    (const __attribute__((address_space(1))) void*)(g), \
    (__attribute__((address_space(3))) void*)(l), 16, 0, 0)

__device__ __forceinline__ float fastexp2(float x){
  float r;
  asm("v_exp_f32 %0, %1" : "=v"(r) : "v"(x));
  return r;
}

// packed f32x2 -> bf16x2 (low16 = bf16(x0), high16 = bf16(x1)), 1 VALU op
__device__ __forceinline__ unsigned cvtpk(float x0, float x1){
  unsigned r;
  asm("v_cvt_pk_bf16_f32 %0, %1, %2" : "=v"(r) : "v"(x0), "v"(x1));
  return r;
}

__device__ __forceinline__ bf16x4 pk4(float x0, float x1, float x2, float x3){
  union { unsigned u[2]; bf16x4 b; } o;
  o.u[0] = cvtpk(x0, x1);
  o.u[1] = cvtpk(x2, x3);
  return o.b;
}

__device__ __forceinline__ u16 f2bf(float x){
  unsigned u = __float_as_uint(x);
  u += 0x7fffu + ((u >> 16) & 1u);
  return (u16)(u >> 16);
}
__device__ __forceinline__ float bf2f(u16 h){ return __uint_as_float(((unsigned)h) << 16); }
__device__ __forceinline__ void fsplit(float x, u16 &h, u16 &l){
  h = f2bf(x);
  l = f2bf(x - bf2f(h));
}

// LDS slot swizzle (involution per row; empirically the low-conflict pattern).
__device__ __forceinline__ int swz(int slot, int r){
  return slot ^ (r & 7);
}

__device__ __forceinline__ bf16x8 frag(const bf16x8* lds, int r, int slot){
  return lds[r*8 + swz(slot, r)];
}

// b64 sub-fragment (A-operand of 16x16x16). Data is stored half-swapped by
// row-bit-3 (see k_proj T-writes) so quarter-wave lanes cover all 32 banks.
__device__ __forceinline__ bf16x4 frag64(const bf16x8* lds, int r, int slot, int half){
  return ((const bf16x4*)&lds[r*8 + swz(slot, r)])[half ^ ((r >> 3) & 1)];
}

// GLDS tile staging: linear LDS dest (wave chunk + lane*16), inverse-swizzled
// global source column -> LDS position swz(c) holds data column c (rule #21).
template<int ROWS>
__device__ __forceinline__ void stage_glds(bf16x8* lds, const u16* __restrict__ g,
                                           size_t row0, int ldg, int col0, int tid, int w){
#pragma unroll
  for (int p = 0; p < ROWS/32; ++p){
    int idx = p*256 + tid;
    int r = idx >> 3, slot = idx & 7;
    int ss = swz(slot, r);
    GLDS(g + (row0 + (size_t)r)*(size_t)ldg + col0 + ss*8, &lds[p*256 + (w<<6)]);
  }
}

// split-bf16 3-term product: X*Y ~= Xh*Yh + Xh*Yl + Xl*Yh   (fp32 accumulate)
__device__ __forceinline__ f32x4 mfma3(bf16x8 xh, bf16x8 xl, bf16x8 yh, bf16x8 yl, f32x4 c){
  c = __builtin_amdgcn_mfma_f32_16x16x32_bf16(xh, yh, c, 0, 0, 0);
  c = __builtin_amdgcn_mfma_f32_16x16x32_bf16(xh, yl, c, 0, 0, 0);
  c = __builtin_amdgcn_mfma_f32_16x16x32_bf16(xl, yh, c, 0, 0, 0);
  return c;
}

// ---- C/D-layout -> B-fragment relayout via 4-lane shuffle (hi-only) ----------
// (used only for the q-rebuild at iteration ends, 4x per kernel)
__device__ __forceinline__ void exchange_hi(const f32x4* X, int srcA, int srcB, bool sel_hi,
                                            bf16x8& oh0, bf16x8& oh1)
{
  unsigned hi[8];
#pragma unroll
  for (int a = 0; a < 4; ++a)
#pragma unroll
    for (int b0 = 0; b0 < 2; ++b0)
      hi[a*2+b0] = cvtpk(X[a][2*b0], X[a][2*b0+1]);
  unsigned OH[8];
#pragma unroll
  for (int f = 0; f < 8; ++f){
    const int t0 = (f>>2)*4 + (f&1);
    const int sl = ((f&3)>>1) ? srcB : srcA;
    unsigned h0 = (unsigned)__shfl((int)hi[t0],     sl, 64);
    unsigned h2 = (unsigned)__shfl((int)hi[t0 + 2], sl, 64);
    OH[f] = sel_hi ? h2 : h0;
  }
  union U { unsigned u[4]; bf16x8 b; };
  U a0, a1;
#pragma unroll
  for (int c = 0; c < 4; ++c){ a0.u[c]=OH[c]; a1.u[c]=OH[4+c]; }
  oh0=a0.b; oh1=a1.b;
}

// ---------------- elementwise split (fused over q/k/v) ----------------
// q,k: hi only (their projections run hi-only). v: hi + lo residual.
__global__ void __launch_bounds__(256) k_split3(
    const float* __restrict__ xq, const float* __restrict__ xk, const float* __restrict__ xv,
    u16* __restrict__ qh,
    u16* __restrict__ kh,
    u16* __restrict__ vh, u16* __restrict__ vl, int n4){
  const int which = blockIdx.y;
  const float* x = which == 0 ? xq : which == 1 ? xk : xv;
  u16* hh = which == 0 ? qh : which == 1 ? kh : vh;
  for (int i = blockIdx.x*256 + threadIdx.x; i < n4; i += gridDim.x*256){
    float4 v = ((const float4*)x)[i];
    float a[4] = {v.x, v.y, v.z, v.w};
    u16x4 h;
    if (which == 2){
      u16x4 l;
#pragma unroll
      for (int j = 0; j < 4; ++j){ u16 p, q; fsplit(a[j], p, q); h[j] = p; l[j] = q; }
      *(u16x4*)(vl + (size_t)i*4) = l;
    } else {
#pragma unroll
      for (int j = 0; j < 4; ++j) h[j] = f2bf(a[j]);
    }
    *(u16x4*)(hh + (size_t)i*4) = h;
  }
}

// ---------------- weight transpose + split (fused over 4 weights) ----------------
// wq, wk: hi only. wv, wo: hi + lo.
__global__ void __launch_bounds__(256) k_wsplit4(
    const float* __restrict__ W0, const float* __restrict__ W1,
    const float* __restrict__ W2, const float* __restrict__ W3,
    u16* __restrict__ T0h, u16* __restrict__ T1h,
    u16* __restrict__ T2h, u16* __restrict__ T2l, u16* __restrict__ T3h, u16* __restrict__ T3l){
  const int which = blockIdx.z;
  const float* W = which == 0 ? W0 : which == 1 ? W1 : which == 2 ? W2 : W3;
  u16* Th = which == 0 ? T0h : which == 1 ? T1h : which == 2 ? T2h : T3h;
  u16* Tl = which == 2 ? T2l : T3l;
  __shared__ float t[32][33];
  int tx = threadIdx.x & 31, ty = threadIdx.x >> 5;      // 32 x 8
  int n0 = blockIdx.x*32, k0 = blockIdx.y*32;
#pragma unroll
  for (int i = 0; i < 4; ++i)
    t[ty + 8*i][tx] = W[(size_t)(k0 + ty + 8*i)*1024 + n0 + tx];
  __syncthreads();
#pragma unroll
  for (int i = 0; i < 4; ++i){
    int n = n0 + ty + 8*i, k = k0 + tx;
    if (which >= 2){
      u16 a, b; fsplit(t[tx][ty + 8*i], a, b);
      Th[(size_t)n*1024 + k] = a;
      Tl[(size_t)n*1024 + k] = b;
    } else {
      Th[(size_t)n*1024 + k] = f2bf(t[tx][ty + 8*i]);
    }
  }
}

// ---------------- projection / output GEMM ----------------
// C(4096x1024) = A(4096x1024) * Bt^T (+bias), tile 128x64, 4 waves x (32 rows x 64 cols)
// Staging via global_load_lds (linear dest + inverse-swizzled source).
// SPLIT=false: 1-term hi*hi GEMM (Q/K projections: outputs get LN'd then bf16-rounded,
// so split precision is wasted). SPLIT=true: 3-term split-bf16 (V, out-proj).
// MODE 0: Q  -> LN, natural head-major write (hi only)
// MODE 1: K  -> LN, natural + transposed writes (hi only; half-swapped T)
// MODE 2: V  -> transposed hi/lo split write (half-swapped)
// MODE 3: out-> fp32 write to d_out
template<int MODE, bool SPLIT>
__global__ void __launch_bounds__(256, 3) k_proj(
    const u16* __restrict__ Ah, const u16* __restrict__ Al,
    const u16* __restrict__ Bh, const u16* __restrict__ Bl,
    const float* __restrict__ bias, const float* __restrict__ gamma, const float* __restrict__ beta,
    u16* __restrict__ Nh,
    u16* __restrict__ Th, u16* __restrict__ Tl,
    float* __restrict__ Fo)
{
  __shared__ bf16x8 sAh[128*8], sBh[64*8];
  __shared__ bf16x8 sAl[SPLIT ? 128*8 : 1], sBl[SPLIT ? 64*8 : 1];
  const int tid = threadIdx.x, lane = tid & 63, w = tid >> 6;
  const int cl = lane & 15, gq = lane >> 4;
  const int nt = blockIdx.x, mt = blockIdx.y;
  f32x4 acc[2][4] = {};
  for (int kt = 0; kt < 16; ++kt){
    __syncthreads();
    stage_glds<128>(sAh, Ah, (size_t)mt*128, 1024, kt*64, tid, w);
    stage_glds<64>(sBh, Bh, (size_t)nt*64, 1024, kt*64, tid, w);
    if constexpr (SPLIT){
      stage_glds<128>(sAl, Al, (size_t)mt*128, 1024, kt*64, tid, w);
      stage_glds<64>(sBl, Bl, (size_t)nt*64, 1024, kt*64, tid, w);
    }
    __syncthreads();
#pragma unroll
    for (int ks = 0; ks < 2; ++ks){
      const int slot = ks*4 + gq;
      bf16x8 ah0 = frag(sAh, w*32 + cl, slot);
      bf16x8 ah1 = frag(sAh, w*32 + 16 + cl, slot);
      if constexpr (SPLIT){
        bf16x8 al0 = frag(sAl, w*32 + cl, slot);
        bf16x8 al1 = frag(sAl, w*32 + 16 + cl, slot);
#pragma unroll
        for (int f = 0; f < 4; ++f){
          bf16x8 bh_ = frag(sBh, f*16 + cl, slot);
          bf16x8 bl_ = frag(sBl, f*16 + cl, slot);
          acc[0][f] = mfma3(ah0, al0, bh_, bl_, acc[0][f]);
          acc[1][f] = mfma3(ah1, al1, bh_, bl_, acc[1][f]);
        }
      } else {
#pragma unroll
        for (int f = 0; f < 4; ++f){
          bf16x8 bh_ = frag(sBh, f*16 + cl, slot);
          acc[0][f] = __builtin_amdgcn_mfma_f32_16x16x32_bf16(ah0, bh_, acc[0][f], 0, 0, 0);
          acc[1][f] = __builtin_amdgcn_mfma_f32_16x16x32_bf16(ah1, bh_, acc[1][f], 0, 0, 0);
        }
      }
    }
  }
  float bv[4];
#pragma unroll
  for (int f = 0; f < 4; ++f) bv[f] = bias[nt*64 + f*16 + cl];
  float gm[4], bt[4];
  if constexpr (MODE <= 1){
#pragma unroll
    for (int f = 0; f < 4; ++f){ gm[f] = gamma[f*16 + cl]; bt[f] = beta[f*16 + cl]; }
  }
#pragma unroll
  for (int mi = 0; mi < 2; ++mi){
    float v[4][4];
#pragma unroll
    for (int f = 0; f < 4; ++f)
#pragma unroll
      for (int r = 0; r < 4; ++r) v[f][r] = acc[mi][f][r] + bv[f];
    if constexpr (MODE <= 1){
#pragma unroll
      for (int r = 0; r < 4; ++r){
        float s1 = v[0][r] + v[1][r] + v[2][r] + v[3][r];
        float s2 = v[0][r]*v[0][r] + v[1][r]*v[1][r] + v[2][r]*v[2][r] + v[3][r]*v[3][r];
#pragma unroll
        for (int d = 1; d < 16; d <<= 1){ s1 += __shfl_xor(s1, d); s2 += __shfl_xor(s2, d); }
        float mu = s1 * (1.f/64.f);
        float var = s2 * (1.f/64.f) - mu*mu;
        float rs = rsqrtf(var + 1e-5f);
#pragma unroll
        for (int f = 0; f < 4; ++f) v[f][r] = (v[f][r] - mu)*rs*gm[f] + bt[f];
      }
    }
    const int mrow = mt*128 + w*32 + mi*16 + gq*4;   // + r
    if constexpr (MODE == 3){
#pragma unroll
      for (int f = 0; f < 4; ++f)
#pragma unroll
        for (int r = 0; r < 4; ++r)
          Fo[(size_t)(mrow + r)*1024 + nt*64 + f*16 + cl] = v[f][r];
    } else {
      const int b = mrow >> 11, srow = mrow & 2047;
      const size_t hb = (size_t)(b*16 + nt);          // head-major (b*16 + head)
      if constexpr (MODE <= 1){                       // natural write, hi only
#pragma unroll
        for (int f = 0; f < 4; ++f)
#pragma unroll
          for (int r = 0; r < 4; ++r)
            Nh[(hb*2048 + srow + r)*64 + f*16 + cl] = f2bf(v[f][r]);
      }
      if constexpr (MODE == 1){                       // transposed write, hi only
        const int srow_sw = srow ^ (((cl >> 3) & 1) << 2);
#pragma unroll
        for (int f = 0; f < 4; ++f){
          u16x4 h4;
#pragma unroll
          for (int r = 0; r < 4; ++r) h4[r] = f2bf(v[f][r]);
          *(u16x4*)(Th + (hb*64 + f*16 + cl)*2048 + srow_sw) = h4;
        }
      }
      if constexpr (MODE == 2){                       // transposed write, hi+lo
        const int srow_sw = srow ^ (((cl >> 3) & 1) << 2);
#pragma unroll
        for (int f = 0; f < 4; ++f){
          u16x4 h4, l4;
#pragma unroll
          for (int r = 0; r < 4; ++r){ u16 a_, b_; fsplit(v[f][r], a_, b_); h4[r] = a_; l4[r] = b_; }
          size_t ix = (hb*64 + f*16 + cl)*2048 + srow_sw;
          *(u16x4*)(Th + ix) = h4;
          *(u16x4*)(Tl + ix) = l4;
        }
      }
    }
  }
}

// ---------------- fused Hopfield attention: all 4 iterations in one launch ----------------
// Block = 512 thr (8 waves), owns (bh, 128 q rows). Grid 512 = 2 blocks/CU.
// FIXED-MAX softmax (scores in [-64,64] deterministically -> m=64).
// Q, K, P all bf16 hi-only in the QK/softmax path. PV uses 16x16x16 MFMA: the
// QK C/D layout IS the native K=16 B-fragment -> NO cross-lane P relayout.
// Softmax denominator via MFMA: accL = mfma(ones, pf[a], accL) gives every lane
// the full column sum of P for its q (no VALU adds, no cross-lane reduce).
// T-operand read as b64 sub-frags with half-swapped storage (bank-spread).
// Update iters: PV on Kt-hi only. Final iteration: full V hi/lo.
__global__ void __launch_bounds__(512, 4) k_hopfield(
    const u16* __restrict__ Qh,
    const u16* __restrict__ Kh,
    const u16* __restrict__ Kth,
    const u16* __restrict__ Vth, const u16* __restrict__ Vtl,
    u16* __restrict__ Oh, u16* __restrict__ Ol)
{
  __shared__ bf16x8 sKh[2][512], sTh[2][512], sTl[2][512];
  const int tid = threadIdx.x, lane = tid & 63, w = tid >> 6;
  const int cl = lane & 15, gq = lane >> 4;
  int flat = blockIdx.x;
  flat = (flat & 7)*64 + (flat >> 3);              // XCD swizzle (512 % 8 == 0: bijective)
  const int bh = flat >> 4, qt = flat & 15;
  const size_t base = (size_t)bh * (2048*64);
  const int q = qt*128 + w*16 + cl;

  // staging geometry: thread stages slot idx=tid of each 64x64 tile; source column
  // pre-swizzled so the lane-linear LDS write yields the swizzled layout.
  const int sr = tid >> 3, ss = swz(tid & 7, sr);
  const size_t offK = base + (size_t)sr*64 + ss*8;      // + kt*4096
  const size_t offT = base + (size_t)sr*2048 + ss*8;    // + kt*64
  const int wslot = w << 6;                             // wave's LDS chunk (bf16x8 units)

  // q fragments (B-operand layout, hi-only), live across all 4 iterations
  bf16x8 qfh[2];
#pragma unroll
  for (int ks = 0; ks < 2; ++ks)
    qfh[ks] = *(const bf16x8*)(Qh + base + (size_t)q*64 + ks*32 + gq*8);

  const int srcA = cl + ((gq & 1) << 5);   // shuffle source lanes for exchange_hi()
  const int srcB = srcA + 16;
  const bool sel_hi = gq >= 2;             // dest-side select: t-offset = 2*(gq>>1)

  const bf16x4 ones = {(short)0x3F80, (short)0x3F80, (short)0x3F80, (short)0x3F80};
  f32x4 accL = {0,0,0,0};                  // P column-sums (softmax denominator)
  f32x4 accO[4] = {};

  // prologue: stage tile 0 (it=0 -> T source is Kt, hi only)
  GLDS(Kh  + offK, &sKh[0][wslot]);
  GLDS(Kth + offT, &sTh[0][wslot]);
  __syncthreads();

#pragma unroll 2
  for (int t = 0; t < 128; ++t){
    const int cur = t & 1, kt = t & 31;
    const bool fin = (t >= 96);
    if (t < 127){
      const int nt_ = t + 1, nb = nt_ & 1, nit = nt_ >> 5, nkt = nt_ & 31;
      const size_t oK = offK + (size_t)nkt*4096;
      const size_t oT = offT + (size_t)nkt*64;
      GLDS(Kh + oK, &sKh[nb][wslot]);
      if (nit < 3){
        GLDS(Kth + oT, &sTh[nb][wslot]);
      } else {
        GLDS(Vth + oT, &sTh[nb][wslot]);
        GLDS(Vtl + oT, &sTl[nb][wslot]);
      }
    }
    // ---- QK^T: St[kv][q] = Kh * Qh (hi-only both sides) ----
    f32x4 S[4] = {};
    __builtin_amdgcn_s_setprio(1);
#pragma unroll
    for (int ks = 0; ks < 2; ++ks){
      const int slot = ks*4 + gq;
#pragma unroll
      for (int i = 0; i < 4; ++i){
        bf16x8 kh_ = frag(&sKh[cur][0], i*16 + cl, slot);
        S[i] = __builtin_amdgcn_mfma_f32_16x16x32_bf16(kh_, qfh[ks], S[i], 0, 0, 0);
      }
    }
    __builtin_amdgcn_s_setprio(0);
    // ---- fixed-max softmax: p = exp2(S*C1 - 64*C1), no reductions at all ----
#pragma unroll
    for (int i = 0; i < 4; ++i)
#pragma unroll
      for (int r = 0; r < 4; ++r)
        S[i][r] = fastexp2(__builtin_fmaf(S[i][r], C1, NEGM));
    // ---- P already in native 16x16x16 B-frag layout: pack only ----
    bf16x4 pf[4];
#pragma unroll
    for (int a = 0; a < 4; ++a)
      pf[a] = pk4(S[a][0], S[a][1], S[a][2], S[a][3]);
    // ---- PV: O^T += T^T * P^T via 16x16x16; denominator via ones-MFMA ----
    __builtin_amdgcn_s_setprio(1);
#pragma unroll
    for (int a = 0; a < 4; ++a)
      accL = __builtin_amdgcn_mfma_f32_16x16x16bf16_1k(ones, pf[a], accL, 0, 0, 0);
    if (fin){
#pragma unroll
      for (int db = 0; db < 4; ++db)
#pragma unroll
        for (int a = 0; a < 4; ++a){
          bf16x4 vh_ = frag64(&sTh[cur][0], db*16 + cl, 2*a + (gq>>1), gq&1);
          bf16x4 vl_ = frag64(&sTl[cur][0], db*16 + cl, 2*a + (gq>>1), gq&1);
          accO[db] = __builtin_amdgcn_mfma_f32_16x16x16bf16_1k(vh_, pf[a], accO[db], 0, 0, 0);
          accO[db] = __builtin_amdgcn_mfma_f32_16x16x16bf16_1k(vl_, pf[a], accO[db], 0, 0, 0);
        }
    } else {
#pragma unroll
      for (int db = 0; db < 4; ++db)
#pragma unroll
        for (int a = 0; a < 4; ++a){
          bf16x4 vh_ = frag64(&sTh[cur][0], db*16 + cl, 2*a + (gq>>1), gq&1);
          accO[db] = __builtin_amdgcn_mfma_f32_16x16x16bf16_1k(vh_, pf[a], accO[db], 0, 0, 0);
        }
    }
    __builtin_amdgcn_s_setprio(0);
    // ---- iteration epilogue ----
    if (kt == 31){
      const float inv = 1.f / accL[0];     // accL rows identical: full Σp for q=cl
      f32x4 vals[4];
#pragma unroll
      for (int db = 0; db < 4; ++db)
#pragma unroll
        for (int r = 0; r < 4; ++r) vals[db][r] = accO[db][r]*inv;
      if (t < 127){
        exchange_hi(vals, srcA, srcB, sel_hi, qfh[0], qfh[1]);
        accL = f32x4{0,0,0,0};
#pragma unroll
        for (int db = 0; db < 4; ++db) accO[db] = f32x4{0,0,0,0};
      } else {
        const int b = bh >> 4, h = bh & 15;
        const size_t row = (size_t)b*2048 + q;
#pragma unroll
        for (int db = 0; db < 4; ++db){
          u16x4 h4, l4;
#pragma unroll
          for (int r = 0; r < 4; ++r){ u16 a_, b_; fsplit(vals[db][r], a_, b_); h4[r] = a_; l4[r] = b_; }
          size_t ix = row*1024 + h*64 + db*16 + gq*4;
          *(u16x4*)(Oh + ix) = h4;
          *(u16x4*)(Ol + ix) = l4;
        }
      }
    }
    __syncthreads();
  }
}

extern "C" void kernel_launch(void* const* d_in, const int* in_sizes, int n_in,
                              void* d_out, int out_size, void* d_ws, size_t ws_size,
                              hipStream_t stream) {
  (void)in_sizes; (void)n_in; (void)out_size; (void)ws_size;
  const float* query = (const float*)d_in[0];
  const float* key   = (const float*)d_in[1];
  const float* value = (const float*)d_in[2];
  const float* Wq = (const float*)d_in[3];
  const float* bq = (const float*)d_in[4];
  const float* Wk = (const float*)d_in[5];
  const float* bk = (const float*)d_in[6];
  const float* Wv = (const float*)d_in[7];
  const float* bv = (const float*)d_in[8];
  const float* Wo = (const float*)d_in[9];
  const float* bo = (const float*)d_in[10];
  const float* gamma = (const float*)d_in[11];
  const float* beta  = (const float*)d_in[12];
  float* out = (float*)d_out;

  char* ws = (char*)d_ws;
  const size_t MB = 1024*1024;
  u16* inq_h = (u16*)(ws + 0*MB),  *inq_l = (u16*)(ws + 8*MB);
  u16* ink_h = (u16*)(ws + 16*MB);
  u16* inv_h = (u16*)(ws + 32*MB), *inv_l = (u16*)(ws + 40*MB);
  u16* wq_h = (u16*)(ws + 48*MB);
  u16* wk_h = (u16*)(ws + 52*MB);
  u16* wv_h = (u16*)(ws + 56*MB), *wv_l = (u16*)(ws + 58*MB);
  u16* wo_h = (u16*)(ws + 60*MB), *wo_l = (u16*)(ws + 62*MB);
  u16* Qh  = (u16*)(ws + 64*MB);
  u16* Kh  = (u16*)(ws + 80*MB);
  u16* Kth = (u16*)(ws + 96*MB);
  u16* Vth = (u16*)(ws + 112*MB), *Vtl = (u16*)(ws + 120*MB);
  u16* Oh = inq_h, *Ol = inq_l;    // reuse: inq dead after proj<0>

  const int n4 = 4096*1024/4;
  k_split3<<<dim3(1024, 3), dim3(256), 0, stream>>>(query, key, value,
                                                    inq_h, ink_h, inv_h, inv_l, n4);
  k_wsplit4<<<dim3(32,32,4), dim3(256), 0, stream>>>(Wq, Wk, Wv, Wo,
                                                     wq_h, wk_h,
                                                     wv_h, wv_l, wo_h, wo_l);

  k_proj<0,false><<<dim3(16,32), dim3(256), 0, stream>>>(inq_h, nullptr, wq_h, nullptr, bq, gamma, beta,
                                                         Qh, nullptr, nullptr, nullptr);
  k_proj<1,false><<<dim3(16,32), dim3(256), 0, stream>>>(ink_h, nullptr, wk_h, nullptr, bk, gamma, beta,
                                                         Kh, Kth, nullptr, nullptr);
  k_proj<2,true><<<dim3(16,32), dim3(256), 0, stream>>>(inv_h, inv_l, wv_h, wv_l, bv, nullptr, nullptr,
                                                        nullptr, Vth, Vtl, nullptr);

  k_hopfield<<<dim3(512), dim3(512), 0, stream>>>(Qh, Kh, Kth, Vth, Vtl, Oh, Ol);

  k_proj<3,true><<<dim3(16,32), dim3(256), 0, stream>>>(Oh, Ol, wo_h, wo_l, bo, nullptr, nullptr,
                                                        nullptr, nullptr, nullptr, out);
}

// Round 15
// 304.089 us; speedup vs baseline: 2.1098x; 1.0510x over previous
//
#include <hip/hip_runtime.h>

typedef unsigned short u16;
typedef __attribute__((ext_vector_type(8))) short bf16x8;
typedef __attribute__((ext_vector_type(4))) short bf16x4;
typedef __attribute__((ext_vector_type(4))) float f32x4;
typedef __attribute__((ext_vector_type(4))) u16 u16x4;

#define C1 0.18033688011112042f   // log2(e)/8  (folds the 1/sqrt(64) score scale)
#define NEGM (-64.0f*C1)          // fixed-max offset in exp2 domain

#define GLDS(g, l) __builtin_amdgcn_global_load_lds( \
    (const __attribute__((address_space(1))) void*)(g), \
    (__attribute__((address_space(3))) void*)(l), 16, 0, 0)

__device__ __forceinline__ float fastexp2(float x){
  float r;
  asm("v_exp_f32 %0, %1" : "=v"(r) : "v"(x));
  return r;
}

// packed f32x2 -> bf16x2 (low16 = bf16(x0), high16 = bf16(x1)), 1 VALU op
__device__ __forceinline__ unsigned cvtpk(float x0, float x1){
  unsigned r;
  asm("v_cvt_pk_bf16_f32 %0, %1, %2" : "=v"(r) : "v"(x0), "v"(x1));
  return r;
}

__device__ __forceinline__ bf16x4 pk4(float x0, float x1, float x2, float x3){
  union { unsigned u[2]; bf16x4 b; } o;
  o.u[0] = cvtpk(x0, x1);
  o.u[1] = cvtpk(x2, x3);
  return o.b;
}

__device__ __forceinline__ u16 f2bf(float x){
  unsigned u = __float_as_uint(x);
  u += 0x7fffu + ((u >> 16) & 1u);
  return (u16)(u >> 16);
}
__device__ __forceinline__ float bf2f(u16 h){ return __uint_as_float(((unsigned)h) << 16); }
__device__ __forceinline__ void fsplit(float x, u16 &h, u16 &l){
  h = f2bf(x);
  l = f2bf(x - bf2f(h));
}

// LDS slot swizzle (involution per row; empirically the low-conflict pattern).
__device__ __forceinline__ int swz(int slot, int r){
  return slot ^ (r & 7);
}

__device__ __forceinline__ bf16x8 frag(const bf16x8* lds, int r, int slot){
  return lds[r*8 + swz(slot, r)];
}

// b64 sub-fragment (A-operand of 16x16x16). Data is stored half-swapped by
// row-bit-3 (see k_proj T-writes) so quarter-wave lanes cover all 32 banks.
__device__ __forceinline__ bf16x4 frag64(const bf16x8* lds, int r, int slot, int half){
  return ((const bf16x4*)&lds[r*8 + swz(slot, r)])[half ^ ((r >> 3) & 1)];
}

// GLDS tile staging: linear LDS dest (wave chunk + lane*16), inverse-swizzled
// global source column -> LDS position swz(c) holds data column c (rule #21).
template<int ROWS>
__device__ __forceinline__ void stage_glds(bf16x8* lds, const u16* __restrict__ g,
                                           size_t row0, int ldg, int col0, int tid, int w){
#pragma unroll
  for (int p = 0; p < ROWS/32; ++p){
    int idx = p*256 + tid;
    int r = idx >> 3, slot = idx & 7;
    int ss = swz(slot, r);
    GLDS(g + (row0 + (size_t)r)*(size_t)ldg + col0 + ss*8, &lds[p*256 + (w<<6)]);
  }
}

// split-bf16 3-term product: X*Y ~= Xh*Yh + Xh*Yl + Xl*Yh   (fp32 accumulate)
__device__ __forceinline__ f32x4 mfma3(bf16x8 xh, bf16x8 xl, bf16x8 yh, bf16x8 yl, f32x4 c){
  c = __builtin_amdgcn_mfma_f32_16x16x32_bf16(xh, yh, c, 0, 0, 0);
  c = __builtin_amdgcn_mfma_f32_16x16x32_bf16(xh, yl, c, 0, 0, 0);
  c = __builtin_amdgcn_mfma_f32_16x16x32_bf16(xl, yh, c, 0, 0, 0);
  return c;
}

// ---- C/D-layout -> B-fragment relayout via 4-lane shuffle (hi-only) ----------
// (used only for the q-rebuild at iteration ends, 4x per kernel)
__device__ __forceinline__ void exchange_hi(const f32x4* X, int srcA, int srcB, bool sel_hi,
                                            bf16x8& oh0, bf16x8& oh1)
{
  unsigned hi[8];
#pragma unroll
  for (int a = 0; a < 4; ++a)
#pragma unroll
    for (int b0 = 0; b0 < 2; ++b0)
      hi[a*2+b0] = cvtpk(X[a][2*b0], X[a][2*b0+1]);
  unsigned OH[8];
#pragma unroll
  for (int f = 0; f < 8; ++f){
    const int t0 = (f>>2)*4 + (f&1);
    const int sl = ((f&3)>>1) ? srcB : srcA;
    unsigned h0 = (unsigned)__shfl((int)hi[t0],     sl, 64);
    unsigned h2 = (unsigned)__shfl((int)hi[t0 + 2], sl, 64);
    OH[f] = sel_hi ? h2 : h0;
  }
  union U { unsigned u[4]; bf16x8 b; };
  U a0, a1;
#pragma unroll
  for (int c = 0; c < 4; ++c){ a0.u[c]=OH[c]; a1.u[c]=OH[4+c]; }
  oh0=a0.b; oh1=a1.b;
}

// ---------------- elementwise convert (fused over q/k/v): fp32 -> bf16 hi ----------------
// All three projections now run 1-term hi GEMMs; lo residuals are never read.
__global__ void __launch_bounds__(256) k_split3(
    const float* __restrict__ xq, const float* __restrict__ xk, const float* __restrict__ xv,
    u16* __restrict__ qh, u16* __restrict__ kh, u16* __restrict__ vh, int n4){
  const int which = blockIdx.y;
  const float* x = which == 0 ? xq : which == 1 ? xk : xv;
  u16* hh = which == 0 ? qh : which == 1 ? kh : vh;
  for (int i = blockIdx.x*256 + threadIdx.x; i < n4; i += gridDim.x*256){
    float4 v = ((const float4*)x)[i];
    u16x4 h;
    h[0] = f2bf(v.x); h[1] = f2bf(v.y); h[2] = f2bf(v.z); h[3] = f2bf(v.w);
    *(u16x4*)(hh + (size_t)i*4) = h;
  }
}

// ---------------- weight transpose + split (fused over 4 weights) ----------------
// wq, wk, wv: hi only. wo: hi + lo (out-proj stays 3-term for output precision).
__global__ void __launch_bounds__(256) k_wsplit4(
    const float* __restrict__ W0, const float* __restrict__ W1,
    const float* __restrict__ W2, const float* __restrict__ W3,
    u16* __restrict__ T0h, u16* __restrict__ T1h, u16* __restrict__ T2h,
    u16* __restrict__ T3h, u16* __restrict__ T3l){
  const int which = blockIdx.z;
  const float* W = which == 0 ? W0 : which == 1 ? W1 : which == 2 ? W2 : W3;
  u16* Th = which == 0 ? T0h : which == 1 ? T1h : which == 2 ? T2h : T3h;
  __shared__ float t[32][33];
  int tx = threadIdx.x & 31, ty = threadIdx.x >> 5;      // 32 x 8
  int n0 = blockIdx.x*32, k0 = blockIdx.y*32;
#pragma unroll
  for (int i = 0; i < 4; ++i)
    t[ty + 8*i][tx] = W[(size_t)(k0 + ty + 8*i)*1024 + n0 + tx];
  __syncthreads();
#pragma unroll
  for (int i = 0; i < 4; ++i){
    int n = n0 + ty + 8*i, k = k0 + tx;
    if (which == 3){
      u16 a, b; fsplit(t[tx][ty + 8*i], a, b);
      Th[(size_t)n*1024 + k] = a;
      T3l[(size_t)n*1024 + k] = b;
    } else {
      Th[(size_t)n*1024 + k] = f2bf(t[tx][ty + 8*i]);
    }
  }
}

// ---------------- projection / output GEMM ----------------
// C(4096x1024) = A(4096x1024) * Bt^T (+bias), tile 128x64, 4 waves x (32 rows x 64 cols)
// Staging via global_load_lds (linear dest + inverse-swizzled source).
// SPLIT=false: 1-term hi*hi GEMM (Q/K/V projections — downstream tolerance absorbs
// the bf16 GEMM error). SPLIT=true: 3-term split-bf16 (out-proj only).
// MODE 0: Q  -> LN, natural head-major write (hi only)
// MODE 1: K  -> LN, natural + transposed writes (hi only; half-swapped T)
// MODE 2: V  -> transposed hi/lo split write of the fp32 accumulator (half-swapped)
// MODE 3: out-> fp32 write to d_out
template<int MODE, bool SPLIT>
__global__ void __launch_bounds__(256, 3) k_proj(
    const u16* __restrict__ Ah, const u16* __restrict__ Al,
    const u16* __restrict__ Bh, const u16* __restrict__ Bl,
    const float* __restrict__ bias, const float* __restrict__ gamma, const float* __restrict__ beta,
    u16* __restrict__ Nh,
    u16* __restrict__ Th, u16* __restrict__ Tl,
    float* __restrict__ Fo)
{
  __shared__ bf16x8 sAh[128*8], sBh[64*8];
  __shared__ bf16x8 sAl[SPLIT ? 128*8 : 1], sBl[SPLIT ? 64*8 : 1];
  const int tid = threadIdx.x, lane = tid & 63, w = tid >> 6;
  const int cl = lane & 15, gq = lane >> 4;
  const int nt = blockIdx.x, mt = blockIdx.y;
  f32x4 acc[2][4] = {};
  for (int kt = 0; kt < 16; ++kt){
    __syncthreads();
    stage_glds<128>(sAh, Ah, (size_t)mt*128, 1024, kt*64, tid, w);
    stage_glds<64>(sBh, Bh, (size_t)nt*64, 1024, kt*64, tid, w);
    if constexpr (SPLIT){
      stage_glds<128>(sAl, Al, (size_t)mt*128, 1024, kt*64, tid, w);
      stage_glds<64>(sBl, Bl, (size_t)nt*64, 1024, kt*64, tid, w);
    }
    __syncthreads();
#pragma unroll
    for (int ks = 0; ks < 2; ++ks){
      const int slot = ks*4 + gq;
      bf16x8 ah0 = frag(sAh, w*32 + cl, slot);
      bf16x8 ah1 = frag(sAh, w*32 + 16 + cl, slot);
      if constexpr (SPLIT){
        bf16x8 al0 = frag(sAl, w*32 + cl, slot);
        bf16x8 al1 = frag(sAl, w*32 + 16 + cl, slot);
#pragma unroll
        for (int f = 0; f < 4; ++f){
          bf16x8 bh_ = frag(sBh, f*16 + cl, slot);
          bf16x8 bl_ = frag(sBl, f*16 + cl, slot);
          acc[0][f] = mfma3(ah0, al0, bh_, bl_, acc[0][f]);
          acc[1][f] = mfma3(ah1, al1, bh_, bl_, acc[1][f]);
        }
      } else {
#pragma unroll
        for (int f = 0; f < 4; ++f){
          bf16x8 bh_ = frag(sBh, f*16 + cl, slot);
          acc[0][f] = __builtin_amdgcn_mfma_f32_16x16x32_bf16(ah0, bh_, acc[0][f], 0, 0, 0);
          acc[1][f] = __builtin_amdgcn_mfma_f32_16x16x32_bf16(ah1, bh_, acc[1][f], 0, 0, 0);
        }
      }
    }
  }
  float bv[4];
#pragma unroll
  for (int f = 0; f < 4; ++f) bv[f] = bias[nt*64 + f*16 + cl];
  float gm[4], bt[4];
  if constexpr (MODE <= 1){
#pragma unroll
    for (int f = 0; f < 4; ++f){ gm[f] = gamma[f*16 + cl]; bt[f] = beta[f*16 + cl]; }
  }
#pragma unroll
  for (int mi = 0; mi < 2; ++mi){
    float v[4][4];
#pragma unroll
    for (int f = 0; f < 4; ++f)
#pragma unroll
      for (int r = 0; r < 4; ++r) v[f][r] = acc[mi][f][r] + bv[f];
    if constexpr (MODE <= 1){
#pragma unroll
      for (int r = 0; r < 4; ++r){
        float s1 = v[0][r] + v[1][r] + v[2][r] + v[3][r];
        float s2 = v[0][r]*v[0][r] + v[1][r]*v[1][r] + v[2][r]*v[2][r] + v[3][r]*v[3][r];
#pragma unroll
        for (int d = 1; d < 16; d <<= 1){ s1 += __shfl_xor(s1, d); s2 += __shfl_xor(s2, d); }
        float mu = s1 * (1.f/64.f);
        float var = s2 * (1.f/64.f) - mu*mu;
        float rs = rsqrtf(var + 1e-5f);
#pragma unroll
        for (int f = 0; f < 4; ++f) v[f][r] = (v[f][r] - mu)*rs*gm[f] + bt[f];
      }
    }
    const int mrow = mt*128 + w*32 + mi*16 + gq*4;   // + r
    if constexpr (MODE == 3){
#pragma unroll
      for (int f = 0; f < 4; ++f)
#pragma unroll
        for (int r = 0; r < 4; ++r)
          Fo[(size_t)(mrow + r)*1024 + nt*64 + f*16 + cl] = v[f][r];
    } else {
      const int b = mrow >> 11, srow = mrow & 2047;
      const size_t hb = (size_t)(b*16 + nt);          // head-major (b*16 + head)
      if constexpr (MODE <= 1){                       // natural write, hi only
#pragma unroll
        for (int f = 0; f < 4; ++f)
#pragma unroll
          for (int r = 0; r < 4; ++r)
            Nh[(hb*2048 + srow + r)*64 + f*16 + cl] = f2bf(v[f][r]);
      }
      if constexpr (MODE == 1){                       // transposed write, hi only
        const int srow_sw = srow ^ (((cl >> 3) & 1) << 2);
#pragma unroll
        for (int f = 0; f < 4; ++f){
          u16x4 h4;
#pragma unroll
          for (int r = 0; r < 4; ++r) h4[r] = f2bf(v[f][r]);
          *(u16x4*)(Th + (hb*64 + f*16 + cl)*2048 + srow_sw) = h4;
        }
      }
      if constexpr (MODE == 2){                       // transposed write, hi+lo
        const int srow_sw = srow ^ (((cl >> 3) & 1) << 2);
#pragma unroll
        for (int f = 0; f < 4; ++f){
          u16x4 h4, l4;
#pragma unroll
          for (int r = 0; r < 4; ++r){ u16 a_, b_; fsplit(v[f][r], a_, b_); h4[r] = a_; l4[r] = b_; }
          size_t ix = (hb*64 + f*16 + cl)*2048 + srow_sw;
          *(u16x4*)(Th + ix) = h4;
          *(u16x4*)(Tl + ix) = l4;
        }
      }
    }
  }
}

// ---------------- fused Hopfield attention: all 4 iterations in one launch ----------------
// Block = 512 thr (8 waves), owns (bh, 128 q rows). Grid 512 = 2 blocks/CU.
// FIXED-MAX softmax (scores in [-64,64] deterministically -> m=64).
// Q, K, P all bf16 hi-only in the QK/softmax path. PV uses 16x16x16 MFMA: the
// QK C/D layout IS the native K=16 B-fragment -> NO cross-lane P relayout.
// Softmax denominator via MFMA: accL = mfma(ones, pf[a], accL) gives every lane
// the full column sum of P for its q (no VALU adds, no cross-lane reduce).
// T-operand read as b64 sub-frags with half-swapped storage (bank-spread).
// Update iters: PV on Kt-hi only. Final iteration: full V hi/lo.
__global__ void __launch_bounds__(512, 4) k_hopfield(
    const u16* __restrict__ Qh,
    const u16* __restrict__ Kh,
    const u16* __restrict__ Kth,
    const u16* __restrict__ Vth, const u16* __restrict__ Vtl,
    u16* __restrict__ Oh, u16* __restrict__ Ol)
{
  __shared__ bf16x8 sKh[2][512], sTh[2][512], sTl[2][512];
  const int tid = threadIdx.x, lane = tid & 63, w = tid >> 6;
  const int cl = lane & 15, gq = lane >> 4;
  int flat = blockIdx.x;
  flat = (flat & 7)*64 + (flat >> 3);              // XCD swizzle (512 % 8 == 0: bijective)
  const int bh = flat >> 4, qt = flat & 15;
  const size_t base = (size_t)bh * (2048*64);
  const int q = qt*128 + w*16 + cl;

  // staging geometry: thread stages slot idx=tid of each 64x64 tile; source column
  // pre-swizzled so the lane-linear LDS write yields the swizzled layout.
  const int sr = tid >> 3, ss = swz(tid & 7, sr);
  const size_t offK = base + (size_t)sr*64 + ss*8;      // + kt*4096
  const size_t offT = base + (size_t)sr*2048 + ss*8;    // + kt*64
  const int wslot = w << 6;                             // wave's LDS chunk (bf16x8 units)

  // q fragments (B-operand layout, hi-only), live across all 4 iterations
  bf16x8 qfh[2];
#pragma unroll
  for (int ks = 0; ks < 2; ++ks)
    qfh[ks] = *(const bf16x8*)(Qh + base + (size_t)q*64 + ks*32 + gq*8);

  const int srcA = cl + ((gq & 1) << 5);   // shuffle source lanes for exchange_hi()
  const int srcB = srcA + 16;
  const bool sel_hi = gq >= 2;             // dest-side select: t-offset = 2*(gq>>1)

  const bf16x4 ones = {(short)0x3F80, (short)0x3F80, (short)0x3F80, (short)0x3F80};
  f32x4 accL = {0,0,0,0};                  // P column-sums (softmax denominator)
  f32x4 accO[4] = {};

  // prologue: stage tile 0 (it=0 -> T source is Kt, hi only)
  GLDS(Kh  + offK, &sKh[0][wslot]);
  GLDS(Kth + offT, &sTh[0][wslot]);
  __syncthreads();

#pragma unroll 2
  for (int t = 0; t < 128; ++t){
    const int cur = t & 1, kt = t & 31;
    const bool fin = (t >= 96);
    if (t < 127){
      const int nt_ = t + 1, nb = nt_ & 1, nit = nt_ >> 5, nkt = nt_ & 31;
      const size_t oK = offK + (size_t)nkt*4096;
      const size_t oT = offT + (size_t)nkt*64;
      GLDS(Kh + oK, &sKh[nb][wslot]);
      if (nit < 3){
        GLDS(Kth + oT, &sTh[nb][wslot]);
      } else {
        GLDS(Vth + oT, &sTh[nb][wslot]);
        GLDS(Vtl + oT, &sTl[nb][wslot]);
      }
    }
    // ---- QK^T: St[kv][q] = Kh * Qh (hi-only both sides) ----
    f32x4 S[4] = {};
    __builtin_amdgcn_s_setprio(1);
#pragma unroll
    for (int ks = 0; ks < 2; ++ks){
      const int slot = ks*4 + gq;
#pragma unroll
      for (int i = 0; i < 4; ++i){
        bf16x8 kh_ = frag(&sKh[cur][0], i*16 + cl, slot);
        S[i] = __builtin_amdgcn_mfma_f32_16x16x32_bf16(kh_, qfh[ks], S[i], 0, 0, 0);
      }
    }
    __builtin_amdgcn_s_setprio(0);
    // ---- fixed-max softmax: p = exp2(S*C1 - 64*C1), no reductions at all ----
#pragma unroll
    for (int i = 0; i < 4; ++i)
#pragma unroll
      for (int r = 0; r < 4; ++r)
        S[i][r] = fastexp2(__builtin_fmaf(S[i][r], C1, NEGM));
    // ---- P already in native 16x16x16 B-frag layout: pack only ----
    bf16x4 pf[4];
#pragma unroll
    for (int a = 0; a < 4; ++a)
      pf[a] = pk4(S[a][0], S[a][1], S[a][2], S[a][3]);
    // ---- PV: O^T += T^T * P^T via 16x16x16; denominator via ones-MFMA ----
    __builtin_amdgcn_s_setprio(1);
#pragma unroll
    for (int a = 0; a < 4; ++a)
      accL = __builtin_amdgcn_mfma_f32_16x16x16bf16_1k(ones, pf[a], accL, 0, 0, 0);
    if (fin){
#pragma unroll
      for (int db = 0; db < 4; ++db)
#pragma unroll
        for (int a = 0; a < 4; ++a){
          bf16x4 vh_ = frag64(&sTh[cur][0], db*16 + cl, 2*a + (gq>>1), gq&1);
          bf16x4 vl_ = frag64(&sTl[cur][0], db*16 + cl, 2*a + (gq>>1), gq&1);
          accO[db] = __builtin_amdgcn_mfma_f32_16x16x16bf16_1k(vh_, pf[a], accO[db], 0, 0, 0);
          accO[db] = __builtin_amdgcn_mfma_f32_16x16x16bf16_1k(vl_, pf[a], accO[db], 0, 0, 0);
        }
    } else {
#pragma unroll
      for (int db = 0; db < 4; ++db)
#pragma unroll
        for (int a = 0; a < 4; ++a){
          bf16x4 vh_ = frag64(&sTh[cur][0], db*16 + cl, 2*a + (gq>>1), gq&1);
          accO[db] = __builtin_amdgcn_mfma_f32_16x16x16bf16_1k(vh_, pf[a], accO[db], 0, 0, 0);
        }
    }
    __builtin_amdgcn_s_setprio(0);
    // ---- iteration epilogue ----
    if (kt == 31){
      const float inv = 1.f / accL[0];     // accL rows identical: full Σp for q=cl
      f32x4 vals[4];
#pragma unroll
      for (int db = 0; db < 4; ++db)
#pragma unroll
        for (int r = 0; r < 4; ++r) vals[db][r] = accO[db][r]*inv;
      if (t < 127){
        exchange_hi(vals, srcA, srcB, sel_hi, qfh[0], qfh[1]);
        accL = f32x4{0,0,0,0};
#pragma unroll
        for (int db = 0; db < 4; ++db) accO[db] = f32x4{0,0,0,0};
      } else {
        const int b = bh >> 4, h = bh & 15;
        const size_t row = (size_t)b*2048 + q;
#pragma unroll
        for (int db = 0; db < 4; ++db){
          u16x4 h4, l4;
#pragma unroll
          for (int r = 0; r < 4; ++r){ u16 a_, b_; fsplit(vals[db][r], a_, b_); h4[r] = a_; l4[r] = b_; }
          size_t ix = row*1024 + h*64 + db*16 + gq*4;
          *(u16x4*)(Oh + ix) = h4;
          *(u16x4*)(Ol + ix) = l4;
        }
      }
    }
    __syncthreads();
  }
}

extern "C" void kernel_launch(void* const* d_in, const int* in_sizes, int n_in,
                              void* d_out, int out_size, void* d_ws, size_t ws_size,
                              hipStream_t stream) {
  (void)in_sizes; (void)n_in; (void)out_size; (void)ws_size;
  const float* query = (const float*)d_in[0];
  const float* key   = (const float*)d_in[1];
  const float* value = (const float*)d_in[2];
  const float* Wq = (const float*)d_in[3];
  const float* bq = (const float*)d_in[4];
  const float* Wk = (const float*)d_in[5];
  const float* bk = (const float*)d_in[6];
  const float* Wv = (const float*)d_in[7];
  const float* bv = (const float*)d_in[8];
  const float* Wo = (const float*)d_in[9];
  const float* bo = (const float*)d_in[10];
  const float* gamma = (const float*)d_in[11];
  const float* beta  = (const float*)d_in[12];
  float* out = (float*)d_out;

  char* ws = (char*)d_ws;
  const size_t MB = 1024*1024;
  u16* inq_h = (u16*)(ws + 0*MB),  *inq_l = (u16*)(ws + 8*MB);
  u16* ink_h = (u16*)(ws + 16*MB);
  u16* inv_h = (u16*)(ws + 32*MB);
  u16* wq_h = (u16*)(ws + 48*MB);
  u16* wk_h = (u16*)(ws + 52*MB);
  u16* wv_h = (u16*)(ws + 56*MB);
  u16* wo_h = (u16*)(ws + 60*MB), *wo_l = (u16*)(ws + 62*MB);
  u16* Qh  = (u16*)(ws + 64*MB);
  u16* Kh  = (u16*)(ws + 80*MB);
  u16* Kth = (u16*)(ws + 96*MB);
  u16* Vth = (u16*)(ws + 112*MB), *Vtl = (u16*)(ws + 120*MB);
  u16* Oh = inq_h, *Ol = inq_l;    // reuse: inq dead after proj<0>

  const int n4 = 4096*1024/4;
  k_split3<<<dim3(1024, 3), dim3(256), 0, stream>>>(query, key, value,
                                                    inq_h, ink_h, inv_h, n4);
  k_wsplit4<<<dim3(32,32,4), dim3(256), 0, stream>>>(Wq, Wk, Wv, Wo,
                                                     wq_h, wk_h, wv_h, wo_h, wo_l);

  k_proj<0,false><<<dim3(16,32), dim3(256), 0, stream>>>(inq_h, nullptr, wq_h, nullptr, bq, gamma, beta,
                                                         Qh, nullptr, nullptr, nullptr);
  k_proj<1,false><<<dim3(16,32), dim3(256), 0, stream>>>(ink_h, nullptr, wk_h, nullptr, bk, gamma, beta,
                                                         Kh, Kth, nullptr, nullptr);
  k_proj<2,false><<<dim3(16,32), dim3(256), 0, stream>>>(inv_h, nullptr, wv_h, nullptr, bv, nullptr, nullptr,
                                                         nullptr, Vth, Vtl, nullptr);

  k_hopfield<<<dim3(512), dim3(512), 0, stream>>>(Qh, Kh, Kth, Vth, Vtl, Oh, Ol);

  k_proj<3,true><<<dim3(16,32), dim3(256), 0, stream>>>(Oh, Ol, wo_h, wo_l, bo, nullptr, nullptr,
                                                        nullptr, nullptr, nullptr, out);
}

// Round 16
// 281.093 us; speedup vs baseline: 2.2825x; 1.0818x over previous
//
#include <hip/hip_runtime.h>

typedef unsigned short u16;
typedef __attribute__((ext_vector_type(8))) short bf16x8;
typedef __attribute__((ext_vector_type(4))) short bf16x4;
typedef __attribute__((ext_vector_type(4))) float f32x4;
typedef __attribute__((ext_vector_type(4))) u16 u16x4;

#define C1 0.18033688011112042f   // log2(e)/8  (folds the 1/sqrt(64) score scale)
#define NEGM (-64.0f*C1)          // fixed-max offset in exp2 domain

#define GLDS(g, l) __builtin_amdgcn_global_load_lds( \
    (const __attribute__((address_space(1))) void*)(g), \
    (__attribute__((address_space(3))) void*)(l), 16, 0, 0)

__device__ __forceinline__ float fastexp2(float x){
  float r;
  asm("v_exp_f32 %0, %1" : "=v"(r) : "v"(x));
  return r;
}

// packed f32x2 -> bf16x2 (low16 = bf16(x0), high16 = bf16(x1)), 1 VALU op
__device__ __forceinline__ unsigned cvtpk(float x0, float x1){
  unsigned r;
  asm("v_cvt_pk_bf16_f32 %0, %1, %2" : "=v"(r) : "v"(x0), "v"(x1));
  return r;
}

__device__ __forceinline__ bf16x4 pk4(float x0, float x1, float x2, float x3){
  union { unsigned u[2]; bf16x4 b; } o;
  o.u[0] = cvtpk(x0, x1);
  o.u[1] = cvtpk(x2, x3);
  return o.b;
}

__device__ __forceinline__ u16 f2bf(float x){
  unsigned u = __float_as_uint(x);
  u += 0x7fffu + ((u >> 16) & 1u);
  return (u16)(u >> 16);
}
__device__ __forceinline__ float bf2f(u16 h){ return __uint_as_float(((unsigned)h) << 16); }
__device__ __forceinline__ void fsplit(float x, u16 &h, u16 &l){
  h = f2bf(x);
  l = f2bf(x - bf2f(h));
}

// LDS slot swizzle (involution per row; empirically the low-conflict pattern).
__device__ __forceinline__ int swz(int slot, int r){
  return slot ^ (r & 7);
}

__device__ __forceinline__ bf16x8 frag(const bf16x8* lds, int r, int slot){
  return lds[r*8 + swz(slot, r)];
}

// b64 sub-fragment (A-operand of 16x16x16). Data is stored half-swapped by
// row-bit-3 (see k_proj T-writes) so quarter-wave lanes cover all 32 banks.
__device__ __forceinline__ bf16x4 frag64(const bf16x8* lds, int r, int slot, int half){
  return ((const bf16x4*)&lds[r*8 + swz(slot, r)])[half ^ ((r >> 3) & 1)];
}

// GLDS tile staging: linear LDS dest (wave chunk + lane*16), inverse-swizzled
// global source column -> LDS position swz(c) holds data column c (rule #21).
template<int ROWS>
__device__ __forceinline__ void stage_glds(bf16x8* lds, const u16* __restrict__ g,
                                           size_t row0, int ldg, int col0, int tid, int w){
#pragma unroll
  for (int p = 0; p < ROWS/32; ++p){
    int idx = p*256 + tid;
    int r = idx >> 3, slot = idx & 7;
    int ss = swz(slot, r);
    GLDS(g + (row0 + (size_t)r)*(size_t)ldg + col0 + ss*8, &lds[p*256 + (w<<6)]);
  }
}

// split-bf16 3-term product: X*Y ~= Xh*Yh + Xh*Yl + Xl*Yh   (fp32 accumulate)
__device__ __forceinline__ f32x4 mfma3(bf16x8 xh, bf16x8 xl, bf16x8 yh, bf16x8 yl, f32x4 c){
  c = __builtin_amdgcn_mfma_f32_16x16x32_bf16(xh, yh, c, 0, 0, 0);
  c = __builtin_amdgcn_mfma_f32_16x16x32_bf16(xh, yl, c, 0, 0, 0);
  c = __builtin_amdgcn_mfma_f32_16x16x32_bf16(xl, yh, c, 0, 0, 0);
  return c;
}

// ---- C/D-layout -> B-fragment relayout via 4-lane shuffle (hi-only) ----------
// (used only for the q-rebuild at iteration ends, 4x per kernel)
__device__ __forceinline__ void exchange_hi(const f32x4* X, int srcA, int srcB, bool sel_hi,
                                            bf16x8& oh0, bf16x8& oh1)
{
  unsigned hi[8];
#pragma unroll
  for (int a = 0; a < 4; ++a)
#pragma unroll
    for (int b0 = 0; b0 < 2; ++b0)
      hi[a*2+b0] = cvtpk(X[a][2*b0], X[a][2*b0+1]);
  unsigned OH[8];
#pragma unroll
  for (int f = 0; f < 8; ++f){
    const int t0 = (f>>2)*4 + (f&1);
    const int sl = ((f&3)>>1) ? srcB : srcA;
    unsigned h0 = (unsigned)__shfl((int)hi[t0],     sl, 64);
    unsigned h2 = (unsigned)__shfl((int)hi[t0 + 2], sl, 64);
    OH[f] = sel_hi ? h2 : h0;
  }
  union U { unsigned u[4]; bf16x8 b; };
  U a0, a1;
#pragma unroll
  for (int c = 0; c < 4; ++c){ a0.u[c]=OH[c]; a1.u[c]=OH[4+c]; }
  oh0=a0.b; oh1=a1.b;
}

// ---------------- elementwise convert (fused over q/k/v): fp32 -> bf16 hi ----------------
__global__ void __launch_bounds__(256) k_split3(
    const float* __restrict__ xq, const float* __restrict__ xk, const float* __restrict__ xv,
    u16* __restrict__ qh, u16* __restrict__ kh, u16* __restrict__ vh, int n4){
  const int which = blockIdx.y;
  const float* x = which == 0 ? xq : which == 1 ? xk : xv;
  u16* hh = which == 0 ? qh : which == 1 ? kh : vh;
  for (int i = blockIdx.x*256 + threadIdx.x; i < n4; i += gridDim.x*256){
    float4 v = ((const float4*)x)[i];
    u16x4 h;
    h[0] = f2bf(v.x); h[1] = f2bf(v.y); h[2] = f2bf(v.z); h[3] = f2bf(v.w);
    *(u16x4*)(hh + (size_t)i*4) = h;
  }
}

// ---------------- weight transpose + split (fused over 4 weights) ----------------
// wq, wk, wv: hi only. wo: hi + lo (out-proj stays 3-term for output precision).
__global__ void __launch_bounds__(256) k_wsplit4(
    const float* __restrict__ W0, const float* __restrict__ W1,
    const float* __restrict__ W2, const float* __restrict__ W3,
    u16* __restrict__ T0h, u16* __restrict__ T1h, u16* __restrict__ T2h,
    u16* __restrict__ T3h, u16* __restrict__ T3l){
  const int which = blockIdx.z;
  const float* W = which == 0 ? W0 : which == 1 ? W1 : which == 2 ? W2 : W3;
  u16* Th = which == 0 ? T0h : which == 1 ? T1h : which == 2 ? T2h : T3h;
  __shared__ float t[32][33];
  int tx = threadIdx.x & 31, ty = threadIdx.x >> 5;      // 32 x 8
  int n0 = blockIdx.x*32, k0 = blockIdx.y*32;
#pragma unroll
  for (int i = 0; i < 4; ++i)
    t[ty + 8*i][tx] = W[(size_t)(k0 + ty + 8*i)*1024 + n0 + tx];
  __syncthreads();
#pragma unroll
  for (int i = 0; i < 4; ++i){
    int n = n0 + ty + 8*i, k = k0 + tx;
    if (which == 3){
      u16 a, b; fsplit(t[tx][ty + 8*i], a, b);
      Th[(size_t)n*1024 + k] = a;
      T3l[(size_t)n*1024 + k] = b;
    } else {
      Th[(size_t)n*1024 + k] = f2bf(t[tx][ty + 8*i]);
    }
  }
}

// ---------------- projection / output GEMM ----------------
// C(4096x1024) = A(4096x1024) * Bt^T (+bias), tile 128x64, 4 waves x (32 rows x 64 cols)
// Staging via global_load_lds (linear dest + inverse-swizzled source).
// SPLIT=false: 1-term hi*hi GEMM (Q/K/V projections). SPLIT=true: 3-term (out-proj).
// MODE 0: Q  -> LN, natural head-major write (hi only)
// MODE 1: K  -> LN, natural + transposed writes (hi only; half-swapped T)
// MODE 2: V  -> transposed hi-only write (half-swapped; V-lo residual dropped:
//               its p-weighted mean contribution to O is ~2e-5, below the floor)
// MODE 3: out-> fp32 write to d_out
template<int MODE, bool SPLIT>
__global__ void __launch_bounds__(256, 3) k_proj(
    const u16* __restrict__ Ah, const u16* __restrict__ Al,
    const u16* __restrict__ Bh, const u16* __restrict__ Bl,
    const float* __restrict__ bias, const float* __restrict__ gamma, const float* __restrict__ beta,
    u16* __restrict__ Nh,
    u16* __restrict__ Th,
    float* __restrict__ Fo)
{
  __shared__ bf16x8 sAh[128*8], sBh[64*8];
  __shared__ bf16x8 sAl[SPLIT ? 128*8 : 1], sBl[SPLIT ? 64*8 : 1];
  const int tid = threadIdx.x, lane = tid & 63, w = tid >> 6;
  const int cl = lane & 15, gq = lane >> 4;
  const int nt = blockIdx.x, mt = blockIdx.y;
  f32x4 acc[2][4] = {};
  for (int kt = 0; kt < 16; ++kt){
    __syncthreads();
    stage_glds<128>(sAh, Ah, (size_t)mt*128, 1024, kt*64, tid, w);
    stage_glds<64>(sBh, Bh, (size_t)nt*64, 1024, kt*64, tid, w);
    if constexpr (SPLIT){
      stage_glds<128>(sAl, Al, (size_t)mt*128, 1024, kt*64, tid, w);
      stage_glds<64>(sBl, Bl, (size_t)nt*64, 1024, kt*64, tid, w);
    }
    __syncthreads();
#pragma unroll
    for (int ks = 0; ks < 2; ++ks){
      const int slot = ks*4 + gq;
      bf16x8 ah0 = frag(sAh, w*32 + cl, slot);
      bf16x8 ah1 = frag(sAh, w*32 + 16 + cl, slot);
      if constexpr (SPLIT){
        bf16x8 al0 = frag(sAl, w*32 + cl, slot);
        bf16x8 al1 = frag(sAl, w*32 + 16 + cl, slot);
#pragma unroll
        for (int f = 0; f < 4; ++f){
          bf16x8 bh_ = frag(sBh, f*16 + cl, slot);
          bf16x8 bl_ = frag(sBl, f*16 + cl, slot);
          acc[0][f] = mfma3(ah0, al0, bh_, bl_, acc[0][f]);
          acc[1][f] = mfma3(ah1, al1, bh_, bl_, acc[1][f]);
        }
      } else {
#pragma unroll
        for (int f = 0; f < 4; ++f){
          bf16x8 bh_ = frag(sBh, f*16 + cl, slot);
          acc[0][f] = __builtin_amdgcn_mfma_f32_16x16x32_bf16(ah0, bh_, acc[0][f], 0, 0, 0);
          acc[1][f] = __builtin_amdgcn_mfma_f32_16x16x32_bf16(ah1, bh_, acc[1][f], 0, 0, 0);
        }
      }
    }
  }
  float bv[4];
#pragma unroll
  for (int f = 0; f < 4; ++f) bv[f] = bias[nt*64 + f*16 + cl];
  float gm[4], bt[4];
  if constexpr (MODE <= 1){
#pragma unroll
    for (int f = 0; f < 4; ++f){ gm[f] = gamma[f*16 + cl]; bt[f] = beta[f*16 + cl]; }
  }
#pragma unroll
  for (int mi = 0; mi < 2; ++mi){
    float v[4][4];
#pragma unroll
    for (int f = 0; f < 4; ++f)
#pragma unroll
      for (int r = 0; r < 4; ++r) v[f][r] = acc[mi][f][r] + bv[f];
    if constexpr (MODE <= 1){
#pragma unroll
      for (int r = 0; r < 4; ++r){
        float s1 = v[0][r] + v[1][r] + v[2][r] + v[3][r];
        float s2 = v[0][r]*v[0][r] + v[1][r]*v[1][r] + v[2][r]*v[2][r] + v[3][r]*v[3][r];
#pragma unroll
        for (int d = 1; d < 16; d <<= 1){ s1 += __shfl_xor(s1, d); s2 += __shfl_xor(s2, d); }
        float mu = s1 * (1.f/64.f);
        float var = s2 * (1.f/64.f) - mu*mu;
        float rs = rsqrtf(var + 1e-5f);
#pragma unroll
        for (int f = 0; f < 4; ++f) v[f][r] = (v[f][r] - mu)*rs*gm[f] + bt[f];
      }
    }
    const int mrow = mt*128 + w*32 + mi*16 + gq*4;   // + r
    if constexpr (MODE == 3){
#pragma unroll
      for (int f = 0; f < 4; ++f)
#pragma unroll
        for (int r = 0; r < 4; ++r)
          Fo[(size_t)(mrow + r)*1024 + nt*64 + f*16 + cl] = v[f][r];
    } else {
      const int b = mrow >> 11, srow = mrow & 2047;
      const size_t hb = (size_t)(b*16 + nt);          // head-major (b*16 + head)
      if constexpr (MODE <= 1){                       // natural write, hi only
#pragma unroll
        for (int f = 0; f < 4; ++f)
#pragma unroll
          for (int r = 0; r < 4; ++r)
            Nh[(hb*2048 + srow + r)*64 + f*16 + cl] = f2bf(v[f][r]);
      }
      if constexpr (MODE == 1 || MODE == 2){          // transposed write, hi only
        const int srow_sw = srow ^ (((cl >> 3) & 1) << 2);
#pragma unroll
        for (int f = 0; f < 4; ++f){
          u16x4 h4;
#pragma unroll
          for (int r = 0; r < 4; ++r) h4[r] = f2bf(v[f][r]);
          *(u16x4*)(Th + (hb*64 + f*16 + cl)*2048 + srow_sw) = h4;
        }
      }
    }
  }
}

// ---------------- fused Hopfield attention: all 4 iterations in one launch ----------------
// Block = 512 thr (8 waves), owns (bh, 128 q rows). Grid 512 = 2 blocks/CU.
// FIXED-MAX softmax (scores in [-64,64] deterministically -> m=64).
// Q, K, P, T all bf16 hi-only (V-lo's p-weighted-mean contribution ~2e-5).
// PV uses 16x16x16 MFMA: the QK C/D layout IS the native K=16 B-fragment ->
// NO cross-lane P relayout. Denominator via ones-MFMA (no VALU adds/reduce).
// T-operand read as b64 sub-frags with half-swapped storage (bank-spread).
// Uniform 28 MFMA/wave/step, no fin branch. LDS 32 KB.
__global__ void __launch_bounds__(512, 4) k_hopfield(
    const u16* __restrict__ Qh,
    const u16* __restrict__ Kh,
    const u16* __restrict__ Kth,
    const u16* __restrict__ Vth,
    u16* __restrict__ Oh, u16* __restrict__ Ol)
{
  __shared__ bf16x8 sKh[2][512], sTh[2][512];
  const int tid = threadIdx.x, lane = tid & 63, w = tid >> 6;
  const int cl = lane & 15, gq = lane >> 4;
  int flat = blockIdx.x;
  flat = (flat & 7)*64 + (flat >> 3);              // XCD swizzle (512 % 8 == 0: bijective)
  const int bh = flat >> 4, qt = flat & 15;
  const size_t base = (size_t)bh * (2048*64);
  const int q = qt*128 + w*16 + cl;

  // staging geometry: thread stages slot idx=tid of each 64x64 tile; source column
  // pre-swizzled so the lane-linear LDS write yields the swizzled layout.
  const int sr = tid >> 3, ss = swz(tid & 7, sr);
  const size_t offK = base + (size_t)sr*64 + ss*8;      // + kt*4096
  const size_t offT = base + (size_t)sr*2048 + ss*8;    // + kt*64
  const int wslot = w << 6;                             // wave's LDS chunk (bf16x8 units)

  // q fragments (B-operand layout, hi-only), live across all 4 iterations
  bf16x8 qfh[2];
#pragma unroll
  for (int ks = 0; ks < 2; ++ks)
    qfh[ks] = *(const bf16x8*)(Qh + base + (size_t)q*64 + ks*32 + gq*8);

  const int srcA = cl + ((gq & 1) << 5);   // shuffle source lanes for exchange_hi()
  const int srcB = srcA + 16;
  const bool sel_hi = gq >= 2;             // dest-side select: t-offset = 2*(gq>>1)

  const bf16x4 ones = {(short)0x3F80, (short)0x3F80, (short)0x3F80, (short)0x3F80};
  f32x4 accL = {0,0,0,0};                  // P column-sums (softmax denominator)
  f32x4 accO[4] = {};

  // prologue: stage tile 0 (it=0 -> T source is Kt)
  GLDS(Kh  + offK, &sKh[0][wslot]);
  GLDS(Kth + offT, &sTh[0][wslot]);
  __syncthreads();

#pragma unroll 2
  for (int t = 0; t < 128; ++t){
    const int cur = t & 1, kt = t & 31;
    if (t < 127){
      const int nt_ = t + 1, nb = nt_ & 1, nit = nt_ >> 5, nkt = nt_ & 31;
      const u16* th = (nit < 3) ? Kth : Vth;
      GLDS(Kh + offK + (size_t)nkt*4096, &sKh[nb][wslot]);
      GLDS(th + offT + (size_t)nkt*64,   &sTh[nb][wslot]);
    }
    // ---- QK^T: St[kv][q] = Kh * Qh (hi-only both sides) ----
    f32x4 S[4] = {};
    __builtin_amdgcn_s_setprio(1);
#pragma unroll
    for (int ks = 0; ks < 2; ++ks){
      const int slot = ks*4 + gq;
#pragma unroll
      for (int i = 0; i < 4; ++i){
        bf16x8 kh_ = frag(&sKh[cur][0], i*16 + cl, slot);
        S[i] = __builtin_amdgcn_mfma_f32_16x16x32_bf16(kh_, qfh[ks], S[i], 0, 0, 0);
      }
    }
    __builtin_amdgcn_s_setprio(0);
    // ---- fixed-max softmax: p = exp2(S*C1 - 64*C1), no reductions at all ----
#pragma unroll
    for (int i = 0; i < 4; ++i)
#pragma unroll
      for (int r = 0; r < 4; ++r)
        S[i][r] = fastexp2(__builtin_fmaf(S[i][r], C1, NEGM));
    // ---- P already in native 16x16x16 B-frag layout: pack only ----
    bf16x4 pf[4];
#pragma unroll
    for (int a = 0; a < 4; ++a)
      pf[a] = pk4(S[a][0], S[a][1], S[a][2], S[a][3]);
    // ---- PV: O^T += T^T * P^T via 16x16x16; denominator via ones-MFMA ----
    __builtin_amdgcn_s_setprio(1);
#pragma unroll
    for (int a = 0; a < 4; ++a)
      accL = __builtin_amdgcn_mfma_f32_16x16x16bf16_1k(ones, pf[a], accL, 0, 0, 0);
#pragma unroll
    for (int db = 0; db < 4; ++db)
#pragma unroll
      for (int a = 0; a < 4; ++a){
        bf16x4 vh_ = frag64(&sTh[cur][0], db*16 + cl, 2*a + (gq>>1), gq&1);
        accO[db] = __builtin_amdgcn_mfma_f32_16x16x16bf16_1k(vh_, pf[a], accO[db], 0, 0, 0);
      }
    __builtin_amdgcn_s_setprio(0);
    // ---- iteration epilogue ----
    if (kt == 31){
      const float inv = 1.f / accL[0];     // accL rows identical: full Σp for q=cl
      f32x4 vals[4];
#pragma unroll
      for (int db = 0; db < 4; ++db)
#pragma unroll
        for (int r = 0; r < 4; ++r) vals[db][r] = accO[db][r]*inv;
      if (t < 127){
        exchange_hi(vals, srcA, srcB, sel_hi, qfh[0], qfh[1]);
        accL = f32x4{0,0,0,0};
#pragma unroll
        for (int db = 0; db < 4; ++db) accO[db] = f32x4{0,0,0,0};
      } else {
        const int b = bh >> 4, h = bh & 15;
        const size_t row = (size_t)b*2048 + q;
#pragma unroll
        for (int db = 0; db < 4; ++db){
          u16x4 h4, l4;
#pragma unroll
          for (int r = 0; r < 4; ++r){ u16 a_, b_; fsplit(vals[db][r], a_, b_); h4[r] = a_; l4[r] = b_; }
          size_t ix = row*1024 + h*64 + db*16 + gq*4;
          *(u16x4*)(Oh + ix) = h4;
          *(u16x4*)(Ol + ix) = l4;
        }
      }
    }
    __syncthreads();
  }
}

extern "C" void kernel_launch(void* const* d_in, const int* in_sizes, int n_in,
                              void* d_out, int out_size, void* d_ws, size_t ws_size,
                              hipStream_t stream) {
  (void)in_sizes; (void)n_in; (void)out_size; (void)ws_size;
  const float* query = (const float*)d_in[0];
  const float* key   = (const float*)d_in[1];
  const float* value = (const float*)d_in[2];
  const float* Wq = (const float*)d_in[3];
  const float* bq = (const float*)d_in[4];
  const float* Wk = (const float*)d_in[5];
  const float* bk = (const float*)d_in[6];
  const float* Wv = (const float*)d_in[7];
  const float* bv = (const float*)d_in[8];
  const float* Wo = (const float*)d_in[9];
  const float* bo = (const float*)d_in[10];
  const float* gamma = (const float*)d_in[11];
  const float* beta  = (const float*)d_in[12];
  float* out = (float*)d_out;

  char* ws = (char*)d_ws;
  const size_t MB = 1024*1024;
  u16* inq_h = (u16*)(ws + 0*MB),  *inq_l = (u16*)(ws + 8*MB);
  u16* ink_h = (u16*)(ws + 16*MB);
  u16* inv_h = (u16*)(ws + 32*MB);
  u16* wq_h = (u16*)(ws + 48*MB);
  u16* wk_h = (u16*)(ws + 52*MB);
  u16* wv_h = (u16*)(ws + 56*MB);
  u16* wo_h = (u16*)(ws + 60*MB), *wo_l = (u16*)(ws + 62*MB);
  u16* Qh  = (u16*)(ws + 64*MB);
  u16* Kh  = (u16*)(ws + 80*MB);
  u16* Kth = (u16*)(ws + 96*MB);
  u16* Vth = (u16*)(ws + 112*MB);
  u16* Oh = inq_h, *Ol = inq_l;    // reuse: inq dead after proj<0>

  const int n4 = 4096*1024/4;
  k_split3<<<dim3(1024, 3), dim3(256), 0, stream>>>(query, key, value,
                                                    inq_h, ink_h, inv_h, n4);
  k_wsplit4<<<dim3(32,32,4), dim3(256), 0, stream>>>(Wq, Wk, Wv, Wo,
                                                     wq_h, wk_h, wv_h, wo_h, wo_l);

  k_proj<0,false><<<dim3(16,32), dim3(256), 0, stream>>>(inq_h, nullptr, wq_h, nullptr, bq, gamma, beta,
                                                         Qh, nullptr, nullptr);
  k_proj<1,false><<<dim3(16,32), dim3(256), 0, stream>>>(ink_h, nullptr, wk_h, nullptr, bk, gamma, beta,
                                                         Kh, Kth, nullptr);
  k_proj<2,false><<<dim3(16,32), dim3(256), 0, stream>>>(inv_h, nullptr, wv_h, nullptr, bv, nullptr, nullptr,
                                                         nullptr, Vth, nullptr);

  k_hopfield<<<dim3(512), dim3(512), 0, stream>>>(Qh, Kh, Kth, Vth, Oh, Ol);

  k_proj<3,true><<<dim3(16,32), dim3(256), 0, stream>>>(Oh, Ol, wo_h, wo_l, bo, nullptr, nullptr,
                                                        nullptr, nullptr, out);
}